// Round 23
// baseline (438.244 us; speedup 1.0000x reference)
//
#include <hip/hip_runtime.h>

#define SL 2048
#define HID 1024
#define NHEAD 16
#define HD 64
#define NEXP 8
#define FF 2048
#define MAXTILE 40
#define MAXROWS (MAXTILE * 128)
#define CPAD 32   /* ints: one 128B line per counter */

typedef short bf16x8 __attribute__((ext_vector_type(8)));
typedef float f32x4 __attribute__((ext_vector_type(4)));
typedef unsigned u32x4 __attribute__((ext_vector_type(4)));

__device__ __forceinline__ unsigned short f2bf(float f) {
  unsigned u = __builtin_bit_cast(unsigned, f);
  u += 0x7fffu + ((u >> 16) & 1u);
  return (unsigned short)(u >> 16);
}

__device__ __forceinline__ void gload16(const void* g, void* l) {
  __builtin_amdgcn_global_load_lds((const __attribute__((address_space(1))) void*)g,
                                   (__attribute__((address_space(3))) void*)l,
                                   16, 0, 0);
}

// XCD-aware remap (bijective when gridDim.x*gridDim.y % 8 == 0).
__device__ __forceinline__ void xcd_remap(int& bx, int& by) {
  const int nx = gridDim.x;
  const int nwg = nx * gridDim.y;
  const int L = by * nx + bx;
  const int per = nwg >> 3;
  const int Lp = (L & 7) * per + (L >> 3);
  bx = Lp % nx;
  by = Lp / nx;
}

// ---- shared scratch for the w1/w2 transpose tiles (49.7 KB) ----
struct TransLds { float Afp[64 * 128]; unsigned Bu[128 * 33]; };

// One 64x128 fp32 tile -> bf16 transposed. 256 threads. Async gload16 staging.
__device__ __forceinline__ void trans_tile(
    int tile, const float* __restrict__ w1, const float* __restrict__ w2,
    unsigned short* __restrict__ w1t, unsigned short* __restrict__ w2t,
    int tid, TransLds* T)
{
  const int m = tile >> 8;          // matrix 0..15
  const int t = tile & 255;
  const float* in;
  unsigned short* out;
  int R, C, r0, c0;
  if (m < 8) {
    in = w1 + (size_t)m * HID * FF;  out = w1t + (size_t)m * HID * FF;
    R = HID; C = FF;  r0 = (t >> 4) * 64;  c0 = (t & 15) * 128;
  } else {
    in = w2 + (size_t)(m - 8) * FF * HID;  out = w2t + (size_t)(m - 8) * FF * HID;
    R = FF; C = HID;  r0 = (t >> 3) * 64;  c0 = (t & 7) * 128;
  }
  const int wv = tid >> 6, ln = tid & 63;
#pragma unroll
  for (int p = 0; p < 8; p++) {
    const int ebase = p * 1024 + wv * 256;
    const int eo = ebase + ln * 4;
    const int r = eo >> 7, c = eo & 127;
    gload16(in + (size_t)(r0 + r) * C + c0 + c, (char*)T->Afp + (size_t)ebase * 4);
  }
  asm volatile("s_waitcnt vmcnt(0)" ::: "memory");
  __syncthreads();
#pragma unroll
  for (int it = 0; it < 16; it++) {
    const int idx = it * 256 + tid;
    const int rp = idx >> 7;
    const int c = idx & 127;
    const float v0 = T->Afp[(2 * rp) * 128 + c];
    const float v1 = T->Afp[(2 * rp + 1) * 128 + c];
    T->Bu[c * 33 + rp] = (unsigned)f2bf(v0) | ((unsigned)f2bf(v1) << 16);
  }
  __syncthreads();
#pragma unroll
  for (int it = 0; it < 8; it++) {
    const int idx = it * 256 + tid;
    const int c = idx >> 4;
    const int r4 = (idx & 15) * 4;
    const unsigned u0 = T->Bu[c * 33 + (r4 >> 1)];
    const unsigned u1 = T->Bu[c * 33 + (r4 >> 1) + 1];
    ushort4 u;
    u.x = (unsigned short)(u0 & 0xffff);
    u.y = (unsigned short)(u0 >> 16);
    u.z = (unsigned short)(u1 & 0xffff);
    u.w = (unsigned short)(u1 >> 16);
    *reinterpret_cast<ushort4*>(&out[(size_t)(c0 + c) * R + r0 + r4]) = u;
  }
}

// ============ 128x128 / BK=32 GEMM, 3-slot depth-2 counted-vmcnt pipeline ==========
#define PIPE_WAIT(i, NT)                                                     \
  if ((i) == (NT) - 1)                                                       \
    asm volatile("s_waitcnt vmcnt(0) lgkmcnt(0)" ::: "memory");              \
  else                                                                       \
    asm volatile("s_waitcnt vmcnt(4) lgkmcnt(0)" ::: "memory");              \
  __builtin_amdgcn_s_barrier();

#define GEMM_FRAGS_MFMA(CC)                                                  \
  bf16x8 af[4], bfr[4];                                                      \
  _Pragma("unroll")                                                          \
  for (int mt = 0; mt < 4; mt++)                                             \
    af[mt] = *reinterpret_cast<const bf16x8*>(                               \
        &Asm[CC][(wm + mt * 16 + la) * 32 + lk]);                            \
  _Pragma("unroll")                                                          \
  for (int nt = 0; nt < 4; nt++)                                             \
    bfr[nt] = *reinterpret_cast<const bf16x8*>(                              \
        &Bsm[CC][(wn + nt * 16 + la) * 32 + lk]);                            \
  __builtin_amdgcn_s_setprio(1);                                             \
  _Pragma("unroll")                                                          \
  for (int mt = 0; mt < 4; mt++)                                             \
    _Pragma("unroll")                                                        \
    for (int nt = 0; nt < 4; nt++)                                           \
      acc[mt][nt] =                                                          \
          __builtin_amdgcn_mfma_f32_16x16x32_bf16(af[mt], bfr[nt], acc[mt][nt], 0, 0, 0); \
  __builtin_amdgcn_s_setprio(0);

#define PIPE_ROT()                                                           \
  cc = (cc == 2) ? 0 : cc + 1;                                               \
  cs = (cs == 2) ? 0 : cs + 1;

// ------- FUSED: z==0 -> QKV GEMM; z=1..7 -> w1/w2 transpose tiles [512,3200) -------
__global__ __launch_bounds__(256) void qkv_trans_kernel(
    const unsigned short* __restrict__ A, const unsigned short* __restrict__ Bt,
    const float* __restrict__ bias,
    unsigned short* __restrict__ q_out, unsigned short* __restrict__ k_out,
    unsigned short* __restrict__ vt_out,
    const float* __restrict__ w1, const float* __restrict__ w2,
    unsigned short* __restrict__ w1t, unsigned short* __restrict__ w2t)
{
  __shared__ union {
    struct { unsigned short A[3][4096]; unsigned short B[3][4096]; } g;   // 48 KB
    TransLds t;                                                           // 49.7 KB
  } sm;
  const int tid = threadIdx.x;

  if (blockIdx.z == 0) {
    unsigned short (*Asm)[4096] = sm.g.A;
    unsigned short (*Bsm)[4096] = sm.g.B;
    int bx = blockIdx.x, by = blockIdx.y;
    xcd_remap(bx, by);
    const int wave = tid >> 6;
    const int lane = tid & 63;
    const int m0 = by * 128;
    const int n0 = bx * 128;
    const int wm = (wave >> 1) * 64;
    const int wn = (wave & 1) * 64;
    const int la = lane & 15;
    const int lk = (lane >> 4) * 8;

    f32x4 acc[4][4] = {};

    const int srow = tid >> 2;
    const int skoff = (tid & 3) * 8;
    const unsigned short* Ag = A + (size_t)(m0 + srow) * HID + skoff;
    const unsigned short* Bg = Bt + (size_t)(n0 + srow) * HID + skoff;

    auto stage = [&](int s, int k0) {
      gload16(Ag + k0, &Asm[s][wave * 512]);
      gload16(Ag + (size_t)64 * HID + k0, &Asm[s][2048 + wave * 512]);
      gload16(Bg + k0, &Bsm[s][wave * 512]);
      gload16(Bg + (size_t)64 * HID + k0, &Bsm[s][2048 + wave * 512]);
    };

    stage(0, 0);
    stage(1, 32);
    const int NT = HID >> 5;
    int cc = 0, cs = 2;
    for (int i = 0; i < NT; ++i) {
      PIPE_WAIT(i, NT)
      if (i + 2 < NT) stage(cs, (i + 2) << 5);
      GEMM_FRAGS_MFMA(cc)
      PIPE_ROT()
    }

    const int lg = lane >> 4;
#pragma unroll
    for (int mt = 0; mt < 4; mt++) {
#pragma unroll
      for (int nt = 0; nt < 4; nt++) {
#pragma unroll
        for (int r = 0; r < 4; r++) {
          const int row = m0 + wm + mt * 16 + lg * 4 + r;
          const int col = n0 + wn + nt * 16 + la;
          float v = acc[mt][nt][r] + bias[col];
          const int hh = (col & 1023) >> 6;
          const int dd = col & 63;
          const unsigned short bv = f2bf(v);
          if (col < 1024)
            q_out[(size_t)hh * SL * HD + (size_t)row * HD + dd] = bv;
          else if (col < 2048)
            k_out[(size_t)hh * SL * HD + (size_t)row * HD + dd] = bv;
          else
            vt_out[(size_t)hh * HD * SL + (size_t)dd * SL + row] = bv;
        }
      }
    }
  } else {
    const int id = blockIdx.y * 24 + blockIdx.x;          // 0..383
    const int tile = 512 + ((int)blockIdx.z - 1) * 384 + id;
    trans_tile(tile, w1, w2, w1t, w2t, tid, &sm.t);
  }
}

// ------- out-proj GEMM (z=0,1: split-K partials) + transpose tiles [3200,4096) -----
__global__ __launch_bounds__(256) void gemm_bt2(
    const unsigned short* __restrict__ A, const unsigned short* __restrict__ Bt,
    float* __restrict__ outf,
    const float* __restrict__ w1, const float* __restrict__ w2,
    unsigned short* __restrict__ w1t, unsigned short* __restrict__ w2t)
{
  __shared__ union {
    struct { unsigned short A[3][4096]; unsigned short B[3][4096]; } g;
    TransLds t;
  } sm;
  const int tid = threadIdx.x;

  if (blockIdx.z >= 2) {
    const int id = blockIdx.y * 8 + blockIdx.x;          // 0..127
    const int tile = 3200 + ((int)blockIdx.z - 2) * 128 + id;
    trans_tile(tile, w1, w2, w1t, w2t, tid, &sm.t);
    return;
  }

  unsigned short (*Asm)[4096] = sm.g.A;
  unsigned short (*Bsm)[4096] = sm.g.B;
  int bx = blockIdx.x, by = blockIdx.y;
  xcd_remap(bx, by);
  const int wave = tid >> 6;
  const int lane = tid & 63;
  const int m0 = by * 128;
  const int n0 = bx * 128;
  const int koff = blockIdx.z * (HID / 2);
  const int wm = (wave >> 1) * 64;
  const int wn = (wave & 1) * 64;
  const int la = lane & 15;
  const int lk = (lane >> 4) * 8;

  f32x4 acc[4][4] = {};

  const int srow = tid >> 2;
  const int skoff = (tid & 3) * 8;
  const unsigned short* Ag = A + (size_t)(m0 + srow) * HID + koff + skoff;
  const unsigned short* Bg = Bt + (size_t)(n0 + srow) * HID + koff + skoff;

  auto stage = [&](int s, int k0) {
    gload16(Ag + k0, &Asm[s][wave * 512]);
    gload16(Ag + (size_t)64 * HID + k0, &Asm[s][2048 + wave * 512]);
    gload16(Bg + k0, &Bsm[s][wave * 512]);
    gload16(Bg + (size_t)64 * HID + k0, &Bsm[s][2048 + wave * 512]);
  };

  stage(0, 0);
  stage(1, 32);
  const int NT = (HID / 2) >> 5;
  int cc = 0, cs = 2;
  for (int i = 0; i < NT; ++i) {
    PIPE_WAIT(i, NT)
    if (i + 2 < NT) stage(cs, (i + 2) << 5);
    GEMM_FRAGS_MFMA(cc)
    PIPE_ROT()
  }

  const int lg = lane >> 4;
#pragma unroll
  for (int mt = 0; mt < 4; mt++) {
#pragma unroll
    for (int nt = 0; nt < 4; nt++) {
#pragma unroll
      for (int r = 0; r < 4; r++) {
        const int row = m0 + wm + mt * 16 + lg * 4 + r;
        const int col = n0 + wn + nt * 16 + la;
        outf[(size_t)blockIdx.z * SL * HID + (size_t)row * HID + col] = acc[mt][nt][r];
      }
    }
  }
}

// ---------------- MoE GEMM1: gathered A, gelu*gate epilogue -> hmidg (bf16) --------
__global__ __launch_bounds__(256) void gemm_moe1(
    const unsigned short* __restrict__ A, const unsigned short* __restrict__ w1t,
    const int* __restrict__ perm, const float* __restrict__ gateg,
    const int* __restrict__ texp, const int* __restrict__ trow,
    unsigned short* __restrict__ hmidg)
{
  __shared__ unsigned short Asm[3][128 * 32];
  __shared__ unsigned short Bsm[3][128 * 32];
  int bx = blockIdx.x, by = blockIdx.y;
  xcd_remap(bx, by);
  const int e = texp[by];
  if (e < 0) return;
  const int row0 = trow[by];
  const int tid = threadIdx.x;
  const int wave = tid >> 6;
  const int lane = tid & 63;
  const int n0 = bx * 128;
  const int wm = (wave >> 1) * 64;
  const int wn = (wave & 1) * 64;
  const int la = lane & 15;
  const int lk = (lane >> 4) * 8;
  f32x4 acc[4][4] = {};

  const int srow = tid >> 2;
  const int skoff = (tid & 3) * 8;
  const int p0 = perm[row0 + srow];
  const int p1 = perm[row0 + 64 + srow];
  const unsigned short* Ag0 = A + (size_t)(p0 < 0 ? 0 : (p0 >> 1)) * HID + skoff;
  const unsigned short* Ag1 = A + (size_t)(p1 < 0 ? 0 : (p1 >> 1)) * HID + skoff;
  const unsigned short* Bg = w1t + (size_t)e * HID * FF + (size_t)(n0 + srow) * HID + skoff;

  auto stage = [&](int s, int k0) {
    gload16(Ag0 + k0, &Asm[s][wave * 512]);
    gload16(Ag1 + k0, &Asm[s][2048 + wave * 512]);
    gload16(Bg + k0, &Bsm[s][wave * 512]);
    gload16(Bg + (size_t)64 * HID + k0, &Bsm[s][2048 + wave * 512]);
  };

  stage(0, 0);
  stage(1, 32);
  const int NT = HID >> 5;
  int cc = 0, cs = 2;
  for (int i = 0; i < NT; ++i) {
    PIPE_WAIT(i, NT)
    if (i + 2 < NT) stage(cs, (i + 2) << 5);
    GEMM_FRAGS_MFMA(cc)
    PIPE_ROT()
  }

  const int lg = lane >> 4;
#pragma unroll
  for (int mt = 0; mt < 4; mt++) {
    float gr[4];
#pragma unroll
    for (int r = 0; r < 4; r++) gr[r] = gateg[row0 + wm + mt * 16 + lg * 4 + r];
#pragma unroll
    for (int nt = 0; nt < 4; nt++) {
#pragma unroll
      for (int r = 0; r < 4; r++) {
        const int grow = row0 + wm + mt * 16 + lg * 4 + r;
        const int col = n0 + wn + nt * 16 + la;
        const float v = acc[mt][nt][r];
        const float g = 0.5f * v * (1.0f + erff(v * 0.70710678118f));
        hmidg[(size_t)grow * FF + col] = f2bf(g * gr[r]);
      }
    }
  }
}

// ------- MoE GEMM2: split-K x2, scatter rows: atomicAdd into out (seeded with x1) --
__global__ __launch_bounds__(256) void gemm_moe2(
    const unsigned short* __restrict__ A, const unsigned short* __restrict__ w2t,
    const int* __restrict__ perm,
    const int* __restrict__ texp, const int* __restrict__ trow,
    float* __restrict__ outbuf)
{
  __shared__ unsigned short Asm[3][128 * 32];
  __shared__ unsigned short Bsm[3][128 * 32];
  int bx = blockIdx.x, by = blockIdx.y;
  xcd_remap(bx, by);
  const int e = texp[by];
  if (e < 0) return;
  const int row0 = trow[by];
  const int tid = threadIdx.x;
  const int wave = tid >> 6;
  const int lane = tid & 63;
  const int n0 = bx * 128;
  const int koff = blockIdx.z * (FF / 2);
  const int wm = (wave >> 1) * 64;
  const int wn = (wave & 1) * 64;
  const int la = lane & 15;
  const int lk = (lane >> 4) * 8;
  f32x4 acc[4][4] = {};

  const int srow = tid >> 2;
  const int skoff = (tid & 3) * 8;
  const unsigned short* Ag = A + (size_t)(row0 + srow) * FF + koff + skoff;
  const unsigned short* Bg = w2t + (size_t)e * FF * HID + (size_t)(n0 + srow) * FF + koff + skoff;

  auto stage = [&](int s, int k0) {
    gload16(Ag + k0, &Asm[s][wave * 512]);
    gload16(Ag + (size_t)64 * FF + k0, &Asm[s][2048 + wave * 512]);
    gload16(Bg + k0, &Bsm[s][wave * 512]);
    gload16(Bg + (size_t)64 * FF + k0, &Bsm[s][2048 + wave * 512]);
  };

  stage(0, 0);
  stage(1, 32);
  const int NT = (FF / 2) >> 5;
  int cc = 0, cs = 2;
  for (int i = 0; i < NT; ++i) {
    PIPE_WAIT(i, NT)
    if (i + 2 < NT) stage(cs, (i + 2) << 5);
    GEMM_FRAGS_MFMA(cc)
    PIPE_ROT()
  }

  const int lg = lane >> 4;
#pragma unroll
  for (int mt = 0; mt < 4; mt++) {
    int pr[4];
#pragma unroll
    for (int r = 0; r < 4; r++) pr[r] = perm[row0 + wm + mt * 16 + lg * 4 + r];
#pragma unroll
    for (int nt = 0; nt < 4; nt++) {
#pragma unroll
      for (int r = 0; r < 4; r++) {
        const int p = pr[r];
        if (p >= 0) {
          const int col = n0 + wn + nt * 16 + la;
          atomicAdd(&outbuf[(size_t)(p >> 1) * HID + col], acc[mt][nt][r]);
        }
      }
    }
  }
}

// FUSED: x<SL -> LayerNorm(ln1); x in [SL,SL+512) -> weight convert;
//        x in [SL+512, SL+1024) -> transpose tiles [0,512)
__global__ __launch_bounds__(256) void ln_conv_kernel(
    const float* __restrict__ x, const float* __restrict__ w, const float* __restrict__ b,
    unsigned short* __restrict__ ob,
    const float4* __restrict__ cva, const float4* __restrict__ cvb,
    ushort4* __restrict__ coa, ushort4* __restrict__ cob,
    const float* __restrict__ w1, const float* __restrict__ w2,
    unsigned short* __restrict__ w1t, unsigned short* __restrict__ w2t)
{
  __shared__ union { struct { float ps[4], pq[4]; } l; TransLds t; } sm;
  const int tid = threadIdx.x;
  if ((int)blockIdx.x < SL) {
    const int row = blockIdx.x;
    const float4 v = *reinterpret_cast<const float4*>(&x[(size_t)row * HID + tid * 4]);
    float s = v.x + v.y + v.z + v.w;
    float q = v.x * v.x + v.y * v.y + v.z * v.z + v.w * v.w;
    for (int off = 32; off > 0; off >>= 1) {
      s += __shfl_down(s, off);
      q += __shfl_down(q, off);
    }
    const int wave = tid >> 6, lane = tid & 63;
    if (lane == 0) { sm.l.ps[wave] = s; sm.l.pq[wave] = q; }
    __syncthreads();
    s = sm.l.ps[0] + sm.l.ps[1] + sm.l.ps[2] + sm.l.ps[3];
    q = sm.l.pq[0] + sm.l.pq[1] + sm.l.pq[2] + sm.l.pq[3];
    const float mu = s * (1.0f / HID);
    const float inv = rsqrtf(q * (1.0f / HID) - mu * mu + 1e-5f);
    const int i = tid * 4;
    const float4 wv = *reinterpret_cast<const float4*>(&w[i]);
    const float4 bv = *reinterpret_cast<const float4*>(&b[i]);
    ushort4 u;
    u.x = f2bf((v.x - mu) * inv * wv.x + bv.x);
    u.y = f2bf((v.y - mu) * inv * wv.y + bv.y);
    u.z = f2bf((v.z - mu) * inv * wv.z + bv.z);
    u.w = f2bf((v.w - mu) * inv * wv.w + bv.w);
    *reinterpret_cast<ushort4*>(&ob[(size_t)row * HID + i]) = u;
  } else if ((int)blockIdx.x < SL + 512) {
    const int NA = 3 * HID * HID / 4, NB = HID * HID / 4;
    for (int i = ((int)blockIdx.x - SL) * 256 + tid; i < NA + NB; i += 512 * 256) {
      if (i < NA) {
        const float4 v = cva[i];
        ushort4 u; u.x = f2bf(v.x); u.y = f2bf(v.y); u.z = f2bf(v.z); u.w = f2bf(v.w);
        coa[i] = u;
      } else {
        const float4 v = cvb[i - NA];
        ushort4 u; u.x = f2bf(v.x); u.y = f2bf(v.y); u.z = f2bf(v.z); u.w = f2bf(v.w);
        cob[i - NA] = u;
      }
    }
  } else {
    const int tile = (int)blockIdx.x - SL - 512;   // 0..511
    trans_tile(tile, w1, w2, w1t, w2t, tid, &sm.t);
  }
}

// fused: out = x + bias + p0 + p1 (residual seed); LN -> hn2_b; ROUTER (top-2);
// last block: scan + build (device-scope fence handoff)
__global__ __launch_bounds__(256) void combine_ln(
    const float4* __restrict__ x, const float* __restrict__ bias,
    const float4* __restrict__ p0, const float4* __restrict__ p1,
    float4* __restrict__ outbuf,
    const float* __restrict__ w, const float* __restrict__ b,
    unsigned short* __restrict__ ob,
    const float* __restrict__ rw,
    int* __restrict__ ti, float* __restrict__ tg, int* __restrict__ cnt,
    int* __restrict__ donecnt,
    int* __restrict__ texp, int* __restrict__ trow,
    int* __restrict__ perm, float* __restrict__ gateg)
{
  __shared__ float ps[4], pq[4];
  __shared__ float rsm[4][8];
  __shared__ int poff[NEXP];
  __shared__ int lfill[NEXP];
  __shared__ int lastflag;
  const int row = blockIdx.x;
  const int tid = threadIdx.x;
  const int i4 = row * 256 + tid;
  const int i = tid * 4;
  const float4 bv0 = *reinterpret_cast<const float4*>(&bias[i]);
  const float4 a = x[i4], c = p0[i4], d = p1[i4];
  float4 v;
  v.x = a.x + bv0.x + c.x + d.x;
  v.y = a.y + bv0.y + c.y + d.y;
  v.z = a.z + bv0.z + c.z + d.z;
  v.w = a.w + bv0.w + c.w + d.w;
  outbuf[i4] = v;
  float s = v.x + v.y + v.z + v.w;
  float q = v.x * v.x + v.y * v.y + v.z * v.z + v.w * v.w;
  for (int off = 32; off > 0; off >>= 1) {
    s += __shfl_down(s, off);
    q += __shfl_down(q, off);
  }
  const int wave = tid >> 6, lane = tid & 63;
  if (lane == 0) { ps[wave] = s; pq[wave] = q; }
  __syncthreads();
  s = ps[0] + ps[1] + ps[2] + ps[3];
  q = pq[0] + pq[1] + pq[2] + pq[3];
  const float mu = s * (1.0f / HID);
  const float inv = rsqrtf(q * (1.0f / HID) - mu * mu + 1e-5f);
  const float4 wv = *reinterpret_cast<const float4*>(&w[i]);
  const float4 bv = *reinterpret_cast<const float4*>(&b[i]);
  const float o0 = (v.x - mu) * inv * wv.x + bv.x;
  const float o1 = (v.y - mu) * inv * wv.y + bv.y;
  const float o2 = (v.z - mu) * inv * wv.z + bv.z;
  const float o3 = (v.w - mu) * inv * wv.w + bv.w;
  ushort4 u; u.x = f2bf(o0); u.y = f2bf(o1); u.z = f2bf(o2); u.w = f2bf(o3);
  *reinterpret_cast<ushort4*>(&ob[(size_t)row * HID + i]) = u;

  // ---- fused router: logits[e] = sum_i hn2[i] * rw[e][i] (fp32) ----
  float pl[NEXP];
#pragma unroll
  for (int e = 0; e < NEXP; e++) {
    const float4 rv = *reinterpret_cast<const float4*>(&rw[e * HID + i]);
    pl[e] = o0 * rv.x + o1 * rv.y + o2 * rv.z + o3 * rv.w;
  }
#pragma unroll
  for (int e = 0; e < NEXP; e++) {
    pl[e] += __shfl_xor(pl[e], 32);
    pl[e] += __shfl_xor(pl[e], 16);
    pl[e] += __shfl_xor(pl[e], 8);
    pl[e] += __shfl_xor(pl[e], 4);
    pl[e] += __shfl_xor(pl[e], 2);
    pl[e] += __shfl_xor(pl[e], 1);
  }
  if (lane == 0) {
#pragma unroll
    for (int e = 0; e < NEXP; e++) rsm[wave][e] = pl[e];
  }
  __syncthreads();
  if (tid == 0) {
    float lgt[NEXP];
#pragma unroll
    for (int e = 0; e < NEXP; e++)
      lgt[e] = rsm[0][e] + rsm[1][e] + rsm[2][e] + rsm[3][e];
    float mx = lgt[0];
#pragma unroll
    for (int e = 1; e < NEXP; e++) mx = fmaxf(mx, lgt[e]);
    float Z = 0.f;
    float pexp[NEXP];
#pragma unroll
    for (int e = 0; e < NEXP; e++) { pexp[e] = expf(lgt[e] - mx); Z += pexp[e]; }
    const float invZ = 1.f / Z;
    int i1 = 0;
#pragma unroll
    for (int e = 1; e < NEXP; e++) if (pexp[e] > pexp[i1]) i1 = e;
    int i2 = (i1 == 0) ? 1 : 0;
#pragma unroll
    for (int e = 0; e < NEXP; e++) if (e != i1 && pexp[e] > pexp[i2]) i2 = e;
    ti[2 * row] = i1; ti[2 * row + 1] = i2;
    tg[2 * row] = pexp[i1] * invZ; tg[2 * row + 1] = pexp[i2] * invZ;
    atomicAdd(&cnt[i1 * CPAD], 1);
    atomicAdd(&cnt[i2 * CPAD], 1);
  }

  // ---- last-block fused scan + build ----
  __threadfence();            // release: publish ti/tg/cnt
  if (tid == 0) {
    const int dcnt = atomicAdd(donecnt, 1);
    lastflag = (dcnt == (int)gridDim.x - 1);
  }
  __syncthreads();
  if (!lastflag) return;
  __threadfence();            // acquire: other blocks' ti/tg/cnt now visible
  if (tid == 0) {
    int off = 0, nt = 0;
    for (int e = 0; e < NEXP; e++) {
      poff[e] = off;
      const int ce = atomicAdd(&cnt[e * CPAD], 0);
      const int ntl = (ce + 127) >> 7;
      for (int t2 = 0; t2 < ntl; t2++) { texp[nt] = e; trow[nt] = off + t2 * 128; nt++; }
      off += ntl * 128;
    }
    for (int t2 = nt; t2 < MAXTILE; t2++) { texp[t2] = -1; trow[t2] = 0; }
  }
  if (tid < NEXP) lfill[tid] = 0;
  __syncthreads();
  for (int t = tid; t < SL; t += 256) {
#pragma unroll
    for (int s2 = 0; s2 < 2; s2++) {
      const int e = ti[2 * t + s2];
      const int l = atomicAdd(&lfill[e], 1);
      const int pos = poff[e] + l;
      perm[pos] = 2 * t + s2;
      gateg[pos] = tg[2 * t + s2];
    }
  }
}

// ------- flash attention, causal, paired q-tiles, 8 waves = 2 KV-split groups -------
#define SC2 0.1803368801111204f  /* 0.125 * log2(e) */
#define PPITCH 20                /* padded u32 pitch for P rows */
__global__ __launch_bounds__(512) void attn_kernel(
    const unsigned short* __restrict__ qb, const unsigned short* __restrict__ kb,
    const unsigned short* __restrict__ vtb, unsigned short* __restrict__ attn)
{
  const int h = blockIdx.y;
  const int tid = threadIdx.x;
  const int wave = tid >> 6, lane = tid & 63;
  const int grp = wave >> 2;
  const int w4 = wave & 3;
  const int la = lane & 15, lg = lane >> 4;
  const int la7 = la & 7;
  __shared__ unsigned short Kt[2][2][64 * 64];
  __shared__ unsigned short Vt[2][2][64 * 64];
  __shared__ unsigned plds[8 * 32 * PPITCH];
  const unsigned short* qh = qb + (size_t)h * SL * HD;
  const unsigned short* kh = kb + (size_t)h * SL * HD;
  const unsigned short* vh = vtb + (size_t)h * HD * SL;
  unsigned* pu = &plds[wave * 32 * PPITCH];

  const int sr_lo = w4 * 8 + (lane >> 3);
  const int ss = lane & 7;

  auto stageKV = [&](int t, int buf) {
    const int kvb = t * 64;
#pragma unroll
    for (int j = 0; j < 2; j++) {
      const int row = j * 32 + sr_lo;
      const int s = ss ^ (row & 7);
      gload16(kh + (size_t)(kvb + row) * HD + s * 8, &Kt[grp][buf][j * 2048 + w4 * 512]);
      gload16(vh + (size_t)row * SL + kvb + s * 8, &Vt[grp][buf][j * 2048 + w4 * 512]);
    }
  };

  for (int half = 0; half < 2; half++) {
    const int qt = half ? (31 - blockIdx.x) : blockIdx.x;
    const int m0 = qt * 64 + w4 * 16;
    const int T = qt + 1;
    const int S = (T + 1) >> 1;
    const int q = m0 + la;

    bf16x8 aq0 = *reinterpret_cast<const bf16x8*>(&qh[(size_t)(m0 + la) * HD + lg * 8]);
    bf16x8 aq1 = *reinterpret_cast<const bf16x8*>(&qh[(size_t)(m0 + la) * HD + 32 + lg * 8]);

    f32x4 oacc[4] = {};
    float mrun = -1e30f, lrun = 0.f;

    if (grp < T) stageKV(grp, 0);
    __syncthreads();
    int cur = 0;

    for (int s = 0; s < S; s++) {
      const int tmy = 2 * s + grp;
      if (tmy + 2 < T) stageKV(tmy + 2, cur ^ 1);
      if (tmy < T) {
        const int kv0 = tmy * 64;
        const unsigned short* Kb = Kt[grp][cur];
        const unsigned short* Vb = Vt[grp][cur];

        f32x4 sac[4] = {};
        __builtin_amdgcn_s_setprio(1);
#pragma unroll
        for (int nt = 0; nt < 4; nt++) {
          const int row = nt * 16 + la;
          bf16x8 b0 = *reinterpret_cast<const bf16x8*>(&Kb[row * 64 + ((lg ^ la7) << 3)]);
          bf16x8 b1 = *reinterpret_cast<const bf16x8*>(&Kb[row * 64 + (((4 + lg) ^ la7) << 3)]);
          sac[nt] = __builtin_amdgcn_mfma_f32_16x16x32_bf16(b0, aq0, sac[nt], 0, 0, 0);
          sac[nt] = __builtin_amdgcn_mfma_f32_16x16x32_bf16(b1, aq1, sac[nt], 0, 0, 0);
        }
        __builtin_amdgcn_s_setprio(0);
        float sv[4][4];
        const bool diag = (tmy == qt);
#pragma unroll
        for (int nt = 0; nt < 4; nt++)
#pragma unroll
          for (int r = 0; r < 4; r++) {
            float xs = sac[nt][r] * SC2;
            if (diag && (kv0 + nt * 16 + lg * 4 + r) > q) xs = -1e30f;
            sv[nt][r] = xs;
          }
        float pm = fmaxf(fmaxf(sv[0][0], sv[0][1]), fmaxf(sv[0][2], sv[0][3]));
#pragma unroll
        for (int nt = 1; nt < 4; nt++)
          pm = fmaxf(pm, fmaxf(fmaxf(sv[nt][0], sv[nt][1]), fmaxf(sv[nt][2], sv[nt][3])));
        pm = fmaxf(pm, __shfl_xor(pm, 16));
        pm = fmaxf(pm, __shfl_xor(pm, 32));
        const float mn = fmaxf(mrun, pm);
        float rs = 0.f;
#pragma unroll
        for (int nt = 0; nt < 4; nt++)
#pragma unroll
          for (int r = 0; r < 4; r++) {
            const float pe = exp2f(sv[nt][r] - mn);
            sv[nt][r] = pe;
            rs += pe;
          }
        rs += __shfl_xor(rs, 16);
        rs += __shfl_xor(rs, 32);
        if (__ballot(pm > mrun) != 0ULL) {
          const float al = exp2f(mrun - mn);
#pragma unroll
          for (int dt = 0; dt < 4; dt++)
#pragma unroll
            for (int r = 0; r < 4; r++) oacc[dt][r] *= al;
          lrun = lrun * al + rs;
          mrun = mn;
        } else {
          lrun += rs;
        }
#pragma unroll
        for (int nt = 0; nt < 4; nt++)
#pragma unroll
          for (int rp = 0; rp < 2; rp++) {
            unsigned pk;
            asm("v_cvt_pk_bf16_f32 %0, %1, %2"
                : "=v"(pk) : "v"(sv[nt][rp * 2]), "v"(sv[nt][rp * 2 + 1]));
            pu[(nt * 8 + lg * 2 + rp) * PPITCH + la] = pk;
          }
        asm volatile("s_waitcnt lgkmcnt(0)" ::: "memory");
        __builtin_amdgcn_sched_barrier(0);
        u32x4 w0, w1;
#pragma unroll
        for (int jj = 0; jj < 4; jj++) {
          w0[jj] = pu[(lg * 4 + jj) * PPITCH + la];
          w1[jj] = pu[(16 + lg * 4 + jj) * PPITCH + la];
        }
        const bf16x8 pa0 = __builtin_bit_cast(bf16x8, w0);
        const bf16x8 pa1 = __builtin_bit_cast(bf16x8, w1);
        __builtin_amdgcn_s_setprio(1);
#pragma unroll
        for (int dt = 0; dt < 4; dt++) {
          const int row = dt * 16 + la;
          bf16x8 v0 = *reinterpret_cast<const bf16x8*>(&Vb[row * 64 + ((lg ^ la7) << 3)]);
          bf16x8 v1 = *reinterpret_cast<const bf16x8*>(&Vb[row * 64 + (((4 + lg) ^ la7) << 3)]);
          oacc[dt] = __builtin_amdgcn_mfma_f32_16x16x32_bf16(v0, pa0, oacc[dt], 0, 0, 0);
          oacc[dt] = __builtin_amdgcn_mfma_f32_16x16x32_bf16(v1, pa1, oacc[dt], 0, 0, 0);
        }
        __builtin_amdgcn_s_setprio(0);
      }
      __syncthreads();
      cur ^= 1;
    }

    float* xb = (float*)&Kt[0][0][0];
    float* mlb = (float*)&Vt[0][0][0];
    if (grp == 1) {
#pragma unroll
      for (int dt = 0; dt < 4; dt++)
#pragma unroll
        for (int r = 0; r < 4; r++)
          xb[w4 * 1024 + (dt * 16 + lg * 4 + r) * 16 + la] = oacc[dt][r];
      if (lg == 0) {
        mlb[w4 * 32 + la * 2] = mrun;
        mlb[w4 * 32 + la * 2 + 1] = lrun;
      }
    }
    __syncthreads();
    if (grp == 0) {
      const float m1 = mlb[w4 * 32 + la * 2];
      const float l1 = mlb[w4 * 32 + la * 2 + 1];
      const float mm = fmaxf(mrun, m1);
      const float a0 = exp2f(mrun - mm);
      const float a1 = exp2f(m1 - mm);
      const float linv = 1.0f / (lrun * a0 + l1 * a1);
#pragma unroll
      for (int dt = 0; dt < 4; dt++) {
        ushort4 u;
        float o0 = (oacc[dt][0] * a0 + xb[w4 * 1024 + (dt * 16 + lg * 4 + 0) * 16 + la] * a1) * linv;
        float o1 = (oacc[dt][1] * a0 + xb[w4 * 1024 + (dt * 16 + lg * 4 + 1) * 16 + la] * a1) * linv;
        float o2 = (oacc[dt][2] * a0 + xb[w4 * 1024 + (dt * 16 + lg * 4 + 2) * 16 + la] * a1) * linv;
        float o3 = (oacc[dt][3] * a0 + xb[w4 * 1024 + (dt * 16 + lg * 4 + 3) * 16 + la] * a1) * linv;
        u.x = f2bf(o0); u.y = f2bf(o1); u.z = f2bf(o2); u.w = f2bf(o3);
        *reinterpret_cast<ushort4*>(&attn[(size_t)q * HID + h * HD + dt * 16 + lg * 4]) = u;
      }
    }
    __syncthreads();
  }
}

extern "C" void kernel_launch(void* const* d_in, const int* in_sizes, int n_in,
                              void* d_out, int out_size, void* d_ws, size_t ws_size,
                              hipStream_t stream)
{
  const float* x          = (const float*)d_in[0];
  const float* ln1_w      = (const float*)d_in[1];
  const float* ln1_b      = (const float*)d_in[2];
  const float* in_proj_w  = (const float*)d_in[3];
  const float* in_proj_b  = (const float*)d_in[4];
  const float* out_proj_w = (const float*)d_in[5];
  const float* out_proj_b = (const float*)d_in[6];
  const float* ln2_w      = (const float*)d_in[7];
  const float* ln2_b      = (const float*)d_in[8];
  const float* router_w   = (const float*)d_in[9];
  const float* w1         = (const float*)d_in[10];
  const float* w2         = (const float*)d_in[11];
  float* out = (float*)d_out;

  char* ws = (char*)d_ws;
  size_t off = 0;
  auto alloc = [&](size_t bytes) -> void* {
    void* p = ws + off;
    off += (bytes + 255) & ~(size_t)255;
    return p;
  };
  unsigned short* hn_b   = (unsigned short*)alloc((size_t)SL * HID * 2);
  unsigned short* ipw_b  = (unsigned short*)alloc((size_t)3 * HID * HID * 2);
  unsigned short* opw_b  = (unsigned short*)alloc((size_t)HID * HID * 2);
  unsigned short* qb     = (unsigned short*)alloc((size_t)SL * HID * 2);
  unsigned short* kb     = (unsigned short*)alloc((size_t)SL * HID * 2);
  unsigned short* vtb    = (unsigned short*)alloc((size_t)SL * HID * 2);
  unsigned short* attn_b = (unsigned short*)alloc((size_t)SL * HID * 2);
  float*          pbuf   = (float*)alloc((size_t)2 * SL * HID * 4);
  unsigned short* hn2_b  = (unsigned short*)alloc((size_t)SL * HID * 2);
  unsigned short* w1t    = (unsigned short*)alloc((size_t)NEXP * HID * FF * 2);
  unsigned short* w2t    = (unsigned short*)alloc((size_t)NEXP * HID * FF * 2);
  unsigned short* hmidg  = (unsigned short*)alloc((size_t)MAXROWS * FF * 2);
  int*            ti     = (int*)alloc((size_t)SL * 2 * 4);
  float*          tg     = (float*)alloc((size_t)SL * 2 * 4);
  int*            perm   = (int*)alloc((size_t)MAXROWS * 4);
  float*          gateg  = (float*)alloc((size_t)MAXROWS * 4);
  int*            cnt    = (int*)alloc((NEXP + 1) * CPAD * 4);   // +1 line: donecnt
  int*            donecnt = cnt + NEXP * CPAD;
  int*            texp   = (int*)alloc(64 * 4);
  int*            trow   = (int*)alloc(64 * 4);

  const dim3 blk(256);

  hipMemsetAsync(cnt, 0, (NEXP + 1) * CPAD * 4, stream);
  hipMemsetAsync(perm, 0xFF, (size_t)MAXROWS * 4, stream);
  hipMemsetAsync(gateg, 0, (size_t)MAXROWS * 4, stream);

  // fused LayerNorm(ln1) + weight convert + transpose tiles [0,512)
  ln_conv_kernel<<<SL + 1024, blk, 0, stream>>>(
      x, ln1_w, ln1_b, hn_b,
      (const float4*)in_proj_w, (const float4*)out_proj_w,
      (ushort4*)ipw_b, (ushort4*)opw_b,
      w1, w2, w1t, w2t);

  // fused QKV GEMM (z=0) + transpose tiles [512,3200) (z=1..7)
  qkv_trans_kernel<<<dim3(3 * HID / 128, SL / 128, 8), blk, 0, stream>>>(
      hn_b, ipw_b, in_proj_b, qb, kb, vtb, w1, w2, w1t, w2t);

  attn_kernel<<<dim3(16, NHEAD), dim3(512), 0, stream>>>(qb, kb, vtb, attn_b);

  // out-proj split-K x2 (z=0,1) + transpose tiles [3200,4096) (z=2..8)
  gemm_bt2<<<dim3(HID / 128, SL / 128, 9), blk, 0, stream>>>(
      attn_b, opw_b, pbuf, w1, w2, w1t, w2t);

  // fused combine(->out) + LN2 + router + last-block scan/build
  combine_ln<<<SL, blk, 0, stream>>>(
      (const float4*)x, out_proj_b, (const float4*)pbuf,
      (const float4*)(pbuf + (size_t)SL * HID), (float4*)out,
      ln2_w, ln2_b, hn2_b,
      router_w, ti, tg, cnt, donecnt, texp, trow, perm, gateg);

  gemm_moe1<<<dim3(FF / 128, MAXTILE), blk, 0, stream>>>(
      hn2_b, w1t, perm, gateg, texp, trow, hmidg);
  gemm_moe2<<<dim3(HID / 128, MAXTILE, 2), blk, 0, stream>>>(
      hmidg, w2t, perm, texp, trow, out);
}

// Round 24
// 248.991 us; speedup vs baseline: 1.7601x; 1.7601x over previous
//
#include <hip/hip_runtime.h>

#define SL 2048
#define HID 1024
#define NHEAD 16
#define HD 64
#define NEXP 8
#define FF 2048
#define MAXTILE 40
#define MAXROWS (MAXTILE * 128)
#define CPAD 32   /* ints: one 128B line per counter */

typedef short bf16x8 __attribute__((ext_vector_type(8)));
typedef float f32x4 __attribute__((ext_vector_type(4)));
typedef unsigned u32x4 __attribute__((ext_vector_type(4)));

__device__ __forceinline__ unsigned short f2bf(float f) {
  unsigned u = __builtin_bit_cast(unsigned, f);
  u += 0x7fffu + ((u >> 16) & 1u);
  return (unsigned short)(u >> 16);
}

__device__ __forceinline__ void gload16(const void* g, void* l) {
  __builtin_amdgcn_global_load_lds((const __attribute__((address_space(1))) void*)g,
                                   (__attribute__((address_space(3))) void*)l,
                                   16, 0, 0);
}

// XCD-aware remap (bijective when gridDim.x*gridDim.y % 8 == 0).
__device__ __forceinline__ void xcd_remap(int& bx, int& by) {
  const int nx = gridDim.x;
  const int nwg = nx * gridDim.y;
  const int L = by * nx + bx;
  const int per = nwg >> 3;
  const int Lp = (L & 7) * per + (L >> 3);
  bx = Lp % nx;
  by = Lp / nx;
}

// ---- shared scratch for the w1/w2 transpose tiles (49.7 KB) ----
struct TransLds { float Afp[64 * 128]; unsigned Bu[128 * 33]; };

// One 64x128 fp32 tile -> bf16 transposed. 256 threads. Async gload16 staging.
__device__ __forceinline__ void trans_tile(
    int tile, const float* __restrict__ w1, const float* __restrict__ w2,
    unsigned short* __restrict__ w1t, unsigned short* __restrict__ w2t,
    int tid, TransLds* T)
{
  const int m = tile >> 8;          // matrix 0..15
  const int t = tile & 255;
  const float* in;
  unsigned short* out;
  int R, C, r0, c0;
  if (m < 8) {
    in = w1 + (size_t)m * HID * FF;  out = w1t + (size_t)m * HID * FF;
    R = HID; C = FF;  r0 = (t >> 4) * 64;  c0 = (t & 15) * 128;
  } else {
    in = w2 + (size_t)(m - 8) * FF * HID;  out = w2t + (size_t)(m - 8) * FF * HID;
    R = FF; C = HID;  r0 = (t >> 3) * 64;  c0 = (t & 7) * 128;
  }
  const int wv = tid >> 6, ln = tid & 63;
#pragma unroll
  for (int p = 0; p < 8; p++) {
    const int ebase = p * 1024 + wv * 256;
    const int eo = ebase + ln * 4;
    const int r = eo >> 7, c = eo & 127;
    gload16(in + (size_t)(r0 + r) * C + c0 + c, (char*)T->Afp + (size_t)ebase * 4);
  }
  asm volatile("s_waitcnt vmcnt(0)" ::: "memory");
  __syncthreads();
#pragma unroll
  for (int it = 0; it < 16; it++) {
    const int idx = it * 256 + tid;
    const int rp = idx >> 7;
    const int c = idx & 127;
    const float v0 = T->Afp[(2 * rp) * 128 + c];
    const float v1 = T->Afp[(2 * rp + 1) * 128 + c];
    T->Bu[c * 33 + rp] = (unsigned)f2bf(v0) | ((unsigned)f2bf(v1) << 16);
  }
  __syncthreads();
#pragma unroll
  for (int it = 0; it < 8; it++) {
    const int idx = it * 256 + tid;
    const int c = idx >> 4;
    const int r4 = (idx & 15) * 4;
    const unsigned u0 = T->Bu[c * 33 + (r4 >> 1)];
    const unsigned u1 = T->Bu[c * 33 + (r4 >> 1) + 1];
    ushort4 u;
    u.x = (unsigned short)(u0 & 0xffff);
    u.y = (unsigned short)(u0 >> 16);
    u.z = (unsigned short)(u1 & 0xffff);
    u.w = (unsigned short)(u1 >> 16);
    *reinterpret_cast<ushort4*>(&out[(size_t)(c0 + c) * R + r0 + r4]) = u;
  }
}

// ============ 128x128 / BK=32 GEMM, 3-slot depth-2 counted-vmcnt pipeline ==========
#define PIPE_WAIT(i, NT)                                                     \
  if ((i) == (NT) - 1)                                                       \
    asm volatile("s_waitcnt vmcnt(0) lgkmcnt(0)" ::: "memory");              \
  else                                                                       \
    asm volatile("s_waitcnt vmcnt(4) lgkmcnt(0)" ::: "memory");              \
  __builtin_amdgcn_s_barrier();

#define GEMM_FRAGS_MFMA(CC)                                                  \
  bf16x8 af[4], bfr[4];                                                      \
  _Pragma("unroll")                                                          \
  for (int mt = 0; mt < 4; mt++)                                             \
    af[mt] = *reinterpret_cast<const bf16x8*>(                               \
        &Asm[CC][(wm + mt * 16 + la) * 32 + lk]);                            \
  _Pragma("unroll")                                                          \
  for (int nt = 0; nt < 4; nt++)                                             \
    bfr[nt] = *reinterpret_cast<const bf16x8*>(                              \
        &Bsm[CC][(wn + nt * 16 + la) * 32 + lk]);                            \
  __builtin_amdgcn_s_setprio(1);                                             \
  _Pragma("unroll")                                                          \
  for (int mt = 0; mt < 4; mt++)                                             \
    _Pragma("unroll")                                                        \
    for (int nt = 0; nt < 4; nt++)                                           \
      acc[mt][nt] =                                                          \
          __builtin_amdgcn_mfma_f32_16x16x32_bf16(af[mt], bfr[nt], acc[mt][nt], 0, 0, 0); \
  __builtin_amdgcn_s_setprio(0);

#define PIPE_ROT()                                                           \
  cc = (cc == 2) ? 0 : cc + 1;                                               \
  cs = (cs == 2) ? 0 : cs + 1;

// ------- FUSED: z==0 -> QKV GEMM; z=1..7 -> w1/w2 transpose tiles [512,3200) -------
__global__ __launch_bounds__(256) void qkv_trans_kernel(
    const unsigned short* __restrict__ A, const unsigned short* __restrict__ Bt,
    const float* __restrict__ bias,
    unsigned short* __restrict__ q_out, unsigned short* __restrict__ k_out,
    unsigned short* __restrict__ vt_out,
    const float* __restrict__ w1, const float* __restrict__ w2,
    unsigned short* __restrict__ w1t, unsigned short* __restrict__ w2t)
{
  __shared__ union {
    struct { unsigned short A[3][4096]; unsigned short B[3][4096]; } g;   // 48 KB
    TransLds t;                                                           // 49.7 KB
  } sm;
  const int tid = threadIdx.x;

  if (blockIdx.z == 0) {
    unsigned short (*Asm)[4096] = sm.g.A;
    unsigned short (*Bsm)[4096] = sm.g.B;
    int bx = blockIdx.x, by = blockIdx.y;
    xcd_remap(bx, by);
    const int wave = tid >> 6;
    const int lane = tid & 63;
    const int m0 = by * 128;
    const int n0 = bx * 128;
    const int wm = (wave >> 1) * 64;
    const int wn = (wave & 1) * 64;
    const int la = lane & 15;
    const int lk = (lane >> 4) * 8;

    f32x4 acc[4][4] = {};

    const int srow = tid >> 2;
    const int skoff = (tid & 3) * 8;
    const unsigned short* Ag = A + (size_t)(m0 + srow) * HID + skoff;
    const unsigned short* Bg = Bt + (size_t)(n0 + srow) * HID + skoff;

    auto stage = [&](int s, int k0) {
      gload16(Ag + k0, &Asm[s][wave * 512]);
      gload16(Ag + (size_t)64 * HID + k0, &Asm[s][2048 + wave * 512]);
      gload16(Bg + k0, &Bsm[s][wave * 512]);
      gload16(Bg + (size_t)64 * HID + k0, &Bsm[s][2048 + wave * 512]);
    };

    stage(0, 0);
    stage(1, 32);
    const int NT = HID >> 5;
    int cc = 0, cs = 2;
    for (int i = 0; i < NT; ++i) {
      PIPE_WAIT(i, NT)
      if (i + 2 < NT) stage(cs, (i + 2) << 5);
      GEMM_FRAGS_MFMA(cc)
      PIPE_ROT()
    }

    const int lg = lane >> 4;
#pragma unroll
    for (int mt = 0; mt < 4; mt++) {
#pragma unroll
      for (int nt = 0; nt < 4; nt++) {
#pragma unroll
        for (int r = 0; r < 4; r++) {
          const int row = m0 + wm + mt * 16 + lg * 4 + r;
          const int col = n0 + wn + nt * 16 + la;
          float v = acc[mt][nt][r] + bias[col];
          const int hh = (col & 1023) >> 6;
          const int dd = col & 63;
          const unsigned short bv = f2bf(v);
          if (col < 1024)
            q_out[(size_t)hh * SL * HD + (size_t)row * HD + dd] = bv;
          else if (col < 2048)
            k_out[(size_t)hh * SL * HD + (size_t)row * HD + dd] = bv;
          else
            vt_out[(size_t)hh * HD * SL + (size_t)dd * SL + row] = bv;
        }
      }
    }
  } else {
    const int id = blockIdx.y * 24 + blockIdx.x;          // 0..383
    const int tile = 512 + ((int)blockIdx.z - 1) * 384 + id;
    trans_tile(tile, w1, w2, w1t, w2t, tid, &sm.t);
  }
}

// ------- out-proj GEMM (z=0,1: split-K partials) + transpose tiles [3200,4096) -----
__global__ __launch_bounds__(256) void gemm_bt2(
    const unsigned short* __restrict__ A, const unsigned short* __restrict__ Bt,
    float* __restrict__ outf,
    const float* __restrict__ w1, const float* __restrict__ w2,
    unsigned short* __restrict__ w1t, unsigned short* __restrict__ w2t)
{
  __shared__ union {
    struct { unsigned short A[3][4096]; unsigned short B[3][4096]; } g;
    TransLds t;
  } sm;
  const int tid = threadIdx.x;

  if (blockIdx.z >= 2) {
    const int id = blockIdx.y * 8 + blockIdx.x;          // 0..127
    const int tile = 3200 + ((int)blockIdx.z - 2) * 128 + id;
    trans_tile(tile, w1, w2, w1t, w2t, tid, &sm.t);
    return;
  }

  unsigned short (*Asm)[4096] = sm.g.A;
  unsigned short (*Bsm)[4096] = sm.g.B;
  int bx = blockIdx.x, by = blockIdx.y;
  xcd_remap(bx, by);
  const int wave = tid >> 6;
  const int lane = tid & 63;
  const int m0 = by * 128;
  const int n0 = bx * 128;
  const int koff = blockIdx.z * (HID / 2);
  const int wm = (wave >> 1) * 64;
  const int wn = (wave & 1) * 64;
  const int la = lane & 15;
  const int lk = (lane >> 4) * 8;

  f32x4 acc[4][4] = {};

  const int srow = tid >> 2;
  const int skoff = (tid & 3) * 8;
  const unsigned short* Ag = A + (size_t)(m0 + srow) * HID + koff + skoff;
  const unsigned short* Bg = Bt + (size_t)(n0 + srow) * HID + koff + skoff;

  auto stage = [&](int s, int k0) {
    gload16(Ag + k0, &Asm[s][wave * 512]);
    gload16(Ag + (size_t)64 * HID + k0, &Asm[s][2048 + wave * 512]);
    gload16(Bg + k0, &Bsm[s][wave * 512]);
    gload16(Bg + (size_t)64 * HID + k0, &Bsm[s][2048 + wave * 512]);
  };

  stage(0, 0);
  stage(1, 32);
  const int NT = (HID / 2) >> 5;
  int cc = 0, cs = 2;
  for (int i = 0; i < NT; ++i) {
    PIPE_WAIT(i, NT)
    if (i + 2 < NT) stage(cs, (i + 2) << 5);
    GEMM_FRAGS_MFMA(cc)
    PIPE_ROT()
  }

  const int lg = lane >> 4;
#pragma unroll
  for (int mt = 0; mt < 4; mt++) {
#pragma unroll
    for (int nt = 0; nt < 4; nt++) {
#pragma unroll
      for (int r = 0; r < 4; r++) {
        const int row = m0 + wm + mt * 16 + lg * 4 + r;
        const int col = n0 + wn + nt * 16 + la;
        outf[(size_t)blockIdx.z * SL * HID + (size_t)row * HID + col] = acc[mt][nt][r];
      }
    }
  }
}

// ---------------- MoE GEMM1: gathered A, gelu*gate epilogue -> hmidg (bf16) --------
__global__ __launch_bounds__(256) void gemm_moe1(
    const unsigned short* __restrict__ A, const unsigned short* __restrict__ w1t,
    const int* __restrict__ perm, const float* __restrict__ gateg,
    const int* __restrict__ texp, const int* __restrict__ trow,
    unsigned short* __restrict__ hmidg)
{
  __shared__ unsigned short Asm[3][128 * 32];
  __shared__ unsigned short Bsm[3][128 * 32];
  int bx = blockIdx.x, by = blockIdx.y;
  xcd_remap(bx, by);
  const int e = texp[by];
  if (e < 0) return;
  const int row0 = trow[by];
  const int tid = threadIdx.x;
  const int wave = tid >> 6;
  const int lane = tid & 63;
  const int n0 = bx * 128;
  const int wm = (wave >> 1) * 64;
  const int wn = (wave & 1) * 64;
  const int la = lane & 15;
  const int lk = (lane >> 4) * 8;
  f32x4 acc[4][4] = {};

  const int srow = tid >> 2;
  const int skoff = (tid & 3) * 8;
  const int p0 = perm[row0 + srow];
  const int p1 = perm[row0 + 64 + srow];
  const unsigned short* Ag0 = A + (size_t)(p0 < 0 ? 0 : (p0 >> 1)) * HID + skoff;
  const unsigned short* Ag1 = A + (size_t)(p1 < 0 ? 0 : (p1 >> 1)) * HID + skoff;
  const unsigned short* Bg = w1t + (size_t)e * HID * FF + (size_t)(n0 + srow) * HID + skoff;

  auto stage = [&](int s, int k0) {
    gload16(Ag0 + k0, &Asm[s][wave * 512]);
    gload16(Ag1 + k0, &Asm[s][2048 + wave * 512]);
    gload16(Bg + k0, &Bsm[s][wave * 512]);
    gload16(Bg + (size_t)64 * HID + k0, &Bsm[s][2048 + wave * 512]);
  };

  stage(0, 0);
  stage(1, 32);
  const int NT = HID >> 5;
  int cc = 0, cs = 2;
  for (int i = 0; i < NT; ++i) {
    PIPE_WAIT(i, NT)
    if (i + 2 < NT) stage(cs, (i + 2) << 5);
    GEMM_FRAGS_MFMA(cc)
    PIPE_ROT()
  }

  const int lg = lane >> 4;
#pragma unroll
  for (int mt = 0; mt < 4; mt++) {
    float gr[4];
#pragma unroll
    for (int r = 0; r < 4; r++) gr[r] = gateg[row0 + wm + mt * 16 + lg * 4 + r];
#pragma unroll
    for (int nt = 0; nt < 4; nt++) {
#pragma unroll
      for (int r = 0; r < 4; r++) {
        const int grow = row0 + wm + mt * 16 + lg * 4 + r;
        const int col = n0 + wn + nt * 16 + la;
        const float v = acc[mt][nt][r];
        const float g = 0.5f * v * (1.0f + erff(v * 0.70710678118f));
        hmidg[(size_t)grow * FF + col] = f2bf(g * gr[r]);
      }
    }
  }
}

// ------- MoE GEMM2: split-K x2, scatter rows: atomicAdd into out (seeded with x1) --
__global__ __launch_bounds__(256) void gemm_moe2(
    const unsigned short* __restrict__ A, const unsigned short* __restrict__ w2t,
    const int* __restrict__ perm,
    const int* __restrict__ texp, const int* __restrict__ trow,
    float* __restrict__ outbuf)
{
  __shared__ unsigned short Asm[3][128 * 32];
  __shared__ unsigned short Bsm[3][128 * 32];
  int bx = blockIdx.x, by = blockIdx.y;
  xcd_remap(bx, by);
  const int e = texp[by];
  if (e < 0) return;
  const int row0 = trow[by];
  const int tid = threadIdx.x;
  const int wave = tid >> 6;
  const int lane = tid & 63;
  const int n0 = bx * 128;
  const int koff = blockIdx.z * (FF / 2);
  const int wm = (wave >> 1) * 64;
  const int wn = (wave & 1) * 64;
  const int la = lane & 15;
  const int lk = (lane >> 4) * 8;
  f32x4 acc[4][4] = {};

  const int srow = tid >> 2;
  const int skoff = (tid & 3) * 8;
  const unsigned short* Ag = A + (size_t)(row0 + srow) * FF + koff + skoff;
  const unsigned short* Bg = w2t + (size_t)e * FF * HID + (size_t)(n0 + srow) * FF + koff + skoff;

  auto stage = [&](int s, int k0) {
    gload16(Ag + k0, &Asm[s][wave * 512]);
    gload16(Ag + (size_t)64 * FF + k0, &Asm[s][2048 + wave * 512]);
    gload16(Bg + k0, &Bsm[s][wave * 512]);
    gload16(Bg + (size_t)64 * FF + k0, &Bsm[s][2048 + wave * 512]);
  };

  stage(0, 0);
  stage(1, 32);
  const int NT = (FF / 2) >> 5;
  int cc = 0, cs = 2;
  for (int i = 0; i < NT; ++i) {
    PIPE_WAIT(i, NT)
    if (i + 2 < NT) stage(cs, (i + 2) << 5);
    GEMM_FRAGS_MFMA(cc)
    PIPE_ROT()
  }

  const int lg = lane >> 4;
#pragma unroll
  for (int mt = 0; mt < 4; mt++) {
    int pr[4];
#pragma unroll
    for (int r = 0; r < 4; r++) pr[r] = perm[row0 + wm + mt * 16 + lg * 4 + r];
#pragma unroll
    for (int nt = 0; nt < 4; nt++) {
#pragma unroll
      for (int r = 0; r < 4; r++) {
        const int p = pr[r];
        if (p >= 0) {
          const int col = n0 + wn + nt * 16 + la;
          atomicAdd(&outbuf[(size_t)(p >> 1) * HID + col], acc[mt][nt][r]);
        }
      }
    }
  }
}

// FUSED: x<SL -> LayerNorm(ln1); x in [SL,SL+512) -> weight convert;
//        x in [SL+512, SL+1024) -> transpose tiles [0,512)
__global__ __launch_bounds__(256) void ln_conv_kernel(
    const float* __restrict__ x, const float* __restrict__ w, const float* __restrict__ b,
    unsigned short* __restrict__ ob,
    const float4* __restrict__ cva, const float4* __restrict__ cvb,
    ushort4* __restrict__ coa, ushort4* __restrict__ cob,
    const float* __restrict__ w1, const float* __restrict__ w2,
    unsigned short* __restrict__ w1t, unsigned short* __restrict__ w2t)
{
  __shared__ union { struct { float ps[4], pq[4]; } l; TransLds t; } sm;
  const int tid = threadIdx.x;
  if ((int)blockIdx.x < SL) {
    const int row = blockIdx.x;
    const float4 v = *reinterpret_cast<const float4*>(&x[(size_t)row * HID + tid * 4]);
    float s = v.x + v.y + v.z + v.w;
    float q = v.x * v.x + v.y * v.y + v.z * v.z + v.w * v.w;
    for (int off = 32; off > 0; off >>= 1) {
      s += __shfl_down(s, off);
      q += __shfl_down(q, off);
    }
    const int wave = tid >> 6, lane = tid & 63;
    if (lane == 0) { sm.l.ps[wave] = s; sm.l.pq[wave] = q; }
    __syncthreads();
    s = sm.l.ps[0] + sm.l.ps[1] + sm.l.ps[2] + sm.l.ps[3];
    q = sm.l.pq[0] + sm.l.pq[1] + sm.l.pq[2] + sm.l.pq[3];
    const float mu = s * (1.0f / HID);
    const float inv = rsqrtf(q * (1.0f / HID) - mu * mu + 1e-5f);
    const int i = tid * 4;
    const float4 wv = *reinterpret_cast<const float4*>(&w[i]);
    const float4 bv = *reinterpret_cast<const float4*>(&b[i]);
    ushort4 u;
    u.x = f2bf((v.x - mu) * inv * wv.x + bv.x);
    u.y = f2bf((v.y - mu) * inv * wv.y + bv.y);
    u.z = f2bf((v.z - mu) * inv * wv.z + bv.z);
    u.w = f2bf((v.w - mu) * inv * wv.w + bv.w);
    *reinterpret_cast<ushort4*>(&ob[(size_t)row * HID + i]) = u;
  } else if ((int)blockIdx.x < SL + 512) {
    const int NA = 3 * HID * HID / 4, NB = HID * HID / 4;
    for (int i = ((int)blockIdx.x - SL) * 256 + tid; i < NA + NB; i += 512 * 256) {
      if (i < NA) {
        const float4 v = cva[i];
        ushort4 u; u.x = f2bf(v.x); u.y = f2bf(v.y); u.z = f2bf(v.z); u.w = f2bf(v.w);
        coa[i] = u;
      } else {
        const float4 v = cvb[i - NA];
        ushort4 u; u.x = f2bf(v.x); u.y = f2bf(v.y); u.z = f2bf(v.z); u.w = f2bf(v.w);
        cob[i - NA] = u;
      }
    }
  } else {
    const int tile = (int)blockIdx.x - SL - 512;   // 0..511
    trans_tile(tile, w1, w2, w1t, w2t, tid, &sm.t);
  }
}

// ------- fused: out = x + bias + p0 + p1 (residual seed); LN -> hn2_b; ROUTER ------
__global__ __launch_bounds__(256) void combine_ln(
    const float4* __restrict__ x, const float* __restrict__ bias,
    const float4* __restrict__ p0, const float4* __restrict__ p1,
    float4* __restrict__ outbuf,
    const float* __restrict__ w, const float* __restrict__ b,
    unsigned short* __restrict__ ob,
    const float* __restrict__ rw,
    int* __restrict__ ti, float* __restrict__ tg, int* __restrict__ cnt)
{
  __shared__ float ps[4], pq[4];
  __shared__ float rsm[4][8];
  const int row = blockIdx.x;
  const int tid = threadIdx.x;
  const int i4 = row * 256 + tid;
  const int i = tid * 4;
  const float4 bv0 = *reinterpret_cast<const float4*>(&bias[i]);
  const float4 a = x[i4], c = p0[i4], d = p1[i4];
  float4 v;
  v.x = a.x + bv0.x + c.x + d.x;
  v.y = a.y + bv0.y + c.y + d.y;
  v.z = a.z + bv0.z + c.z + d.z;
  v.w = a.w + bv0.w + c.w + d.w;
  outbuf[i4] = v;
  float s = v.x + v.y + v.z + v.w;
  float q = v.x * v.x + v.y * v.y + v.z * v.z + v.w * v.w;
  for (int off = 32; off > 0; off >>= 1) {
    s += __shfl_down(s, off);
    q += __shfl_down(q, off);
  }
  const int wave = tid >> 6, lane = tid & 63;
  if (lane == 0) { ps[wave] = s; pq[wave] = q; }
  __syncthreads();
  s = ps[0] + ps[1] + ps[2] + ps[3];
  q = pq[0] + pq[1] + pq[2] + pq[3];
  const float mu = s * (1.0f / HID);
  const float inv = rsqrtf(q * (1.0f / HID) - mu * mu + 1e-5f);
  const float4 wv = *reinterpret_cast<const float4*>(&w[i]);
  const float4 bv = *reinterpret_cast<const float4*>(&b[i]);
  const float o0 = (v.x - mu) * inv * wv.x + bv.x;
  const float o1 = (v.y - mu) * inv * wv.y + bv.y;
  const float o2 = (v.z - mu) * inv * wv.z + bv.z;
  const float o3 = (v.w - mu) * inv * wv.w + bv.w;
  ushort4 u; u.x = f2bf(o0); u.y = f2bf(o1); u.z = f2bf(o2); u.w = f2bf(o3);
  *reinterpret_cast<ushort4*>(&ob[(size_t)row * HID + i]) = u;

  // ---- fused router: logits[e] = sum_i hn2[i] * rw[e][i] (fp32) ----
  float pl[NEXP];
#pragma unroll
  for (int e = 0; e < NEXP; e++) {
    const float4 rv = *reinterpret_cast<const float4*>(&rw[e * HID + i]);
    pl[e] = o0 * rv.x + o1 * rv.y + o2 * rv.z + o3 * rv.w;
  }
#pragma unroll
  for (int e = 0; e < NEXP; e++) {
    pl[e] += __shfl_xor(pl[e], 32);
    pl[e] += __shfl_xor(pl[e], 16);
    pl[e] += __shfl_xor(pl[e], 8);
    pl[e] += __shfl_xor(pl[e], 4);
    pl[e] += __shfl_xor(pl[e], 2);
    pl[e] += __shfl_xor(pl[e], 1);
  }
  if (lane == 0) {
#pragma unroll
    for (int e = 0; e < NEXP; e++) rsm[wave][e] = pl[e];
  }
  __syncthreads();
  if (tid == 0) {
    float lgt[NEXP];
#pragma unroll
    for (int e = 0; e < NEXP; e++)
      lgt[e] = rsm[0][e] + rsm[1][e] + rsm[2][e] + rsm[3][e];
    float mx = lgt[0];
#pragma unroll
    for (int e = 1; e < NEXP; e++) mx = fmaxf(mx, lgt[e]);
    float Z = 0.f;
    float pexp[NEXP];
#pragma unroll
    for (int e = 0; e < NEXP; e++) { pexp[e] = expf(lgt[e] - mx); Z += pexp[e]; }
    const float invZ = 1.f / Z;
    int i1 = 0;
#pragma unroll
    for (int e = 1; e < NEXP; e++) if (pexp[e] > pexp[i1]) i1 = e;
    int i2 = (i1 == 0) ? 1 : 0;
#pragma unroll
    for (int e = 0; e < NEXP; e++) if (e != i1 && pexp[e] > pexp[i2]) i2 = e;
    ti[2 * row] = i1; ti[2 * row + 1] = i2;
    tg[2 * row] = pexp[i1] * invZ; tg[2 * row + 1] = pexp[i2] * invZ;
    atomicAdd(&cnt[i1 * CPAD], 1);
    atomicAdd(&cnt[i2 * CPAD], 1);
  }
}

// ------- fused scan + build: single block, LDS-atomic fills ----------------
__global__ __launch_bounds__(256) void scan_build_kernel(
    const int* __restrict__ cnt, const int* __restrict__ ti, const float* __restrict__ tg,
    int* __restrict__ texp, int* __restrict__ trow,
    int* __restrict__ perm, float* __restrict__ gateg)
{
  __shared__ int poff[NEXP];
  __shared__ int lfill[NEXP];
  const int tid = threadIdx.x;
  if (tid == 0) {
    int off = 0, nt = 0;
    for (int e = 0; e < NEXP; e++) {
      poff[e] = off;
      const int c = cnt[e * CPAD];
      const int ntl = (c + 127) >> 7;
      for (int i = 0; i < ntl; i++) { texp[nt] = e; trow[nt] = off + i * 128; nt++; }
      off += ntl * 128;
    }
    for (int i = nt; i < MAXTILE; i++) { texp[i] = -1; trow[i] = 0; }
  }
  if (tid < NEXP) lfill[tid] = 0;
  __syncthreads();
  for (int t = tid; t < SL; t += 256) {
#pragma unroll
    for (int s2 = 0; s2 < 2; s2++) {
      const int e = ti[2 * t + s2];
      const int l = atomicAdd(&lfill[e], 1);
      const int pos = poff[e] + l;
      perm[pos] = 2 * t + s2;
      gateg[pos] = tg[2 * t + s2];
    }
  }
}

// ------- flash attention, causal, paired q-tiles, 8 waves = 2 KV-split groups -------
#define SC2 0.1803368801111204f  /* 0.125 * log2(e) */
#define PPITCH 20                /* padded u32 pitch for P rows */
__global__ __launch_bounds__(512) void attn_kernel(
    const unsigned short* __restrict__ qb, const unsigned short* __restrict__ kb,
    const unsigned short* __restrict__ vtb, unsigned short* __restrict__ attn)
{
  const int h = blockIdx.y;
  const int tid = threadIdx.x;
  const int wave = tid >> 6, lane = tid & 63;
  const int grp = wave >> 2;
  const int w4 = wave & 3;
  const int la = lane & 15, lg = lane >> 4;
  const int la7 = la & 7;
  __shared__ unsigned short Kt[2][2][64 * 64];
  __shared__ unsigned short Vt[2][2][64 * 64];
  __shared__ unsigned plds[8 * 32 * PPITCH];
  const unsigned short* qh = qb + (size_t)h * SL * HD;
  const unsigned short* kh = kb + (size_t)h * SL * HD;
  const unsigned short* vh = vtb + (size_t)h * HD * SL;
  unsigned* pu = &plds[wave * 32 * PPITCH];

  const int sr_lo = w4 * 8 + (lane >> 3);
  const int ss = lane & 7;

  auto stageKV = [&](int t, int buf) {
    const int kvb = t * 64;
#pragma unroll
    for (int j = 0; j < 2; j++) {
      const int row = j * 32 + sr_lo;
      const int s = ss ^ (row & 7);
      gload16(kh + (size_t)(kvb + row) * HD + s * 8, &Kt[grp][buf][j * 2048 + w4 * 512]);
      gload16(vh + (size_t)row * SL + kvb + s * 8, &Vt[grp][buf][j * 2048 + w4 * 512]);
    }
  };

  for (int half = 0; half < 2; half++) {
    const int qt = half ? (31 - blockIdx.x) : blockIdx.x;
    const int m0 = qt * 64 + w4 * 16;
    const int T = qt + 1;
    const int S = (T + 1) >> 1;
    const int q = m0 + la;

    bf16x8 aq0 = *reinterpret_cast<const bf16x8*>(&qh[(size_t)(m0 + la) * HD + lg * 8]);
    bf16x8 aq1 = *reinterpret_cast<const bf16x8*>(&qh[(size_t)(m0 + la) * HD + 32 + lg * 8]);

    f32x4 oacc[4] = {};
    float mrun = -1e30f, lrun = 0.f;

    if (grp < T) stageKV(grp, 0);
    __syncthreads();
    int cur = 0;

    for (int s = 0; s < S; s++) {
      const int tmy = 2 * s + grp;
      if (tmy + 2 < T) stageKV(tmy + 2, cur ^ 1);
      if (tmy < T) {
        const int kv0 = tmy * 64;
        const unsigned short* Kb = Kt[grp][cur];
        const unsigned short* Vb = Vt[grp][cur];

        f32x4 sac[4] = {};
        __builtin_amdgcn_s_setprio(1);
#pragma unroll
        for (int nt = 0; nt < 4; nt++) {
          const int row = nt * 16 + la;
          bf16x8 b0 = *reinterpret_cast<const bf16x8*>(&Kb[row * 64 + ((lg ^ la7) << 3)]);
          bf16x8 b1 = *reinterpret_cast<const bf16x8*>(&Kb[row * 64 + (((4 + lg) ^ la7) << 3)]);
          sac[nt] = __builtin_amdgcn_mfma_f32_16x16x32_bf16(b0, aq0, sac[nt], 0, 0, 0);
          sac[nt] = __builtin_amdgcn_mfma_f32_16x16x32_bf16(b1, aq1, sac[nt], 0, 0, 0);
        }
        __builtin_amdgcn_s_setprio(0);
        float sv[4][4];
        const bool diag = (tmy == qt);
#pragma unroll
        for (int nt = 0; nt < 4; nt++)
#pragma unroll
          for (int r = 0; r < 4; r++) {
            float xs = sac[nt][r] * SC2;
            if (diag && (kv0 + nt * 16 + lg * 4 + r) > q) xs = -1e30f;
            sv[nt][r] = xs;
          }
        float pm = fmaxf(fmaxf(sv[0][0], sv[0][1]), fmaxf(sv[0][2], sv[0][3]));
#pragma unroll
        for (int nt = 1; nt < 4; nt++)
          pm = fmaxf(pm, fmaxf(fmaxf(sv[nt][0], sv[nt][1]), fmaxf(sv[nt][2], sv[nt][3])));
        pm = fmaxf(pm, __shfl_xor(pm, 16));
        pm = fmaxf(pm, __shfl_xor(pm, 32));
        const float mn = fmaxf(mrun, pm);
        float rs = 0.f;
#pragma unroll
        for (int nt = 0; nt < 4; nt++)
#pragma unroll
          for (int r = 0; r < 4; r++) {
            const float pe = exp2f(sv[nt][r] - mn);
            sv[nt][r] = pe;
            rs += pe;
          }
        rs += __shfl_xor(rs, 16);
        rs += __shfl_xor(rs, 32);
        if (__ballot(pm > mrun) != 0ULL) {
          const float al = exp2f(mrun - mn);
#pragma unroll
          for (int dt = 0; dt < 4; dt++)
#pragma unroll
            for (int r = 0; r < 4; r++) oacc[dt][r] *= al;
          lrun = lrun * al + rs;
          mrun = mn;
        } else {
          lrun += rs;
        }
#pragma unroll
        for (int nt = 0; nt < 4; nt++)
#pragma unroll
          for (int rp = 0; rp < 2; rp++) {
            unsigned pk;
            asm("v_cvt_pk_bf16_f32 %0, %1, %2"
                : "=v"(pk) : "v"(sv[nt][rp * 2]), "v"(sv[nt][rp * 2 + 1]));
            pu[(nt * 8 + lg * 2 + rp) * PPITCH + la] = pk;
          }
        asm volatile("s_waitcnt lgkmcnt(0)" ::: "memory");
        __builtin_amdgcn_sched_barrier(0);
        u32x4 w0, w1;
#pragma unroll
        for (int jj = 0; jj < 4; jj++) {
          w0[jj] = pu[(lg * 4 + jj) * PPITCH + la];
          w1[jj] = pu[(16 + lg * 4 + jj) * PPITCH + la];
        }
        const bf16x8 pa0 = __builtin_bit_cast(bf16x8, w0);
        const bf16x8 pa1 = __builtin_bit_cast(bf16x8, w1);
        __builtin_amdgcn_s_setprio(1);
#pragma unroll
        for (int dt = 0; dt < 4; dt++) {
          const int row = dt * 16 + la;
          bf16x8 v0 = *reinterpret_cast<const bf16x8*>(&Vb[row * 64 + ((lg ^ la7) << 3)]);
          bf16x8 v1 = *reinterpret_cast<const bf16x8*>(&Vb[row * 64 + (((4 + lg) ^ la7) << 3)]);
          oacc[dt] = __builtin_amdgcn_mfma_f32_16x16x32_bf16(v0, pa0, oacc[dt], 0, 0, 0);
          oacc[dt] = __builtin_amdgcn_mfma_f32_16x16x32_bf16(v1, pa1, oacc[dt], 0, 0, 0);
        }
        __builtin_amdgcn_s_setprio(0);
      }
      __syncthreads();
      cur ^= 1;
    }

    float* xb = (float*)&Kt[0][0][0];
    float* mlb = (float*)&Vt[0][0][0];
    if (grp == 1) {
#pragma unroll
      for (int dt = 0; dt < 4; dt++)
#pragma unroll
        for (int r = 0; r < 4; r++)
          xb[w4 * 1024 + (dt * 16 + lg * 4 + r) * 16 + la] = oacc[dt][r];
      if (lg == 0) {
        mlb[w4 * 32 + la * 2] = mrun;
        mlb[w4 * 32 + la * 2 + 1] = lrun;
      }
    }
    __syncthreads();
    if (grp == 0) {
      const float m1 = mlb[w4 * 32 + la * 2];
      const float l1 = mlb[w4 * 32 + la * 2 + 1];
      const float mm = fmaxf(mrun, m1);
      const float a0 = exp2f(mrun - mm);
      const float a1 = exp2f(m1 - mm);
      const float linv = 1.0f / (lrun * a0 + l1 * a1);
#pragma unroll
      for (int dt = 0; dt < 4; dt++) {
        ushort4 u;
        float o0 = (oacc[dt][0] * a0 + xb[w4 * 1024 + (dt * 16 + lg * 4 + 0) * 16 + la] * a1) * linv;
        float o1 = (oacc[dt][1] * a0 + xb[w4 * 1024 + (dt * 16 + lg * 4 + 1) * 16 + la] * a1) * linv;
        float o2 = (oacc[dt][2] * a0 + xb[w4 * 1024 + (dt * 16 + lg * 4 + 2) * 16 + la] * a1) * linv;
        float o3 = (oacc[dt][3] * a0 + xb[w4 * 1024 + (dt * 16 + lg * 4 + 3) * 16 + la] * a1) * linv;
        u.x = f2bf(o0); u.y = f2bf(o1); u.z = f2bf(o2); u.w = f2bf(o3);
        *reinterpret_cast<ushort4*>(&attn[(size_t)q * HID + h * HD + dt * 16 + lg * 4]) = u;
      }
    }
    __syncthreads();
  }
}

extern "C" void kernel_launch(void* const* d_in, const int* in_sizes, int n_in,
                              void* d_out, int out_size, void* d_ws, size_t ws_size,
                              hipStream_t stream)
{
  const float* x          = (const float*)d_in[0];
  const float* ln1_w      = (const float*)d_in[1];
  const float* ln1_b      = (const float*)d_in[2];
  const float* in_proj_w  = (const float*)d_in[3];
  const float* in_proj_b  = (const float*)d_in[4];
  const float* out_proj_w = (const float*)d_in[5];
  const float* out_proj_b = (const float*)d_in[6];
  const float* ln2_w      = (const float*)d_in[7];
  const float* ln2_b      = (const float*)d_in[8];
  const float* router_w   = (const float*)d_in[9];
  const float* w1         = (const float*)d_in[10];
  const float* w2         = (const float*)d_in[11];
  float* out = (float*)d_out;

  char* ws = (char*)d_ws;
  size_t off = 0;
  auto alloc = [&](size_t bytes) -> void* {
    void* p = ws + off;
    off += (bytes + 255) & ~(size_t)255;
    return p;
  };
  unsigned short* hn_b   = (unsigned short*)alloc((size_t)SL * HID * 2);
  unsigned short* ipw_b  = (unsigned short*)alloc((size_t)3 * HID * HID * 2);
  unsigned short* opw_b  = (unsigned short*)alloc((size_t)HID * HID * 2);
  unsigned short* qb     = (unsigned short*)alloc((size_t)SL * HID * 2);
  unsigned short* kb     = (unsigned short*)alloc((size_t)SL * HID * 2);
  unsigned short* vtb    = (unsigned short*)alloc((size_t)SL * HID * 2);
  unsigned short* attn_b = (unsigned short*)alloc((size_t)SL * HID * 2);
  float*          pbuf   = (float*)alloc((size_t)2 * SL * HID * 4);
  unsigned short* hn2_b  = (unsigned short*)alloc((size_t)SL * HID * 2);
  unsigned short* w1t    = (unsigned short*)alloc((size_t)NEXP * HID * FF * 2);
  unsigned short* w2t    = (unsigned short*)alloc((size_t)NEXP * HID * FF * 2);
  unsigned short* hmidg  = (unsigned short*)alloc((size_t)MAXROWS * FF * 2);
  int*            ti     = (int*)alloc((size_t)SL * 2 * 4);
  float*          tg     = (float*)alloc((size_t)SL * 2 * 4);
  int*            perm   = (int*)alloc((size_t)MAXROWS * 4);
  float*          gateg  = (float*)alloc((size_t)MAXROWS * 4);
  int*            cnt    = (int*)alloc(NEXP * CPAD * 4);
  int*            texp   = (int*)alloc(64 * 4);
  int*            trow   = (int*)alloc(64 * 4);

  const dim3 blk(256);

  hipMemsetAsync(cnt, 0, NEXP * CPAD * 4, stream);
  hipMemsetAsync(perm, 0xFF, (size_t)MAXROWS * 4, stream);
  hipMemsetAsync(gateg, 0, (size_t)MAXROWS * 4, stream);

  // fused LayerNorm(ln1) + weight convert + transpose tiles [0,512)
  ln_conv_kernel<<<SL + 1024, blk, 0, stream>>>(
      x, ln1_w, ln1_b, hn_b,
      (const float4*)in_proj_w, (const float4*)out_proj_w,
      (ushort4*)ipw_b, (ushort4*)opw_b,
      w1, w2, w1t, w2t);

  // fused QKV GEMM (z=0) + transpose tiles [512,3200) (z=1..7)
  qkv_trans_kernel<<<dim3(3 * HID / 128, SL / 128, 8), blk, 0, stream>>>(
      hn_b, ipw_b, in_proj_b, qb, kb, vtb, w1, w2, w1t, w2t);

  attn_kernel<<<dim3(16, NHEAD), dim3(512), 0, stream>>>(qb, kb, vtb, attn_b);

  // out-proj split-K x2 (z=0,1) + transpose tiles [3200,4096) (z=2..8)
  gemm_bt2<<<dim3(HID / 128, SL / 128, 9), blk, 0, stream>>>(
      attn_b, opw_b, pbuf, w1, w2, w1t, w2t);

  // fused combine(->out, residual seed) + LN2 + router
  combine_ln<<<SL, blk, 0, stream>>>(
      (const float4*)x, out_proj_b, (const float4*)pbuf,
      (const float4*)(pbuf + (size_t)SL * HID), (float4*)out,
      ln2_w, ln2_b, hn2_b,
      router_w, ti, tg, cnt);

  scan_build_kernel<<<1, blk, 0, stream>>>(cnt, ti, tg, texp, trow, perm, gateg);

  gemm_moe1<<<dim3(FF / 128, MAXTILE), blk, 0, stream>>>(
      hn2_b, w1t, perm, gateg, texp, trow, hmidg);
  gemm_moe2<<<dim3(HID / 128, MAXTILE, 2), blk, 0, stream>>>(
      hmidg, w2t, perm, texp, trow, out);
}

// Round 25
// 244.668 us; speedup vs baseline: 1.7912x; 1.0177x over previous
//
#include <hip/hip_runtime.h>

#define SL 2048
#define HID 1024
#define NHEAD 16
#define HD 64
#define NEXP 8
#define FF 2048
#define MAXTILE 40
#define MAXROWS (MAXTILE * 128)
#define CPAD 32   /* ints: one 128B line per counter */

typedef short bf16x8 __attribute__((ext_vector_type(8)));
typedef float f32x4 __attribute__((ext_vector_type(4)));
typedef unsigned u32x4 __attribute__((ext_vector_type(4)));

__device__ __forceinline__ unsigned short f2bf(float f) {
  unsigned u = __builtin_bit_cast(unsigned, f);
  u += 0x7fffu + ((u >> 16) & 1u);
  return (unsigned short)(u >> 16);
}

__device__ __forceinline__ void gload16(const void* g, void* l) {
  __builtin_amdgcn_global_load_lds((const __attribute__((address_space(1))) void*)g,
                                   (__attribute__((address_space(3))) void*)l,
                                   16, 0, 0);
}

// XCD-aware remap (bijective when gridDim.x*gridDim.y % 8 == 0).
__device__ __forceinline__ void xcd_remap(int& bx, int& by) {
  const int nx = gridDim.x;
  const int nwg = nx * gridDim.y;
  const int L = by * nx + bx;
  const int per = nwg >> 3;
  const int Lp = (L & 7) * per + (L >> 3);
  bx = Lp % nx;
  by = Lp / nx;
}

// ---- shared scratch for the w1/w2 transpose tiles (49.7 KB) ----
struct TransLds { float Afp[64 * 128]; unsigned Bu[128 * 33]; };

// One 64x128 fp32 tile -> bf16 transposed. 256 threads. Async gload16 staging.
__device__ __forceinline__ void trans_tile(
    int tile, const float* __restrict__ w1, const float* __restrict__ w2,
    unsigned short* __restrict__ w1t, unsigned short* __restrict__ w2t,
    int tid, TransLds* T)
{
  const int m = tile >> 8;          // matrix 0..15
  const int t = tile & 255;
  const float* in;
  unsigned short* out;
  int R, C, r0, c0;
  if (m < 8) {
    in = w1 + (size_t)m * HID * FF;  out = w1t + (size_t)m * HID * FF;
    R = HID; C = FF;  r0 = (t >> 4) * 64;  c0 = (t & 15) * 128;
  } else {
    in = w2 + (size_t)(m - 8) * FF * HID;  out = w2t + (size_t)(m - 8) * FF * HID;
    R = FF; C = HID;  r0 = (t >> 3) * 64;  c0 = (t & 7) * 128;
  }
  const int wv = tid >> 6, ln = tid & 63;
#pragma unroll
  for (int p = 0; p < 8; p++) {
    const int ebase = p * 1024 + wv * 256;
    const int eo = ebase + ln * 4;
    const int r = eo >> 7, c = eo & 127;
    gload16(in + (size_t)(r0 + r) * C + c0 + c, (char*)T->Afp + (size_t)ebase * 4);
  }
  asm volatile("s_waitcnt vmcnt(0)" ::: "memory");
  __syncthreads();
#pragma unroll
  for (int it = 0; it < 16; it++) {
    const int idx = it * 256 + tid;
    const int rp = idx >> 7;
    const int c = idx & 127;
    const float v0 = T->Afp[(2 * rp) * 128 + c];
    const float v1 = T->Afp[(2 * rp + 1) * 128 + c];
    T->Bu[c * 33 + rp] = (unsigned)f2bf(v0) | ((unsigned)f2bf(v1) << 16);
  }
  __syncthreads();
#pragma unroll
  for (int it = 0; it < 8; it++) {
    const int idx = it * 256 + tid;
    const int c = idx >> 4;
    const int r4 = (idx & 15) * 4;
    const unsigned u0 = T->Bu[c * 33 + (r4 >> 1)];
    const unsigned u1 = T->Bu[c * 33 + (r4 >> 1) + 1];
    ushort4 u;
    u.x = (unsigned short)(u0 & 0xffff);
    u.y = (unsigned short)(u0 >> 16);
    u.z = (unsigned short)(u1 & 0xffff);
    u.w = (unsigned short)(u1 >> 16);
    *reinterpret_cast<ushort4*>(&out[(size_t)(c0 + c) * R + r0 + r4]) = u;
  }
}

// ============ 128x128 / BK=32 GEMM, 3-slot depth-2 counted-vmcnt pipeline ==========
#define PIPE_WAIT(i, NT)                                                     \
  if ((i) == (NT) - 1)                                                       \
    asm volatile("s_waitcnt vmcnt(0) lgkmcnt(0)" ::: "memory");              \
  else                                                                       \
    asm volatile("s_waitcnt vmcnt(4) lgkmcnt(0)" ::: "memory");              \
  __builtin_amdgcn_s_barrier();

#define GEMM_FRAGS_MFMA(CC)                                                  \
  bf16x8 af[4], bfr[4];                                                      \
  _Pragma("unroll")                                                          \
  for (int mt = 0; mt < 4; mt++)                                             \
    af[mt] = *reinterpret_cast<const bf16x8*>(                               \
        &Asm[CC][(wm + mt * 16 + la) * 32 + lk]);                            \
  _Pragma("unroll")                                                          \
  for (int nt = 0; nt < 4; nt++)                                             \
    bfr[nt] = *reinterpret_cast<const bf16x8*>(                              \
        &Bsm[CC][(wn + nt * 16 + la) * 32 + lk]);                            \
  __builtin_amdgcn_s_setprio(1);                                             \
  _Pragma("unroll")                                                          \
  for (int mt = 0; mt < 4; mt++)                                             \
    _Pragma("unroll")                                                        \
    for (int nt = 0; nt < 4; nt++)                                           \
      acc[mt][nt] =                                                          \
          __builtin_amdgcn_mfma_f32_16x16x32_bf16(af[mt], bfr[nt], acc[mt][nt], 0, 0, 0); \
  __builtin_amdgcn_s_setprio(0);

#define PIPE_ROT()                                                           \
  cc = (cc == 2) ? 0 : cc + 1;                                               \
  cs = (cs == 2) ? 0 : cs + 1;

// ------- FUSED: z==0 -> QKV GEMM; z=1..7 -> w1/w2 transpose tiles [512,3200) -------
__global__ __launch_bounds__(256) void qkv_trans_kernel(
    const unsigned short* __restrict__ A, const unsigned short* __restrict__ Bt,
    const float* __restrict__ bias,
    unsigned short* __restrict__ q_out, unsigned short* __restrict__ k_out,
    unsigned short* __restrict__ vt_out,
    const float* __restrict__ w1, const float* __restrict__ w2,
    unsigned short* __restrict__ w1t, unsigned short* __restrict__ w2t)
{
  __shared__ union {
    struct { unsigned short A[3][4096]; unsigned short B[3][4096]; } g;   // 48 KB
    TransLds t;                                                           // 49.7 KB
  } sm;
  const int tid = threadIdx.x;

  if (blockIdx.z == 0) {
    unsigned short (*Asm)[4096] = sm.g.A;
    unsigned short (*Bsm)[4096] = sm.g.B;
    int bx = blockIdx.x, by = blockIdx.y;
    xcd_remap(bx, by);
    const int wave = tid >> 6;
    const int lane = tid & 63;
    const int m0 = by * 128;
    const int n0 = bx * 128;
    const int wm = (wave >> 1) * 64;
    const int wn = (wave & 1) * 64;
    const int la = lane & 15;
    const int lk = (lane >> 4) * 8;

    f32x4 acc[4][4] = {};

    const int srow = tid >> 2;
    const int skoff = (tid & 3) * 8;
    const unsigned short* Ag = A + (size_t)(m0 + srow) * HID + skoff;
    const unsigned short* Bg = Bt + (size_t)(n0 + srow) * HID + skoff;

    auto stage = [&](int s, int k0) {
      gload16(Ag + k0, &Asm[s][wave * 512]);
      gload16(Ag + (size_t)64 * HID + k0, &Asm[s][2048 + wave * 512]);
      gload16(Bg + k0, &Bsm[s][wave * 512]);
      gload16(Bg + (size_t)64 * HID + k0, &Bsm[s][2048 + wave * 512]);
    };

    stage(0, 0);
    stage(1, 32);
    const int NT = HID >> 5;
    int cc = 0, cs = 2;
    for (int i = 0; i < NT; ++i) {
      PIPE_WAIT(i, NT)
      if (i + 2 < NT) stage(cs, (i + 2) << 5);
      GEMM_FRAGS_MFMA(cc)
      PIPE_ROT()
    }

    const int lg = lane >> 4;
#pragma unroll
    for (int mt = 0; mt < 4; mt++) {
#pragma unroll
      for (int nt = 0; nt < 4; nt++) {
#pragma unroll
        for (int r = 0; r < 4; r++) {
          const int row = m0 + wm + mt * 16 + lg * 4 + r;
          const int col = n0 + wn + nt * 16 + la;
          float v = acc[mt][nt][r] + bias[col];
          const int hh = (col & 1023) >> 6;
          const int dd = col & 63;
          const unsigned short bv = f2bf(v);
          if (col < 1024)
            q_out[(size_t)hh * SL * HD + (size_t)row * HD + dd] = bv;
          else if (col < 2048)
            k_out[(size_t)hh * SL * HD + (size_t)row * HD + dd] = bv;
          else
            vt_out[(size_t)hh * HD * SL + (size_t)dd * SL + row] = bv;
        }
      }
    }
  } else {
    const int id = blockIdx.y * 24 + blockIdx.x;          // 0..383
    const int tile = 512 + ((int)blockIdx.z - 1) * 384 + id;
    trans_tile(tile, w1, w2, w1t, w2t, tid, &sm.t);
  }
}

// ------- out-proj GEMM (z=0,1: split-K partials) + transpose tiles [3200,4096) -----
__global__ __launch_bounds__(256) void gemm_bt2(
    const unsigned short* __restrict__ A, const unsigned short* __restrict__ Bt,
    float* __restrict__ outf,
    const float* __restrict__ w1, const float* __restrict__ w2,
    unsigned short* __restrict__ w1t, unsigned short* __restrict__ w2t)
{
  __shared__ union {
    struct { unsigned short A[3][4096]; unsigned short B[3][4096]; } g;
    TransLds t;
  } sm;
  const int tid = threadIdx.x;

  if (blockIdx.z >= 2) {
    const int id = blockIdx.y * 8 + blockIdx.x;          // 0..127
    const int tile = 3200 + ((int)blockIdx.z - 2) * 128 + id;
    trans_tile(tile, w1, w2, w1t, w2t, tid, &sm.t);
    return;
  }

  unsigned short (*Asm)[4096] = sm.g.A;
  unsigned short (*Bsm)[4096] = sm.g.B;
  int bx = blockIdx.x, by = blockIdx.y;
  xcd_remap(bx, by);
  const int wave = tid >> 6;
  const int lane = tid & 63;
  const int m0 = by * 128;
  const int n0 = bx * 128;
  const int koff = blockIdx.z * (HID / 2);
  const int wm = (wave >> 1) * 64;
  const int wn = (wave & 1) * 64;
  const int la = lane & 15;
  const int lk = (lane >> 4) * 8;

  f32x4 acc[4][4] = {};

  const int srow = tid >> 2;
  const int skoff = (tid & 3) * 8;
  const unsigned short* Ag = A + (size_t)(m0 + srow) * HID + koff + skoff;
  const unsigned short* Bg = Bt + (size_t)(n0 + srow) * HID + koff + skoff;

  auto stage = [&](int s, int k0) {
    gload16(Ag + k0, &Asm[s][wave * 512]);
    gload16(Ag + (size_t)64 * HID + k0, &Asm[s][2048 + wave * 512]);
    gload16(Bg + k0, &Bsm[s][wave * 512]);
    gload16(Bg + (size_t)64 * HID + k0, &Bsm[s][2048 + wave * 512]);
  };

  stage(0, 0);
  stage(1, 32);
  const int NT = (HID / 2) >> 5;
  int cc = 0, cs = 2;
  for (int i = 0; i < NT; ++i) {
    PIPE_WAIT(i, NT)
    if (i + 2 < NT) stage(cs, (i + 2) << 5);
    GEMM_FRAGS_MFMA(cc)
    PIPE_ROT()
  }

  const int lg = lane >> 4;
#pragma unroll
  for (int mt = 0; mt < 4; mt++) {
#pragma unroll
    for (int nt = 0; nt < 4; nt++) {
#pragma unroll
      for (int r = 0; r < 4; r++) {
        const int row = m0 + wm + mt * 16 + lg * 4 + r;
        const int col = n0 + wn + nt * 16 + la;
        outf[(size_t)blockIdx.z * SL * HID + (size_t)row * HID + col] = acc[mt][nt][r];
      }
    }
  }
}

// ---------------- MoE GEMM1: gathered A, gelu*gate epilogue -> hmidg (bf16) --------
__global__ __launch_bounds__(256) void gemm_moe1(
    const unsigned short* __restrict__ A, const unsigned short* __restrict__ w1t,
    const int* __restrict__ perm, const float* __restrict__ gateg,
    const int* __restrict__ texp, const int* __restrict__ trow,
    unsigned short* __restrict__ hmidg)
{
  __shared__ unsigned short Asm[3][128 * 32];
  __shared__ unsigned short Bsm[3][128 * 32];
  int bx = blockIdx.x, by = blockIdx.y;
  xcd_remap(bx, by);
  const int e = texp[by];
  if (e < 0) return;
  const int row0 = trow[by];
  const int tid = threadIdx.x;
  const int wave = tid >> 6;
  const int lane = tid & 63;
  const int n0 = bx * 128;
  const int wm = (wave >> 1) * 64;
  const int wn = (wave & 1) * 64;
  const int la = lane & 15;
  const int lk = (lane >> 4) * 8;
  f32x4 acc[4][4] = {};

  const int srow = tid >> 2;
  const int skoff = (tid & 3) * 8;
  const int p0 = perm[row0 + srow];
  const int p1 = perm[row0 + 64 + srow];
  const unsigned short* Ag0 = A + (size_t)(p0 < 0 ? 0 : (p0 >> 1)) * HID + skoff;
  const unsigned short* Ag1 = A + (size_t)(p1 < 0 ? 0 : (p1 >> 1)) * HID + skoff;
  const unsigned short* Bg = w1t + (size_t)e * HID * FF + (size_t)(n0 + srow) * HID + skoff;

  auto stage = [&](int s, int k0) {
    gload16(Ag0 + k0, &Asm[s][wave * 512]);
    gload16(Ag1 + k0, &Asm[s][2048 + wave * 512]);
    gload16(Bg + k0, &Bsm[s][wave * 512]);
    gload16(Bg + (size_t)64 * HID + k0, &Bsm[s][2048 + wave * 512]);
  };

  stage(0, 0);
  stage(1, 32);
  const int NT = HID >> 5;
  int cc = 0, cs = 2;
  for (int i = 0; i < NT; ++i) {
    PIPE_WAIT(i, NT)
    if (i + 2 < NT) stage(cs, (i + 2) << 5);
    GEMM_FRAGS_MFMA(cc)
    PIPE_ROT()
  }

  const int lg = lane >> 4;
#pragma unroll
  for (int mt = 0; mt < 4; mt++) {
    float gr[4];
#pragma unroll
    for (int r = 0; r < 4; r++) gr[r] = gateg[row0 + wm + mt * 16 + lg * 4 + r];
#pragma unroll
    for (int nt = 0; nt < 4; nt++) {
#pragma unroll
      for (int r = 0; r < 4; r++) {
        const int grow = row0 + wm + mt * 16 + lg * 4 + r;
        const int col = n0 + wn + nt * 16 + la;
        const float v = acc[mt][nt][r];
        const float g = 0.5f * v * (1.0f + erff(v * 0.70710678118f));
        hmidg[(size_t)grow * FF + col] = f2bf(g * gr[r]);
      }
    }
  }
}

// ------- MoE GEMM2: split-K x2, scatter partial rows -> ybuf[z*2+slot][token] ------
__global__ __launch_bounds__(256) void gemm_moe2(
    const unsigned short* __restrict__ A, const unsigned short* __restrict__ w2t,
    const int* __restrict__ perm,
    const int* __restrict__ texp, const int* __restrict__ trow,
    float* __restrict__ ybuf)
{
  __shared__ unsigned short Asm[3][128 * 32];
  __shared__ unsigned short Bsm[3][128 * 32];
  int bx = blockIdx.x, by = blockIdx.y;
  xcd_remap(bx, by);
  const int e = texp[by];
  if (e < 0) return;
  const int row0 = trow[by];
  const int tid = threadIdx.x;
  const int wave = tid >> 6;
  const int lane = tid & 63;
  const int n0 = bx * 128;
  const int koff = blockIdx.z * (FF / 2);
  const int wm = (wave >> 1) * 64;
  const int wn = (wave & 1) * 64;
  const int la = lane & 15;
  const int lk = (lane >> 4) * 8;
  f32x4 acc[4][4] = {};

  const int srow = tid >> 2;
  const int skoff = (tid & 3) * 8;
  const unsigned short* Ag = A + (size_t)(row0 + srow) * FF + koff + skoff;
  const unsigned short* Bg = w2t + (size_t)e * FF * HID + (size_t)(n0 + srow) * FF + koff + skoff;

  auto stage = [&](int s, int k0) {
    gload16(Ag + k0, &Asm[s][wave * 512]);
    gload16(Ag + (size_t)64 * FF + k0, &Asm[s][2048 + wave * 512]);
    gload16(Bg + k0, &Bsm[s][wave * 512]);
    gload16(Bg + (size_t)64 * FF + k0, &Bsm[s][2048 + wave * 512]);
  };

  stage(0, 0);
  stage(1, 32);
  const int NT = (FF / 2) >> 5;
  int cc = 0, cs = 2;
  for (int i = 0; i < NT; ++i) {
    PIPE_WAIT(i, NT)
    if (i + 2 < NT) stage(cs, (i + 2) << 5);
    GEMM_FRAGS_MFMA(cc)
    PIPE_ROT()
  }

  const int lg = lane >> 4;
#pragma unroll
  for (int mt = 0; mt < 4; mt++) {
    int pr[4];
#pragma unroll
    for (int r = 0; r < 4; r++) pr[r] = perm[row0 + wm + mt * 16 + lg * 4 + r];
#pragma unroll
    for (int nt = 0; nt < 4; nt++) {
#pragma unroll
      for (int r = 0; r < 4; r++) {
        const int p = pr[r];
        if (p >= 0) {
          const int col = n0 + wn + nt * 16 + la;
          ybuf[(size_t)(blockIdx.z * 2 + (p & 1)) * SL * HID + (size_t)(p >> 1) * HID + col] =
              acc[mt][nt][r];
        }
      }
    }
  }
}

// FUSED: x<SL -> LayerNorm(ln1); x in [SL,SL+512) -> weight convert;
//        x in [SL+512, SL+1024) -> transpose tiles [0,512)
__global__ __launch_bounds__(256) void ln_conv_kernel(
    const float* __restrict__ x, const float* __restrict__ w, const float* __restrict__ b,
    unsigned short* __restrict__ ob,
    const float4* __restrict__ cva, const float4* __restrict__ cvb,
    ushort4* __restrict__ coa, ushort4* __restrict__ cob,
    const float* __restrict__ w1, const float* __restrict__ w2,
    unsigned short* __restrict__ w1t, unsigned short* __restrict__ w2t)
{
  __shared__ union { struct { float ps[4], pq[4]; } l; TransLds t; } sm;
  const int tid = threadIdx.x;
  if ((int)blockIdx.x < SL) {
    const int row = blockIdx.x;
    const float4 v = *reinterpret_cast<const float4*>(&x[(size_t)row * HID + tid * 4]);
    float s = v.x + v.y + v.z + v.w;
    float q = v.x * v.x + v.y * v.y + v.z * v.z + v.w * v.w;
    for (int off = 32; off > 0; off >>= 1) {
      s += __shfl_down(s, off);
      q += __shfl_down(q, off);
    }
    const int wave = tid >> 6, lane = tid & 63;
    if (lane == 0) { sm.l.ps[wave] = s; sm.l.pq[wave] = q; }
    __syncthreads();
    s = sm.l.ps[0] + sm.l.ps[1] + sm.l.ps[2] + sm.l.ps[3];
    q = sm.l.pq[0] + sm.l.pq[1] + sm.l.pq[2] + sm.l.pq[3];
    const float mu = s * (1.0f / HID);
    const float inv = rsqrtf(q * (1.0f / HID) - mu * mu + 1e-5f);
    const int i = tid * 4;
    const float4 wv = *reinterpret_cast<const float4*>(&w[i]);
    const float4 bv = *reinterpret_cast<const float4*>(&b[i]);
    ushort4 u;
    u.x = f2bf((v.x - mu) * inv * wv.x + bv.x);
    u.y = f2bf((v.y - mu) * inv * wv.y + bv.y);
    u.z = f2bf((v.z - mu) * inv * wv.z + bv.z);
    u.w = f2bf((v.w - mu) * inv * wv.w + bv.w);
    *reinterpret_cast<ushort4*>(&ob[(size_t)row * HID + i]) = u;
  } else if ((int)blockIdx.x < SL + 512) {
    const int NA = 3 * HID * HID / 4, NB = HID * HID / 4;
    for (int i = ((int)blockIdx.x - SL) * 256 + tid; i < NA + NB; i += 512 * 256) {
      if (i < NA) {
        const float4 v = cva[i];
        ushort4 u; u.x = f2bf(v.x); u.y = f2bf(v.y); u.z = f2bf(v.z); u.w = f2bf(v.w);
        coa[i] = u;
      } else {
        const float4 v = cvb[i - NA];
        ushort4 u; u.x = f2bf(v.x); u.y = f2bf(v.y); u.z = f2bf(v.z); u.w = f2bf(v.w);
        cob[i - NA] = u;
      }
    }
  } else {
    const int tile = (int)blockIdx.x - SL - 512;   // 0..511
    trans_tile(tile, w1, w2, w1t, w2t, tid, &sm.t);
  }
}

// ------- fused: x1 = x + bias + p0 + p1; LN(x1) -> hn2_b; ROUTER (top-2) -----------
__global__ __launch_bounds__(256) void combine_ln(
    const float4* __restrict__ x, const float* __restrict__ bias,
    const float4* __restrict__ p0, const float4* __restrict__ p1,
    float4* __restrict__ x1,
    const float* __restrict__ w, const float* __restrict__ b,
    unsigned short* __restrict__ ob,
    const float* __restrict__ rw,
    int* __restrict__ ti, float* __restrict__ tg, int* __restrict__ cnt)
{
  __shared__ float ps[4], pq[4];
  __shared__ float rsm[4][8];
  const int row = blockIdx.x;
  const int tid = threadIdx.x;
  const int i4 = row * 256 + tid;
  const int i = tid * 4;
  const float4 bv0 = *reinterpret_cast<const float4*>(&bias[i]);
  const float4 a = x[i4], c = p0[i4], d = p1[i4];
  float4 v;
  v.x = a.x + bv0.x + c.x + d.x;
  v.y = a.y + bv0.y + c.y + d.y;
  v.z = a.z + bv0.z + c.z + d.z;
  v.w = a.w + bv0.w + c.w + d.w;
  x1[i4] = v;
  float s = v.x + v.y + v.z + v.w;
  float q = v.x * v.x + v.y * v.y + v.z * v.z + v.w * v.w;
  for (int off = 32; off > 0; off >>= 1) {
    s += __shfl_down(s, off);
    q += __shfl_down(q, off);
  }
  const int wave = tid >> 6, lane = tid & 63;
  if (lane == 0) { ps[wave] = s; pq[wave] = q; }
  __syncthreads();
  s = ps[0] + ps[1] + ps[2] + ps[3];
  q = pq[0] + pq[1] + pq[2] + pq[3];
  const float mu = s * (1.0f / HID);
  const float inv = rsqrtf(q * (1.0f / HID) - mu * mu + 1e-5f);
  const float4 wv = *reinterpret_cast<const float4*>(&w[i]);
  const float4 bv = *reinterpret_cast<const float4*>(&b[i]);
  const float o0 = (v.x - mu) * inv * wv.x + bv.x;
  const float o1 = (v.y - mu) * inv * wv.y + bv.y;
  const float o2 = (v.z - mu) * inv * wv.z + bv.z;
  const float o3 = (v.w - mu) * inv * wv.w + bv.w;
  ushort4 u; u.x = f2bf(o0); u.y = f2bf(o1); u.z = f2bf(o2); u.w = f2bf(o3);
  *reinterpret_cast<ushort4*>(&ob[(size_t)row * HID + i]) = u;

  // ---- fused router: logits[e] = sum_i hn2[i] * rw[e][i] (fp32) ----
  float pl[NEXP];
#pragma unroll
  for (int e = 0; e < NEXP; e++) {
    const float4 rv = *reinterpret_cast<const float4*>(&rw[e * HID + i]);
    pl[e] = o0 * rv.x + o1 * rv.y + o2 * rv.z + o3 * rv.w;
  }
#pragma unroll
  for (int e = 0; e < NEXP; e++) {
    pl[e] += __shfl_xor(pl[e], 32);
    pl[e] += __shfl_xor(pl[e], 16);
    pl[e] += __shfl_xor(pl[e], 8);
    pl[e] += __shfl_xor(pl[e], 4);
    pl[e] += __shfl_xor(pl[e], 2);
    pl[e] += __shfl_xor(pl[e], 1);
  }
  if (lane == 0) {
#pragma unroll
    for (int e = 0; e < NEXP; e++) rsm[wave][e] = pl[e];
  }
  __syncthreads();
  if (tid == 0) {
    float lgt[NEXP];
#pragma unroll
    for (int e = 0; e < NEXP; e++)
      lgt[e] = rsm[0][e] + rsm[1][e] + rsm[2][e] + rsm[3][e];
    float mx = lgt[0];
#pragma unroll
    for (int e = 1; e < NEXP; e++) mx = fmaxf(mx, lgt[e]);
    float Z = 0.f;
    float pexp[NEXP];
#pragma unroll
    for (int e = 0; e < NEXP; e++) { pexp[e] = expf(lgt[e] - mx); Z += pexp[e]; }
    const float invZ = 1.f / Z;
    int i1 = 0;
#pragma unroll
    for (int e = 1; e < NEXP; e++) if (pexp[e] > pexp[i1]) i1 = e;
    int i2 = (i1 == 0) ? 1 : 0;
#pragma unroll
    for (int e = 0; e < NEXP; e++) if (e != i1 && pexp[e] > pexp[i2]) i2 = e;
    ti[2 * row] = i1; ti[2 * row + 1] = i2;
    tg[2 * row] = pexp[i1] * invZ; tg[2 * row + 1] = pexp[i2] * invZ;
    atomicAdd(&cnt[i1 * CPAD], 1);
    atomicAdd(&cnt[i2 * CPAD], 1);
  }
}

// ------- fused scan + build: single block, LDS-atomic fills ----------------
__global__ __launch_bounds__(256) void scan_build_kernel(
    const int* __restrict__ cnt, const int* __restrict__ ti, const float* __restrict__ tg,
    int* __restrict__ texp, int* __restrict__ trow,
    int* __restrict__ perm, float* __restrict__ gateg)
{
  __shared__ int poff[NEXP];
  __shared__ int lfill[NEXP];
  const int tid = threadIdx.x;
  if (tid == 0) {
    int off = 0, nt = 0;
    for (int e = 0; e < NEXP; e++) {
      poff[e] = off;
      const int c = cnt[e * CPAD];
      const int ntl = (c + 127) >> 7;
      for (int i = 0; i < ntl; i++) { texp[nt] = e; trow[nt] = off + i * 128; nt++; }
      off += ntl * 128;
    }
    for (int i = nt; i < MAXTILE; i++) { texp[i] = -1; trow[i] = 0; }
  }
  if (tid < NEXP) lfill[tid] = 0;
  __syncthreads();
  for (int t = tid; t < SL; t += 256) {
#pragma unroll
    for (int s2 = 0; s2 < 2; s2++) {
      const int e = ti[2 * t + s2];
      const int l = atomicAdd(&lfill[e], 1);
      const int pos = poff[e] + l;
      perm[pos] = 2 * t + s2;
      gateg[pos] = tg[2 * t + s2];
    }
  }
}

// ---------------- final: out = x1 + y0 + y1 + y2 + y3 ----------------
__global__ __launch_bounds__(256) void final_add(
    const float4* __restrict__ x1, const float4* __restrict__ y0,
    const float4* __restrict__ y1, const float4* __restrict__ y2,
    const float4* __restrict__ y3, float4* __restrict__ out)
{
  const int i = blockIdx.x * 256 + threadIdx.x;
  const float4 a = x1[i], b = y0[i], c = y1[i], d = y2[i], e = y3[i];
  float4 o;
  o.x = a.x + b.x + c.x + d.x + e.x;
  o.y = a.y + b.y + c.y + d.y + e.y;
  o.z = a.z + b.z + c.z + d.z + e.z;
  o.w = a.w + b.w + c.w + d.w + e.w;
  out[i] = o;
}

// ------- flash attention, causal, paired q-tiles, 8 waves = 2 KV-split groups -------
#define SC2 0.1803368801111204f  /* 0.125 * log2(e) */
#define PPITCH 20                /* padded u32 pitch for P rows */
__global__ __launch_bounds__(512) void attn_kernel(
    const unsigned short* __restrict__ qb, const unsigned short* __restrict__ kb,
    const unsigned short* __restrict__ vtb, unsigned short* __restrict__ attn)
{
  const int h = blockIdx.y;
  const int tid = threadIdx.x;
  const int wave = tid >> 6, lane = tid & 63;
  const int grp = wave >> 2;
  const int w4 = wave & 3;
  const int la = lane & 15, lg = lane >> 4;
  const int la7 = la & 7;
  __shared__ unsigned short Kt[2][2][64 * 64];
  __shared__ unsigned short Vt[2][2][64 * 64];
  __shared__ unsigned plds[8 * 32 * PPITCH];
  const unsigned short* qh = qb + (size_t)h * SL * HD;
  const unsigned short* kh = kb + (size_t)h * SL * HD;
  const unsigned short* vh = vtb + (size_t)h * HD * SL;
  unsigned* pu = &plds[wave * 32 * PPITCH];

  const int sr_lo = w4 * 8 + (lane >> 3);
  const int ss = lane & 7;

  auto stageKV = [&](int t, int buf) {
    const int kvb = t * 64;
#pragma unroll
    for (int j = 0; j < 2; j++) {
      const int row = j * 32 + sr_lo;
      const int s = ss ^ (row & 7);
      gload16(kh + (size_t)(kvb + row) * HD + s * 8, &Kt[grp][buf][j * 2048 + w4 * 512]);
      gload16(vh + (size_t)row * SL + kvb + s * 8, &Vt[grp][buf][j * 2048 + w4 * 512]);
    }
  };

  for (int half = 0; half < 2; half++) {
    const int qt = half ? (31 - blockIdx.x) : blockIdx.x;
    const int m0 = qt * 64 + w4 * 16;
    const int T = qt + 1;
    const int S = (T + 1) >> 1;
    const int q = m0 + la;

    bf16x8 aq0 = *reinterpret_cast<const bf16x8*>(&qh[(size_t)(m0 + la) * HD + lg * 8]);
    bf16x8 aq1 = *reinterpret_cast<const bf16x8*>(&qh[(size_t)(m0 + la) * HD + 32 + lg * 8]);

    f32x4 oacc[4] = {};
    float mrun = -1e30f, lrun = 0.f;

    if (grp < T) stageKV(grp, 0);
    __syncthreads();
    int cur = 0;

    for (int s = 0; s < S; s++) {
      const int tmy = 2 * s + grp;
      if (tmy + 2 < T) stageKV(tmy + 2, cur ^ 1);
      if (tmy < T) {
        const int kv0 = tmy * 64;
        const unsigned short* Kb = Kt[grp][cur];
        const unsigned short* Vb = Vt[grp][cur];

        f32x4 sac[4] = {};
        __builtin_amdgcn_s_setprio(1);
#pragma unroll
        for (int nt = 0; nt < 4; nt++) {
          const int row = nt * 16 + la;
          bf16x8 b0 = *reinterpret_cast<const bf16x8*>(&Kb[row * 64 + ((lg ^ la7) << 3)]);
          bf16x8 b1 = *reinterpret_cast<const bf16x8*>(&Kb[row * 64 + (((4 + lg) ^ la7) << 3)]);
          sac[nt] = __builtin_amdgcn_mfma_f32_16x16x32_bf16(b0, aq0, sac[nt], 0, 0, 0);
          sac[nt] = __builtin_amdgcn_mfma_f32_16x16x32_bf16(b1, aq1, sac[nt], 0, 0, 0);
        }
        __builtin_amdgcn_s_setprio(0);
        float sv[4][4];
        const bool diag = (tmy == qt);
#pragma unroll
        for (int nt = 0; nt < 4; nt++)
#pragma unroll
          for (int r = 0; r < 4; r++) {
            float xs = sac[nt][r] * SC2;
            if (diag && (kv0 + nt * 16 + lg * 4 + r) > q) xs = -1e30f;
            sv[nt][r] = xs;
          }
        float pm = fmaxf(fmaxf(sv[0][0], sv[0][1]), fmaxf(sv[0][2], sv[0][3]));
#pragma unroll
        for (int nt = 1; nt < 4; nt++)
          pm = fmaxf(pm, fmaxf(fmaxf(sv[nt][0], sv[nt][1]), fmaxf(sv[nt][2], sv[nt][3])));
        pm = fmaxf(pm, __shfl_xor(pm, 16));
        pm = fmaxf(pm, __shfl_xor(pm, 32));
        const float mn = fmaxf(mrun, pm);
        float rs = 0.f;
#pragma unroll
        for (int nt = 0; nt < 4; nt++)
#pragma unroll
          for (int r = 0; r < 4; r++) {
            const float pe = exp2f(sv[nt][r] - mn);
            sv[nt][r] = pe;
            rs += pe;
          }
        rs += __shfl_xor(rs, 16);
        rs += __shfl_xor(rs, 32);
        if (__ballot(pm > mrun) != 0ULL) {
          const float al = exp2f(mrun - mn);
#pragma unroll
          for (int dt = 0; dt < 4; dt++)
#pragma unroll
            for (int r = 0; r < 4; r++) oacc[dt][r] *= al;
          lrun = lrun * al + rs;
          mrun = mn;
        } else {
          lrun += rs;
        }
#pragma unroll
        for (int nt = 0; nt < 4; nt++)
#pragma unroll
          for (int rp = 0; rp < 2; rp++) {
            unsigned pk;
            asm("v_cvt_pk_bf16_f32 %0, %1, %2"
                : "=v"(pk) : "v"(sv[nt][rp * 2]), "v"(sv[nt][rp * 2 + 1]));
            pu[(nt * 8 + lg * 2 + rp) * PPITCH + la] = pk;
          }
        asm volatile("s_waitcnt lgkmcnt(0)" ::: "memory");
        __builtin_amdgcn_sched_barrier(0);
        u32x4 w0, w1;
#pragma unroll
        for (int jj = 0; jj < 4; jj++) {
          w0[jj] = pu[(lg * 4 + jj) * PPITCH + la];
          w1[jj] = pu[(16 + lg * 4 + jj) * PPITCH + la];
        }
        const bf16x8 pa0 = __builtin_bit_cast(bf16x8, w0);
        const bf16x8 pa1 = __builtin_bit_cast(bf16x8, w1);
        __builtin_amdgcn_s_setprio(1);
#pragma unroll
        for (int dt = 0; dt < 4; dt++) {
          const int row = dt * 16 + la;
          bf16x8 v0 = *reinterpret_cast<const bf16x8*>(&Vb[row * 64 + ((lg ^ la7) << 3)]);
          bf16x8 v1 = *reinterpret_cast<const bf16x8*>(&Vb[row * 64 + (((4 + lg) ^ la7) << 3)]);
          oacc[dt] = __builtin_amdgcn_mfma_f32_16x16x32_bf16(v0, pa0, oacc[dt], 0, 0, 0);
          oacc[dt] = __builtin_amdgcn_mfma_f32_16x16x32_bf16(v1, pa1, oacc[dt], 0, 0, 0);
        }
        __builtin_amdgcn_s_setprio(0);
      }
      __syncthreads();
      cur ^= 1;
    }

    float* xb = (float*)&Kt[0][0][0];
    float* mlb = (float*)&Vt[0][0][0];
    if (grp == 1) {
#pragma unroll
      for (int dt = 0; dt < 4; dt++)
#pragma unroll
        for (int r = 0; r < 4; r++)
          xb[w4 * 1024 + (dt * 16 + lg * 4 + r) * 16 + la] = oacc[dt][r];
      if (lg == 0) {
        mlb[w4 * 32 + la * 2] = mrun;
        mlb[w4 * 32 + la * 2 + 1] = lrun;
      }
    }
    __syncthreads();
    if (grp == 0) {
      const float m1 = mlb[w4 * 32 + la * 2];
      const float l1 = mlb[w4 * 32 + la * 2 + 1];
      const float mm = fmaxf(mrun, m1);
      const float a0 = exp2f(mrun - mm);
      const float a1 = exp2f(m1 - mm);
      const float linv = 1.0f / (lrun * a0 + l1 * a1);
#pragma unroll
      for (int dt = 0; dt < 4; dt++) {
        ushort4 u;
        float o0 = (oacc[dt][0] * a0 + xb[w4 * 1024 + (dt * 16 + lg * 4 + 0) * 16 + la] * a1) * linv;
        float o1 = (oacc[dt][1] * a0 + xb[w4 * 1024 + (dt * 16 + lg * 4 + 1) * 16 + la] * a1) * linv;
        float o2 = (oacc[dt][2] * a0 + xb[w4 * 1024 + (dt * 16 + lg * 4 + 2) * 16 + la] * a1) * linv;
        float o3 = (oacc[dt][3] * a0 + xb[w4 * 1024 + (dt * 16 + lg * 4 + 3) * 16 + la] * a1) * linv;
        u.x = f2bf(o0); u.y = f2bf(o1); u.z = f2bf(o2); u.w = f2bf(o3);
        *reinterpret_cast<ushort4*>(&attn[(size_t)q * HID + h * HD + dt * 16 + lg * 4]) = u;
      }
    }
    __syncthreads();
  }
}

extern "C" void kernel_launch(void* const* d_in, const int* in_sizes, int n_in,
                              void* d_out, int out_size, void* d_ws, size_t ws_size,
                              hipStream_t stream)
{
  const float* x          = (const float*)d_in[0];
  const float* ln1_w      = (const float*)d_in[1];
  const float* ln1_b      = (const float*)d_in[2];
  const float* in_proj_w  = (const float*)d_in[3];
  const float* in_proj_b  = (const float*)d_in[4];
  const float* out_proj_w = (const float*)d_in[5];
  const float* out_proj_b = (const float*)d_in[6];
  const float* ln2_w      = (const float*)d_in[7];
  const float* ln2_b      = (const float*)d_in[8];
  const float* router_w   = (const float*)d_in[9];
  const float* w1         = (const float*)d_in[10];
  const float* w2         = (const float*)d_in[11];
  float* out = (float*)d_out;

  char* ws = (char*)d_ws;
  size_t off = 0;
  auto alloc = [&](size_t bytes) -> void* {
    void* p = ws + off;
    off += (bytes + 255) & ~(size_t)255;
    return p;
  };
  unsigned short* hn_b   = (unsigned short*)alloc((size_t)SL * HID * 2);
  unsigned short* ipw_b  = (unsigned short*)alloc((size_t)3 * HID * HID * 2);
  unsigned short* opw_b  = (unsigned short*)alloc((size_t)HID * HID * 2);
  unsigned short* qb     = (unsigned short*)alloc((size_t)SL * HID * 2);
  unsigned short* kb     = (unsigned short*)alloc((size_t)SL * HID * 2);
  unsigned short* vtb    = (unsigned short*)alloc((size_t)SL * HID * 2);
  unsigned short* attn_b = (unsigned short*)alloc((size_t)SL * HID * 2);
  float*          x1     = (float*)alloc((size_t)SL * HID * 4);
  float*          pbuf   = (float*)alloc((size_t)2 * SL * HID * 4);
  unsigned short* hn2_b  = (unsigned short*)alloc((size_t)SL * HID * 2);
  unsigned short* w1t    = (unsigned short*)alloc((size_t)NEXP * HID * FF * 2);
  unsigned short* w2t    = (unsigned short*)alloc((size_t)NEXP * HID * FF * 2);
  unsigned short* hmidg  = (unsigned short*)alloc((size_t)MAXROWS * FF * 2);
  float*          ybuf   = (float*)alloc((size_t)4 * SL * HID * 4);
  int*            ti     = (int*)alloc((size_t)SL * 2 * 4);
  float*          tg     = (float*)alloc((size_t)SL * 2 * 4);
  int*            perm   = (int*)alloc((size_t)MAXROWS * 4);
  float*          gateg  = (float*)alloc((size_t)MAXROWS * 4);
  int*            cnt    = (int*)alloc(NEXP * CPAD * 4);
  int*            poff   = (int*)alloc(64 * 4);
  int*            texp   = (int*)alloc(64 * 4);
  int*            trow   = (int*)alloc(64 * 4);
  (void)poff;

  const dim3 blk(256);

  hipMemsetAsync(cnt, 0, NEXP * CPAD * 4, stream);
  hipMemsetAsync(perm, 0xFF, (size_t)MAXROWS * 4, stream);
  hipMemsetAsync(gateg, 0, (size_t)MAXROWS * 4, stream);

  // fused LayerNorm(ln1) + weight convert + transpose tiles [0,512)
  ln_conv_kernel<<<SL + 1024, blk, 0, stream>>>(
      x, ln1_w, ln1_b, hn_b,
      (const float4*)in_proj_w, (const float4*)out_proj_w,
      (ushort4*)ipw_b, (ushort4*)opw_b,
      w1, w2, w1t, w2t);

  // fused QKV GEMM (z=0) + transpose tiles [512,3200) (z=1..7)
  qkv_trans_kernel<<<dim3(3 * HID / 128, SL / 128, 8), blk, 0, stream>>>(
      hn_b, ipw_b, in_proj_b, qb, kb, vtb, w1, w2, w1t, w2t);

  attn_kernel<<<dim3(16, NHEAD), dim3(512), 0, stream>>>(qb, kb, vtb, attn_b);

  // out-proj split-K x2 (z=0,1) + transpose tiles [3200,4096) (z=2..8)
  gemm_bt2<<<dim3(HID / 128, SL / 128, 9), blk, 0, stream>>>(
      attn_b, opw_b, pbuf, w1, w2, w1t, w2t);

  // fused combine + LN2 + router
  combine_ln<<<SL, blk, 0, stream>>>(
      (const float4*)x, out_proj_b, (const float4*)pbuf,
      (const float4*)(pbuf + (size_t)SL * HID), (float4*)x1,
      ln2_w, ln2_b, hn2_b,
      router_w, ti, tg, cnt);

  scan_build_kernel<<<1, blk, 0, stream>>>(cnt, ti, tg, texp, trow, perm, gateg);

  gemm_moe1<<<dim3(FF / 128, MAXTILE), blk, 0, stream>>>(
      hn2_b, w1t, perm, gateg, texp, trow, hmidg);
  gemm_moe2<<<dim3(HID / 128, MAXTILE, 2), blk, 0, stream>>>(
      hmidg, w2t, perm, texp, trow, ybuf);

  final_add<<<SL * HID / 1024, blk, 0, stream>>>(
      (const float4*)x1, (const float4*)ybuf,
      (const float4*)(ybuf + (size_t)SL * HID),
      (const float4*)(ybuf + (size_t)2 * SL * HID),
      (const float4*)(ybuf + (size_t)3 * SL * HID),
      (float4*)out);
}

// Round 26
// 234.702 us; speedup vs baseline: 1.8672x; 1.0425x over previous
//
#include <hip/hip_runtime.h>

#define SL 2048
#define HID 1024
#define NHEAD 16
#define HD 64
#define NEXP 8
#define FF 2048
#define MAXTILE 40
#define MAXROWS (MAXTILE * 128)
#define CPAD 32   /* ints: one 128B line per counter */

typedef short bf16x8 __attribute__((ext_vector_type(8)));
typedef float f32x4 __attribute__((ext_vector_type(4)));
typedef unsigned u32x4 __attribute__((ext_vector_type(4)));

__device__ __forceinline__ unsigned short f2bf(float f) {
  unsigned u = __builtin_bit_cast(unsigned, f);
  u += 0x7fffu + ((u >> 16) & 1u);
  return (unsigned short)(u >> 16);
}

__device__ __forceinline__ void gload16(const void* g, void* l) {
  __builtin_amdgcn_global_load_lds((const __attribute__((address_space(1))) void*)g,
                                   (__attribute__((address_space(3))) void*)l,
                                   16, 0, 0);
}

// XCD-aware remap (bijective when gridDim.x*gridDim.y % 8 == 0).
__device__ __forceinline__ void xcd_remap(int& bx, int& by) {
  const int nx = gridDim.x;
  const int nwg = nx * gridDim.y;
  const int L = by * nx + bx;
  const int per = nwg >> 3;
  const int Lp = (L & 7) * per + (L >> 3);
  bx = Lp % nx;
  by = Lp / nx;
}

// ---- shared scratch for the w1/w2 transpose tiles (49.7 KB) ----
struct TransLds { float Afp[64 * 128]; unsigned Bu[128 * 33]; };

// Tile geometry shared by both trans_tile variants.
__device__ __forceinline__ void trans_geom(
    int tile, const float* __restrict__ w1, const float* __restrict__ w2,
    unsigned short* __restrict__ w1t, unsigned short* __restrict__ w2t,
    const float*& in, unsigned short*& out, int& R, int& C, int& r0, int& c0)
{
  const int m = tile >> 8;          // matrix 0..15
  const int t = tile & 255;
  if (m < 8) {
    in = w1 + (size_t)m * HID * FF;  out = w1t + (size_t)m * HID * FF;
    R = HID; C = FF;  r0 = (t >> 4) * 64;  c0 = (t & 15) * 128;
  } else {
    in = w2 + (size_t)(m - 8) * FF * HID;  out = w2t + (size_t)(m - 8) * FF * HID;
    R = FF; C = HID;  r0 = (t >> 3) * 64;  c0 = (t & 7) * 128;
  }
}

// One 64x128 fp32 tile -> bf16 transposed. 256 threads. Async gload16 staging.
__device__ __forceinline__ void trans_tile(
    int tile, const float* __restrict__ w1, const float* __restrict__ w2,
    unsigned short* __restrict__ w1t, unsigned short* __restrict__ w2t,
    int tid, TransLds* T)
{
  const float* in; unsigned short* out; int R, C, r0, c0;
  trans_geom(tile, w1, w2, w1t, w2t, in, out, R, C, r0, c0);
  const int wv = tid >> 6, ln = tid & 63;
#pragma unroll
  for (int p = 0; p < 8; p++) {
    const int ebase = p * 1024 + wv * 256;
    const int eo = ebase + ln * 4;
    const int r = eo >> 7, c = eo & 127;
    gload16(in + (size_t)(r0 + r) * C + c0 + c, (char*)T->Afp + (size_t)ebase * 4);
  }
  asm volatile("s_waitcnt vmcnt(0)" ::: "memory");
  __syncthreads();
#pragma unroll
  for (int it = 0; it < 16; it++) {
    const int idx = it * 256 + tid;
    const int rp = idx >> 7;
    const int c = idx & 127;
    const float v0 = T->Afp[(2 * rp) * 128 + c];
    const float v1 = T->Afp[(2 * rp + 1) * 128 + c];
    T->Bu[c * 33 + rp] = (unsigned)f2bf(v0) | ((unsigned)f2bf(v1) << 16);
  }
  __syncthreads();
#pragma unroll
  for (int it = 0; it < 8; it++) {
    const int idx = it * 256 + tid;
    const int c = idx >> 4;
    const int r4 = (idx & 15) * 4;
    const unsigned u0 = T->Bu[c * 33 + (r4 >> 1)];
    const unsigned u1 = T->Bu[c * 33 + (r4 >> 1) + 1];
    ushort4 u;
    u.x = (unsigned short)(u0 & 0xffff);
    u.y = (unsigned short)(u0 >> 16);
    u.z = (unsigned short)(u1 & 0xffff);
    u.w = (unsigned short)(u1 >> 16);
    *reinterpret_cast<ushort4*>(&out[(size_t)(c0 + c) * R + r0 + r4]) = u;
  }
}

// Same tile, 512 threads (hosted in the attention launch).
__device__ __forceinline__ void trans_tile512(
    int tile, const float* __restrict__ w1, const float* __restrict__ w2,
    unsigned short* __restrict__ w1t, unsigned short* __restrict__ w2t,
    int tid, TransLds* T)
{
  const float* in; unsigned short* out; int R, C, r0, c0;
  trans_geom(tile, w1, w2, w1t, w2t, in, out, R, C, r0, c0);
  const int wv = tid >> 6, ln = tid & 63;   // wv in [0,8)
#pragma unroll
  for (int p = 0; p < 4; p++) {
    const int ebase = p * 2048 + wv * 256;
    const int eo = ebase + ln * 4;
    const int r = eo >> 7, c = eo & 127;
    gload16(in + (size_t)(r0 + r) * C + c0 + c, (char*)T->Afp + (size_t)ebase * 4);
  }
  asm volatile("s_waitcnt vmcnt(0)" ::: "memory");
  __syncthreads();
#pragma unroll
  for (int it = 0; it < 8; it++) {
    const int idx = it * 512 + tid;
    const int rp = idx >> 7;
    const int c = idx & 127;
    const float v0 = T->Afp[(2 * rp) * 128 + c];
    const float v1 = T->Afp[(2 * rp + 1) * 128 + c];
    T->Bu[c * 33 + rp] = (unsigned)f2bf(v0) | ((unsigned)f2bf(v1) << 16);
  }
  __syncthreads();
#pragma unroll
  for (int it = 0; it < 4; it++) {
    const int idx = it * 512 + tid;
    const int c = idx >> 4;
    const int r4 = (idx & 15) * 4;
    const unsigned u0 = T->Bu[c * 33 + (r4 >> 1)];
    const unsigned u1 = T->Bu[c * 33 + (r4 >> 1) + 1];
    ushort4 u;
    u.x = (unsigned short)(u0 & 0xffff);
    u.y = (unsigned short)(u0 >> 16);
    u.z = (unsigned short)(u1 & 0xffff);
    u.w = (unsigned short)(u1 >> 16);
    *reinterpret_cast<ushort4*>(&out[(size_t)(c0 + c) * R + r0 + r4]) = u;
  }
}

// ============ 128x128 / BK=32 GEMM, 3-slot depth-2 counted-vmcnt pipeline ==========
#define PIPE_WAIT(i, NT)                                                     \
  if ((i) == (NT) - 1)                                                       \
    asm volatile("s_waitcnt vmcnt(0) lgkmcnt(0)" ::: "memory");              \
  else                                                                       \
    asm volatile("s_waitcnt vmcnt(4) lgkmcnt(0)" ::: "memory");              \
  __builtin_amdgcn_s_barrier();

#define GEMM_FRAGS_MFMA(CC)                                                  \
  bf16x8 af[4], bfr[4];                                                      \
  _Pragma("unroll")                                                          \
  for (int mt = 0; mt < 4; mt++)                                             \
    af[mt] = *reinterpret_cast<const bf16x8*>(                               \
        &Asm[CC][(wm + mt * 16 + la) * 32 + lk]);                            \
  _Pragma("unroll")                                                          \
  for (int nt = 0; nt < 4; nt++)                                             \
    bfr[nt] = *reinterpret_cast<const bf16x8*>(                              \
        &Bsm[CC][(wn + nt * 16 + la) * 32 + lk]);                            \
  __builtin_amdgcn_s_setprio(1);                                             \
  _Pragma("unroll")                                                          \
  for (int mt = 0; mt < 4; mt++)                                             \
    _Pragma("unroll")                                                        \
    for (int nt = 0; nt < 4; nt++)                                           \
      acc[mt][nt] =                                                          \
          __builtin_amdgcn_mfma_f32_16x16x32_bf16(af[mt], bfr[nt], acc[mt][nt], 0, 0, 0); \
  __builtin_amdgcn_s_setprio(0);

#define PIPE_ROT()                                                           \
  cc = (cc == 2) ? 0 : cc + 1;                                               \
  cs = (cs == 2) ? 0 : cs + 1;

// ------- FUSED: z==0 -> QKV GEMM; z=1..5 -> w1/w2 transpose tiles [1536,3200) ------
__global__ __launch_bounds__(256) void qkv_trans_kernel(
    const unsigned short* __restrict__ A, const unsigned short* __restrict__ Bt,
    const float* __restrict__ bias,
    unsigned short* __restrict__ q_out, unsigned short* __restrict__ k_out,
    unsigned short* __restrict__ vt_out,
    const float* __restrict__ w1, const float* __restrict__ w2,
    unsigned short* __restrict__ w1t, unsigned short* __restrict__ w2t)
{
  __shared__ union {
    struct { unsigned short A[3][4096]; unsigned short B[3][4096]; } g;   // 48 KB
    TransLds t;                                                           // 49.7 KB
  } sm;
  const int tid = threadIdx.x;

  if (blockIdx.z == 0) {
    unsigned short (*Asm)[4096] = sm.g.A;
    unsigned short (*Bsm)[4096] = sm.g.B;
    int bx = blockIdx.x, by = blockIdx.y;
    xcd_remap(bx, by);
    const int wave = tid >> 6;
    const int lane = tid & 63;
    const int m0 = by * 128;
    const int n0 = bx * 128;
    const int wm = (wave >> 1) * 64;
    const int wn = (wave & 1) * 64;
    const int la = lane & 15;
    const int lk = (lane >> 4) * 8;

    f32x4 acc[4][4] = {};

    const int srow = tid >> 2;
    const int skoff = (tid & 3) * 8;
    const unsigned short* Ag = A + (size_t)(m0 + srow) * HID + skoff;
    const unsigned short* Bg = Bt + (size_t)(n0 + srow) * HID + skoff;

    auto stage = [&](int s, int k0) {
      gload16(Ag + k0, &Asm[s][wave * 512]);
      gload16(Ag + (size_t)64 * HID + k0, &Asm[s][2048 + wave * 512]);
      gload16(Bg + k0, &Bsm[s][wave * 512]);
      gload16(Bg + (size_t)64 * HID + k0, &Bsm[s][2048 + wave * 512]);
    };

    stage(0, 0);
    stage(1, 32);
    const int NT = HID >> 5;
    int cc = 0, cs = 2;
    for (int i = 0; i < NT; ++i) {
      PIPE_WAIT(i, NT)
      if (i + 2 < NT) stage(cs, (i + 2) << 5);
      GEMM_FRAGS_MFMA(cc)
      PIPE_ROT()
    }

    const int lg = lane >> 4;
#pragma unroll
    for (int mt = 0; mt < 4; mt++) {
#pragma unroll
      for (int nt = 0; nt < 4; nt++) {
#pragma unroll
        for (int r = 0; r < 4; r++) {
          const int row = m0 + wm + mt * 16 + lg * 4 + r;
          const int col = n0 + wn + nt * 16 + la;
          float v = acc[mt][nt][r] + bias[col];
          const int hh = (col & 1023) >> 6;
          const int dd = col & 63;
          const unsigned short bv = f2bf(v);
          if (col < 1024)
            q_out[(size_t)hh * SL * HD + (size_t)row * HD + dd] = bv;
          else if (col < 2048)
            k_out[(size_t)hh * SL * HD + (size_t)row * HD + dd] = bv;
          else
            vt_out[(size_t)hh * HD * SL + (size_t)dd * SL + row] = bv;
        }
      }
    }
  } else {
    const int id = blockIdx.y * 24 + blockIdx.x;          // 0..383
    const int tile = 1536 + ((int)blockIdx.z - 1) * 384 + id;
    if (tile >= 3200) return;
    trans_tile(tile, w1, w2, w1t, w2t, tid, &sm.t);
  }
}

// ------- out-proj GEMM (z=0,1: split-K partials) + transpose tiles [3200,4096) -----
__global__ __launch_bounds__(256) void gemm_bt2(
    const unsigned short* __restrict__ A, const unsigned short* __restrict__ Bt,
    float* __restrict__ outf,
    const float* __restrict__ w1, const float* __restrict__ w2,
    unsigned short* __restrict__ w1t, unsigned short* __restrict__ w2t)
{
  __shared__ union {
    struct { unsigned short A[3][4096]; unsigned short B[3][4096]; } g;
    TransLds t;
  } sm;
  const int tid = threadIdx.x;

  if (blockIdx.z >= 2) {
    const int id = blockIdx.y * 8 + blockIdx.x;          // 0..127
    const int tile = 3200 + ((int)blockIdx.z - 2) * 128 + id;
    trans_tile(tile, w1, w2, w1t, w2t, tid, &sm.t);
    return;
  }

  unsigned short (*Asm)[4096] = sm.g.A;
  unsigned short (*Bsm)[4096] = sm.g.B;
  int bx = blockIdx.x, by = blockIdx.y;
  xcd_remap(bx, by);
  const int wave = tid >> 6;
  const int lane = tid & 63;
  const int m0 = by * 128;
  const int n0 = bx * 128;
  const int koff = blockIdx.z * (HID / 2);
  const int wm = (wave >> 1) * 64;
  const int wn = (wave & 1) * 64;
  const int la = lane & 15;
  const int lk = (lane >> 4) * 8;

  f32x4 acc[4][4] = {};

  const int srow = tid >> 2;
  const int skoff = (tid & 3) * 8;
  const unsigned short* Ag = A + (size_t)(m0 + srow) * HID + koff + skoff;
  const unsigned short* Bg = Bt + (size_t)(n0 + srow) * HID + koff + skoff;

  auto stage = [&](int s, int k0) {
    gload16(Ag + k0, &Asm[s][wave * 512]);
    gload16(Ag + (size_t)64 * HID + k0, &Asm[s][2048 + wave * 512]);
    gload16(Bg + k0, &Bsm[s][wave * 512]);
    gload16(Bg + (size_t)64 * HID + k0, &Bsm[s][2048 + wave * 512]);
  };

  stage(0, 0);
  stage(1, 32);
  const int NT = (HID / 2) >> 5;
  int cc = 0, cs = 2;
  for (int i = 0; i < NT; ++i) {
    PIPE_WAIT(i, NT)
    if (i + 2 < NT) stage(cs, (i + 2) << 5);
    GEMM_FRAGS_MFMA(cc)
    PIPE_ROT()
  }

  const int lg = lane >> 4;
#pragma unroll
  for (int mt = 0; mt < 4; mt++) {
#pragma unroll
    for (int nt = 0; nt < 4; nt++) {
#pragma unroll
      for (int r = 0; r < 4; r++) {
        const int row = m0 + wm + mt * 16 + lg * 4 + r;
        const int col = n0 + wn + nt * 16 + la;
        outf[(size_t)blockIdx.z * SL * HID + (size_t)row * HID + col] = acc[mt][nt][r];
      }
    }
  }
}

// ---------------- MoE GEMM1: gathered A, gelu*gate epilogue -> hmidg (bf16) --------
__global__ __launch_bounds__(256) void gemm_moe1(
    const unsigned short* __restrict__ A, const unsigned short* __restrict__ w1t,
    const int* __restrict__ perm, const float* __restrict__ gateg,
    const int* __restrict__ texp, const int* __restrict__ trow,
    unsigned short* __restrict__ hmidg)
{
  __shared__ unsigned short Asm[3][128 * 32];
  __shared__ unsigned short Bsm[3][128 * 32];
  int bx = blockIdx.x, by = blockIdx.y;
  xcd_remap(bx, by);
  const int e = texp[by];
  if (e < 0) return;
  const int row0 = trow[by];
  const int tid = threadIdx.x;
  const int wave = tid >> 6;
  const int lane = tid & 63;
  const int n0 = bx * 128;
  const int wm = (wave >> 1) * 64;
  const int wn = (wave & 1) * 64;
  const int la = lane & 15;
  const int lk = (lane >> 4) * 8;
  f32x4 acc[4][4] = {};

  const int srow = tid >> 2;
  const int skoff = (tid & 3) * 8;
  const int p0 = perm[row0 + srow];
  const int p1 = perm[row0 + 64 + srow];
  const unsigned short* Ag0 = A + (size_t)(p0 < 0 ? 0 : (p0 >> 1)) * HID + skoff;
  const unsigned short* Ag1 = A + (size_t)(p1 < 0 ? 0 : (p1 >> 1)) * HID + skoff;
  const unsigned short* Bg = w1t + (size_t)e * HID * FF + (size_t)(n0 + srow) * HID + skoff;

  auto stage = [&](int s, int k0) {
    gload16(Ag0 + k0, &Asm[s][wave * 512]);
    gload16(Ag1 + k0, &Asm[s][2048 + wave * 512]);
    gload16(Bg + k0, &Bsm[s][wave * 512]);
    gload16(Bg + (size_t)64 * HID + k0, &Bsm[s][2048 + wave * 512]);
  };

  stage(0, 0);
  stage(1, 32);
  const int NT = HID >> 5;
  int cc = 0, cs = 2;
  for (int i = 0; i < NT; ++i) {
    PIPE_WAIT(i, NT)
    if (i + 2 < NT) stage(cs, (i + 2) << 5);
    GEMM_FRAGS_MFMA(cc)
    PIPE_ROT()
  }

  const int lg = lane >> 4;
#pragma unroll
  for (int mt = 0; mt < 4; mt++) {
    float gr[4];
#pragma unroll
    for (int r = 0; r < 4; r++) gr[r] = gateg[row0 + wm + mt * 16 + lg * 4 + r];
#pragma unroll
    for (int nt = 0; nt < 4; nt++) {
#pragma unroll
      for (int r = 0; r < 4; r++) {
        const int grow = row0 + wm + mt * 16 + lg * 4 + r;
        const int col = n0 + wn + nt * 16 + la;
        const float v = acc[mt][nt][r];
        const float g = 0.5f * v * (1.0f + erff(v * 0.70710678118f));
        hmidg[(size_t)grow * FF + col] = f2bf(g * gr[r]);
      }
    }
  }
}

// ------- MoE GEMM2: split-K x2, scatter partial rows -> ybuf[z*2+slot][token] ------
__global__ __launch_bounds__(256) void gemm_moe2(
    const unsigned short* __restrict__ A, const unsigned short* __restrict__ w2t,
    const int* __restrict__ perm,
    const int* __restrict__ texp, const int* __restrict__ trow,
    float* __restrict__ ybuf)
{
  __shared__ unsigned short Asm[3][128 * 32];
  __shared__ unsigned short Bsm[3][128 * 32];
  int bx = blockIdx.x, by = blockIdx.y;
  xcd_remap(bx, by);
  const int e = texp[by];
  if (e < 0) return;
  const int row0 = trow[by];
  const int tid = threadIdx.x;
  const int wave = tid >> 6;
  const int lane = tid & 63;
  const int n0 = bx * 128;
  const int koff = blockIdx.z * (FF / 2);
  const int wm = (wave >> 1) * 64;
  const int wn = (wave & 1) * 64;
  const int la = lane & 15;
  const int lk = (lane >> 4) * 8;
  f32x4 acc[4][4] = {};

  const int srow = tid >> 2;
  const int skoff = (tid & 3) * 8;
  const unsigned short* Ag = A + (size_t)(row0 + srow) * FF + koff + skoff;
  const unsigned short* Bg = w2t + (size_t)e * FF * HID + (size_t)(n0 + srow) * FF + koff + skoff;

  auto stage = [&](int s, int k0) {
    gload16(Ag + k0, &Asm[s][wave * 512]);
    gload16(Ag + (size_t)64 * FF + k0, &Asm[s][2048 + wave * 512]);
    gload16(Bg + k0, &Bsm[s][wave * 512]);
    gload16(Bg + (size_t)64 * FF + k0, &Bsm[s][2048 + wave * 512]);
  };

  stage(0, 0);
  stage(1, 32);
  const int NT = (FF / 2) >> 5;
  int cc = 0, cs = 2;
  for (int i = 0; i < NT; ++i) {
    PIPE_WAIT(i, NT)
    if (i + 2 < NT) stage(cs, (i + 2) << 5);
    GEMM_FRAGS_MFMA(cc)
    PIPE_ROT()
  }

  const int lg = lane >> 4;
#pragma unroll
  for (int mt = 0; mt < 4; mt++) {
    int pr[4];
#pragma unroll
    for (int r = 0; r < 4; r++) pr[r] = perm[row0 + wm + mt * 16 + lg * 4 + r];
#pragma unroll
    for (int nt = 0; nt < 4; nt++) {
#pragma unroll
      for (int r = 0; r < 4; r++) {
        const int p = pr[r];
        if (p >= 0) {
          const int col = n0 + wn + nt * 16 + la;
          ybuf[(size_t)(blockIdx.z * 2 + (p & 1)) * SL * HID + (size_t)(p >> 1) * HID + col] =
              acc[mt][nt][r];
        }
      }
    }
  }
}

// FUSED: x<SL -> LayerNorm(ln1); x in [SL,SL+512) -> weight convert;
//        x in [SL+512, SL+1024) -> transpose tiles [0,512)
__global__ __launch_bounds__(256) void ln_conv_kernel(
    const float* __restrict__ x, const float* __restrict__ w, const float* __restrict__ b,
    unsigned short* __restrict__ ob,
    const float4* __restrict__ cva, const float4* __restrict__ cvb,
    ushort4* __restrict__ coa, ushort4* __restrict__ cob,
    const float* __restrict__ w1, const float* __restrict__ w2,
    unsigned short* __restrict__ w1t, unsigned short* __restrict__ w2t)
{
  __shared__ union { struct { float ps[4], pq[4]; } l; TransLds t; } sm;
  const int tid = threadIdx.x;
  if ((int)blockIdx.x < SL) {
    const int row = blockIdx.x;
    const float4 v = *reinterpret_cast<const float4*>(&x[(size_t)row * HID + tid * 4]);
    float s = v.x + v.y + v.z + v.w;
    float q = v.x * v.x + v.y * v.y + v.z * v.z + v.w * v.w;
    for (int off = 32; off > 0; off >>= 1) {
      s += __shfl_down(s, off);
      q += __shfl_down(q, off);
    }
    const int wave = tid >> 6, lane = tid & 63;
    if (lane == 0) { sm.l.ps[wave] = s; sm.l.pq[wave] = q; }
    __syncthreads();
    s = sm.l.ps[0] + sm.l.ps[1] + sm.l.ps[2] + sm.l.ps[3];
    q = sm.l.pq[0] + sm.l.pq[1] + sm.l.pq[2] + sm.l.pq[3];
    const float mu = s * (1.0f / HID);
    const float inv = rsqrtf(q * (1.0f / HID) - mu * mu + 1e-5f);
    const int i = tid * 4;
    const float4 wv = *reinterpret_cast<const float4*>(&w[i]);
    const float4 bv = *reinterpret_cast<const float4*>(&b[i]);
    ushort4 u;
    u.x = f2bf((v.x - mu) * inv * wv.x + bv.x);
    u.y = f2bf((v.y - mu) * inv * wv.y + bv.y);
    u.z = f2bf((v.z - mu) * inv * wv.z + bv.z);
    u.w = f2bf((v.w - mu) * inv * wv.w + bv.w);
    *reinterpret_cast<ushort4*>(&ob[(size_t)row * HID + i]) = u;
  } else if ((int)blockIdx.x < SL + 512) {
    const int NA = 3 * HID * HID / 4, NB = HID * HID / 4;
    for (int i = ((int)blockIdx.x - SL) * 256 + tid; i < NA + NB; i += 512 * 256) {
      if (i < NA) {
        const float4 v = cva[i];
        ushort4 u; u.x = f2bf(v.x); u.y = f2bf(v.y); u.z = f2bf(v.z); u.w = f2bf(v.w);
        coa[i] = u;
      } else {
        const float4 v = cvb[i - NA];
        ushort4 u; u.x = f2bf(v.x); u.y = f2bf(v.y); u.z = f2bf(v.z); u.w = f2bf(v.w);
        cob[i - NA] = u;
      }
    }
  } else {
    const int tile = (int)blockIdx.x - SL - 512;   // 0..511
    trans_tile(tile, w1, w2, w1t, w2t, tid, &sm.t);
  }
}

// ------- fused: x1 = x + bias + p0 + p1; LN(x1) -> hn2_b; ROUTER (top-2) -----------
__global__ __launch_bounds__(256) void combine_ln(
    const float4* __restrict__ x, const float* __restrict__ bias,
    const float4* __restrict__ p0, const float4* __restrict__ p1,
    float4* __restrict__ x1,
    const float* __restrict__ w, const float* __restrict__ b,
    unsigned short* __restrict__ ob,
    const float* __restrict__ rw,
    int* __restrict__ ti, float* __restrict__ tg, int* __restrict__ cnt)
{
  __shared__ float ps[4], pq[4];
  __shared__ float rsm[4][8];
  const int row = blockIdx.x;
  const int tid = threadIdx.x;
  const int i4 = row * 256 + tid;
  const int i = tid * 4;
  const float4 bv0 = *reinterpret_cast<const float4*>(&bias[i]);
  const float4 a = x[i4], c = p0[i4], d = p1[i4];
  float4 v;
  v.x = a.x + bv0.x + c.x + d.x;
  v.y = a.y + bv0.y + c.y + d.y;
  v.z = a.z + bv0.z + c.z + d.z;
  v.w = a.w + bv0.w + c.w + d.w;
  x1[i4] = v;
  float s = v.x + v.y + v.z + v.w;
  float q = v.x * v.x + v.y * v.y + v.z * v.z + v.w * v.w;
  for (int off = 32; off > 0; off >>= 1) {
    s += __shfl_down(s, off);
    q += __shfl_down(q, off);
  }
  const int wave = tid >> 6, lane = tid & 63;
  if (lane == 0) { ps[wave] = s; pq[wave] = q; }
  __syncthreads();
  s = ps[0] + ps[1] + ps[2] + ps[3];
  q = pq[0] + pq[1] + pq[2] + pq[3];
  const float mu = s * (1.0f / HID);
  const float inv = rsqrtf(q * (1.0f / HID) - mu * mu + 1e-5f);
  const float4 wv = *reinterpret_cast<const float4*>(&w[i]);
  const float4 bv = *reinterpret_cast<const float4*>(&b[i]);
  const float o0 = (v.x - mu) * inv * wv.x + bv.x;
  const float o1 = (v.y - mu) * inv * wv.y + bv.y;
  const float o2 = (v.z - mu) * inv * wv.z + bv.z;
  const float o3 = (v.w - mu) * inv * wv.w + bv.w;
  ushort4 u; u.x = f2bf(o0); u.y = f2bf(o1); u.z = f2bf(o2); u.w = f2bf(o3);
  *reinterpret_cast<ushort4*>(&ob[(size_t)row * HID + i]) = u;

  // ---- fused router: logits[e] = sum_i hn2[i] * rw[e][i] (fp32) ----
  float pl[NEXP];
#pragma unroll
  for (int e = 0; e < NEXP; e++) {
    const float4 rv = *reinterpret_cast<const float4*>(&rw[e * HID + i]);
    pl[e] = o0 * rv.x + o1 * rv.y + o2 * rv.z + o3 * rv.w;
  }
#pragma unroll
  for (int e = 0; e < NEXP; e++) {
    pl[e] += __shfl_xor(pl[e], 32);
    pl[e] += __shfl_xor(pl[e], 16);
    pl[e] += __shfl_xor(pl[e], 8);
    pl[e] += __shfl_xor(pl[e], 4);
    pl[e] += __shfl_xor(pl[e], 2);
    pl[e] += __shfl_xor(pl[e], 1);
  }
  if (lane == 0) {
#pragma unroll
    for (int e = 0; e < NEXP; e++) rsm[wave][e] = pl[e];
  }
  __syncthreads();
  if (tid == 0) {
    float lgt[NEXP];
#pragma unroll
    for (int e = 0; e < NEXP; e++)
      lgt[e] = rsm[0][e] + rsm[1][e] + rsm[2][e] + rsm[3][e];
    float mx = lgt[0];
#pragma unroll
    for (int e = 1; e < NEXP; e++) mx = fmaxf(mx, lgt[e]);
    float Z = 0.f;
    float pexp[NEXP];
#pragma unroll
    for (int e = 0; e < NEXP; e++) { pexp[e] = expf(lgt[e] - mx); Z += pexp[e]; }
    const float invZ = 1.f / Z;
    int i1 = 0;
#pragma unroll
    for (int e = 1; e < NEXP; e++) if (pexp[e] > pexp[i1]) i1 = e;
    int i2 = (i1 == 0) ? 1 : 0;
#pragma unroll
    for (int e = 0; e < NEXP; e++) if (e != i1 && pexp[e] > pexp[i2]) i2 = e;
    ti[2 * row] = i1; ti[2 * row + 1] = i2;
    tg[2 * row] = pexp[i1] * invZ; tg[2 * row + 1] = pexp[i2] * invZ;
    atomicAdd(&cnt[i1 * CPAD], 1);
    atomicAdd(&cnt[i2 * CPAD], 1);
  }
}

// ------- fused scan + build: single block, LDS-atomic fills ----------------
__global__ __launch_bounds__(256) void scan_build_kernel(
    const int* __restrict__ cnt, const int* __restrict__ ti, const float* __restrict__ tg,
    int* __restrict__ texp, int* __restrict__ trow,
    int* __restrict__ perm, float* __restrict__ gateg)
{
  __shared__ int poff[NEXP];
  __shared__ int lfill[NEXP];
  const int tid = threadIdx.x;
  if (tid == 0) {
    int off = 0, nt = 0;
    for (int e = 0; e < NEXP; e++) {
      poff[e] = off;
      const int c = cnt[e * CPAD];
      const int ntl = (c + 127) >> 7;
      for (int i = 0; i < ntl; i++) { texp[nt] = e; trow[nt] = off + i * 128; nt++; }
      off += ntl * 128;
    }
    for (int i = nt; i < MAXTILE; i++) { texp[i] = -1; trow[i] = 0; }
  }
  if (tid < NEXP) lfill[tid] = 0;
  __syncthreads();
  for (int t = tid; t < SL; t += 256) {
#pragma unroll
    for (int s2 = 0; s2 < 2; s2++) {
      const int e = ti[2 * t + s2];
      const int l = atomicAdd(&lfill[e], 1);
      const int pos = poff[e] + l;
      perm[pos] = 2 * t + s2;
      gateg[pos] = tg[2 * t + s2];
    }
  }
}

// ---------------- final: out = x1 + y0 + y1 + y2 + y3 ----------------
__global__ __launch_bounds__(256) void final_add(
    const float4* __restrict__ x1, const float4* __restrict__ y0,
    const float4* __restrict__ y1, const float4* __restrict__ y2,
    const float4* __restrict__ y3, float4* __restrict__ out)
{
  const int i = blockIdx.x * 256 + threadIdx.x;
  const float4 a = x1[i], b = y0[i], c = y1[i], d = y2[i], e = y3[i];
  float4 o;
  o.x = a.x + b.x + c.x + d.x + e.x;
  o.y = a.y + b.y + c.y + d.y + e.y;
  o.z = a.z + b.z + c.z + d.z + e.z;
  o.w = a.w + b.w + c.w + d.w + e.w;
  out[i] = o;
}

// ------- flash attention (z=0), causal, paired q-tiles, 8 waves = 2 KV-split groups;
//         z=1..4 -> w1/w2 transpose tiles [512,1536) (co-resident: 80KB LDS each) ----
#define SC2 0.1803368801111204f  /* 0.125 * log2(e) */
#define PPITCH 16                /* u32 pitch for P rows (16 -> 80KB block, 2/CU) */
__global__ __launch_bounds__(512) void attn_kernel(
    const unsigned short* __restrict__ qb, const unsigned short* __restrict__ kb,
    const unsigned short* __restrict__ vtb, unsigned short* __restrict__ attn,
    const float* __restrict__ w1, const float* __restrict__ w2,
    unsigned short* __restrict__ w1t, unsigned short* __restrict__ w2t)
{
  __shared__ union {
    struct {
      unsigned short Kt[2][2][64 * 64];   // 32 KB
      unsigned short Vt[2][2][64 * 64];   // 32 KB
      unsigned plds[8 * 32 * PPITCH];     // 16 KB
    } a;
    TransLds t;                           // 49.7 KB
  } sm;
  const int tid = threadIdx.x;

  if (blockIdx.z > 0) {
    const int id = blockIdx.y * 16 + blockIdx.x;             // 0..255
    const int tile = 512 + ((int)blockIdx.z - 1) * 256 + id; // [512,1536)
    trans_tile512(tile, w1, w2, w1t, w2t, tid, &sm.t);
    return;
  }

  const int h = blockIdx.y;
  const int wave = tid >> 6, lane = tid & 63;
  const int grp = wave >> 2;
  const int w4 = wave & 3;
  const int la = lane & 15, lg = lane >> 4;
  const int la7 = la & 7;
  const unsigned short* qh = qb + (size_t)h * SL * HD;
  const unsigned short* kh = kb + (size_t)h * SL * HD;
  const unsigned short* vh = vtb + (size_t)h * HD * SL;
  unsigned* pu = &sm.a.plds[wave * 32 * PPITCH];

  const int sr_lo = w4 * 8 + (lane >> 3);
  const int ss = lane & 7;

  auto stageKV = [&](int t, int buf) {
    const int kvb = t * 64;
#pragma unroll
    for (int j = 0; j < 2; j++) {
      const int row = j * 32 + sr_lo;
      const int s = ss ^ (row & 7);
      gload16(kh + (size_t)(kvb + row) * HD + s * 8, &sm.a.Kt[grp][buf][j * 2048 + w4 * 512]);
      gload16(vh + (size_t)row * SL + kvb + s * 8, &sm.a.Vt[grp][buf][j * 2048 + w4 * 512]);
    }
  };

  for (int half = 0; half < 2; half++) {
    const int qt = half ? (31 - blockIdx.x) : blockIdx.x;
    const int m0 = qt * 64 + w4 * 16;
    const int T = qt + 1;
    const int S = (T + 1) >> 1;
    const int q = m0 + la;

    bf16x8 aq0 = *reinterpret_cast<const bf16x8*>(&qh[(size_t)(m0 + la) * HD + lg * 8]);
    bf16x8 aq1 = *reinterpret_cast<const bf16x8*>(&qh[(size_t)(m0 + la) * HD + 32 + lg * 8]);

    f32x4 oacc[4] = {};
    float mrun = -1e30f, lrun = 0.f;

    if (grp < T) stageKV(grp, 0);
    __syncthreads();
    int cur = 0;

    for (int s = 0; s < S; s++) {
      const int tmy = 2 * s + grp;
      if (tmy + 2 < T) stageKV(tmy + 2, cur ^ 1);
      if (tmy < T) {
        const int kv0 = tmy * 64;
        const unsigned short* Kb = sm.a.Kt[grp][cur];
        const unsigned short* Vb = sm.a.Vt[grp][cur];

        f32x4 sac[4] = {};
        __builtin_amdgcn_s_setprio(1);
#pragma unroll
        for (int nt = 0; nt < 4; nt++) {
          const int row = nt * 16 + la;
          bf16x8 b0 = *reinterpret_cast<const bf16x8*>(&Kb[row * 64 + ((lg ^ la7) << 3)]);
          bf16x8 b1 = *reinterpret_cast<const bf16x8*>(&Kb[row * 64 + (((4 + lg) ^ la7) << 3)]);
          sac[nt] = __builtin_amdgcn_mfma_f32_16x16x32_bf16(b0, aq0, sac[nt], 0, 0, 0);
          sac[nt] = __builtin_amdgcn_mfma_f32_16x16x32_bf16(b1, aq1, sac[nt], 0, 0, 0);
        }
        __builtin_amdgcn_s_setprio(0);
        float sv[4][4];
        const bool diag = (tmy == qt);
#pragma unroll
        for (int nt = 0; nt < 4; nt++)
#pragma unroll
          for (int r = 0; r < 4; r++) {
            float xs = sac[nt][r] * SC2;
            if (diag && (kv0 + nt * 16 + lg * 4 + r) > q) xs = -1e30f;
            sv[nt][r] = xs;
          }
        float pm = fmaxf(fmaxf(sv[0][0], sv[0][1]), fmaxf(sv[0][2], sv[0][3]));
#pragma unroll
        for (int nt = 1; nt < 4; nt++)
          pm = fmaxf(pm, fmaxf(fmaxf(sv[nt][0], sv[nt][1]), fmaxf(sv[nt][2], sv[nt][3])));
        pm = fmaxf(pm, __shfl_xor(pm, 16));
        pm = fmaxf(pm, __shfl_xor(pm, 32));
        const float mn = fmaxf(mrun, pm);
        float rs = 0.f;
#pragma unroll
        for (int nt = 0; nt < 4; nt++)
#pragma unroll
          for (int r = 0; r < 4; r++) {
            const float pe = exp2f(sv[nt][r] - mn);
            sv[nt][r] = pe;
            rs += pe;
          }
        rs += __shfl_xor(rs, 16);
        rs += __shfl_xor(rs, 32);
        if (__ballot(pm > mrun) != 0ULL) {
          const float al = exp2f(mrun - mn);
#pragma unroll
          for (int dt = 0; dt < 4; dt++)
#pragma unroll
            for (int r = 0; r < 4; r++) oacc[dt][r] *= al;
          lrun = lrun * al + rs;
          mrun = mn;
        } else {
          lrun += rs;
        }
#pragma unroll
        for (int nt = 0; nt < 4; nt++)
#pragma unroll
          for (int rp = 0; rp < 2; rp++) {
            unsigned pk;
            asm("v_cvt_pk_bf16_f32 %0, %1, %2"
                : "=v"(pk) : "v"(sv[nt][rp * 2]), "v"(sv[nt][rp * 2 + 1]));
            pu[(nt * 8 + lg * 2 + rp) * PPITCH + la] = pk;
          }
        asm volatile("s_waitcnt lgkmcnt(0)" ::: "memory");
        __builtin_amdgcn_sched_barrier(0);
        u32x4 w0, w1v;
#pragma unroll
        for (int jj = 0; jj < 4; jj++) {
          w0[jj] = pu[(lg * 4 + jj) * PPITCH + la];
          w1v[jj] = pu[(16 + lg * 4 + jj) * PPITCH + la];
        }
        const bf16x8 pa0 = __builtin_bit_cast(bf16x8, w0);
        const bf16x8 pa1 = __builtin_bit_cast(bf16x8, w1v);
        __builtin_amdgcn_s_setprio(1);
#pragma unroll
        for (int dt = 0; dt < 4; dt++) {
          const int row = dt * 16 + la;
          bf16x8 v0 = *reinterpret_cast<const bf16x8*>(&Vb[row * 64 + ((lg ^ la7) << 3)]);
          bf16x8 v1 = *reinterpret_cast<const bf16x8*>(&Vb[row * 64 + (((4 + lg) ^ la7) << 3)]);
          oacc[dt] = __builtin_amdgcn_mfma_f32_16x16x32_bf16(v0, pa0, oacc[dt], 0, 0, 0);
          oacc[dt] = __builtin_amdgcn_mfma_f32_16x16x32_bf16(v1, pa1, oacc[dt], 0, 0, 0);
        }
        __builtin_amdgcn_s_setprio(0);
      }
      __syncthreads();
      cur ^= 1;
    }

    float* xb = (float*)&sm.a.Kt[0][0][0];
    float* mlb = (float*)&sm.a.Vt[0][0][0];
    if (grp == 1) {
#pragma unroll
      for (int dt = 0; dt < 4; dt++)
#pragma unroll
        for (int r = 0; r < 4; r++)
          xb[w4 * 1024 + (dt * 16 + lg * 4 + r) * 16 + la] = oacc[dt][r];
      if (lg == 0) {
        mlb[w4 * 32 + la * 2] = mrun;
        mlb[w4 * 32 + la * 2 + 1] = lrun;
      }
    }
    __syncthreads();
    if (grp == 0) {
      const float m1 = mlb[w4 * 32 + la * 2];
      const float l1 = mlb[w4 * 32 + la * 2 + 1];
      const float mm = fmaxf(mrun, m1);
      const float a0 = exp2f(mrun - mm);
      const float a1 = exp2f(m1 - mm);
      const float linv = 1.0f / (lrun * a0 + l1 * a1);
#pragma unroll
      for (int dt = 0; dt < 4; dt++) {
        ushort4 u;
        float o0 = (oacc[dt][0] * a0 + xb[w4 * 1024 + (dt * 16 + lg * 4 + 0) * 16 + la] * a1) * linv;
        float o1 = (oacc[dt][1] * a0 + xb[w4 * 1024 + (dt * 16 + lg * 4 + 1) * 16 + la] * a1) * linv;
        float o2 = (oacc[dt][2] * a0 + xb[w4 * 1024 + (dt * 16 + lg * 4 + 2) * 16 + la] * a1) * linv;
        float o3 = (oacc[dt][3] * a0 + xb[w4 * 1024 + (dt * 16 + lg * 4 + 3) * 16 + la] * a1) * linv;
        u.x = f2bf(o0); u.y = f2bf(o1); u.z = f2bf(o2); u.w = f2bf(o3);
        *reinterpret_cast<ushort4*>(&attn[(size_t)q * HID + h * HD + dt * 16 + lg * 4]) = u;
      }
    }
    __syncthreads();
  }
}

extern "C" void kernel_launch(void* const* d_in, const int* in_sizes, int n_in,
                              void* d_out, int out_size, void* d_ws, size_t ws_size,
                              hipStream_t stream)
{
  const float* x          = (const float*)d_in[0];
  const float* ln1_w      = (const float*)d_in[1];
  const float* ln1_b      = (const float*)d_in[2];
  const float* in_proj_w  = (const float*)d_in[3];
  const float* in_proj_b  = (const float*)d_in[4];
  const float* out_proj_w = (const float*)d_in[5];
  const float* out_proj_b = (const float*)d_in[6];
  const float* ln2_w      = (const float*)d_in[7];
  const float* ln2_b      = (const float*)d_in[8];
  const float* router_w   = (const float*)d_in[9];
  const float* w1         = (const float*)d_in[10];
  const float* w2         = (const float*)d_in[11];
  float* out = (float*)d_out;

  char* ws = (char*)d_ws;
  size_t off = 0;
  auto alloc = [&](size_t bytes) -> void* {
    void* p = ws + off;
    off += (bytes + 255) & ~(size_t)255;
    return p;
  };
  unsigned short* hn_b   = (unsigned short*)alloc((size_t)SL * HID * 2);
  unsigned short* ipw_b  = (unsigned short*)alloc((size_t)3 * HID * HID * 2);
  unsigned short* opw_b  = (unsigned short*)alloc((size_t)HID * HID * 2);
  unsigned short* qb     = (unsigned short*)alloc((size_t)SL * HID * 2);
  unsigned short* kb     = (unsigned short*)alloc((size_t)SL * HID * 2);
  unsigned short* vtb    = (unsigned short*)alloc((size_t)SL * HID * 2);
  unsigned short* attn_b = (unsigned short*)alloc((size_t)SL * HID * 2);
  float*          x1     = (float*)alloc((size_t)SL * HID * 4);
  float*          pbuf   = (float*)alloc((size_t)2 * SL * HID * 4);
  unsigned short* hn2_b  = (unsigned short*)alloc((size_t)SL * HID * 2);
  unsigned short* w1t    = (unsigned short*)alloc((size_t)NEXP * HID * FF * 2);
  unsigned short* w2t    = (unsigned short*)alloc((size_t)NEXP * HID * FF * 2);
  unsigned short* hmidg  = (unsigned short*)alloc((size_t)MAXROWS * FF * 2);
  float*          ybuf   = (float*)alloc((size_t)4 * SL * HID * 4);
  int*            ti     = (int*)alloc((size_t)SL * 2 * 4);
  float*          tg     = (float*)alloc((size_t)SL * 2 * 4);
  int*            perm   = (int*)alloc((size_t)MAXROWS * 4);
  float*          gateg  = (float*)alloc((size_t)MAXROWS * 4);
  int*            cnt    = (int*)alloc(NEXP * CPAD * 4);
  int*            texp   = (int*)alloc(64 * 4);
  int*            trow   = (int*)alloc(64 * 4);

  const dim3 blk(256);

  hipMemsetAsync(cnt, 0, NEXP * CPAD * 4, stream);
  hipMemsetAsync(perm, 0xFF, (size_t)MAXROWS * 4, stream);
  hipMemsetAsync(gateg, 0, (size_t)MAXROWS * 4, stream);

  // fused LayerNorm(ln1) + weight convert + transpose tiles [0,512)
  ln_conv_kernel<<<SL + 1024, blk, 0, stream>>>(
      x, ln1_w, ln1_b, hn_b,
      (const float4*)in_proj_w, (const float4*)out_proj_w,
      (ushort4*)ipw_b, (ushort4*)opw_b,
      w1, w2, w1t, w2t);

  // fused QKV GEMM (z=0) + transpose tiles [1536,3200) (z=1..5, guarded)
  qkv_trans_kernel<<<dim3(3 * HID / 128, SL / 128, 6), blk, 0, stream>>>(
      hn_b, ipw_b, in_proj_b, qb, kb, vtb, w1, w2, w1t, w2t);

  // attn (z=0) + transpose tiles [512,1536) (z=1..4, co-resident at 80KB LDS)
  attn_kernel<<<dim3(16, NHEAD, 5), dim3(512), 0, stream>>>(
      qb, kb, vtb, attn_b, w1, w2, w1t, w2t);

  // out-proj split-K x2 (z=0,1) + transpose tiles [3200,4096) (z=2..8)
  gemm_bt2<<<dim3(HID / 128, SL / 128, 9), blk, 0, stream>>>(
      attn_b, opw_b, pbuf, w1, w2, w1t, w2t);

  // fused combine + LN2 + router
  combine_ln<<<SL, blk, 0, stream>>>(
      (const float4*)x, out_proj_b, (const float4*)pbuf,
      (const float4*)(pbuf + (size_t)SL * HID), (float4*)x1,
      ln2_w, ln2_b, hn2_b,
      router_w, ti, tg, cnt);

  scan_build_kernel<<<1, blk, 0, stream>>>(cnt, ti, tg, texp, trow, perm, gateg);

  gemm_moe1<<<dim3(FF / 128, MAXTILE), blk, 0, stream>>>(
      hn2_b, w1t, perm, gateg, texp, trow, hmidg);
  gemm_moe2<<<dim3(HID / 128, MAXTILE, 2), blk, 0, stream>>>(
      hmidg, w2t, perm, texp, trow, ybuf);

  final_add<<<SL * HID / 1024, blk, 0, stream>>>(
      (const float4*)x1, (const float4*)ybuf,
      (const float4*)(ybuf + (size_t)SL * HID),
      (const float4*)(ybuf + (size_t)2 * SL * HID),
      (const float4*)(ybuf + (size_t)3 * SL * HID),
      (float4*)out);
}

// Round 28
// 234.586 us; speedup vs baseline: 1.8682x; 1.0005x over previous
//
#include <hip/hip_runtime.h>

#define SL 2048
#define HID 1024
#define NHEAD 16
#define HD 64
#define NEXP 8
#define FF 2048
#define MAXTILE 40
#define MAXROWS (MAXTILE * 128)
#define CPAD 32   /* ints: one 128B line per counter */

typedef short bf16x8 __attribute__((ext_vector_type(8)));
typedef float f32x4 __attribute__((ext_vector_type(4)));
typedef unsigned u32x4 __attribute__((ext_vector_type(4)));

__device__ __forceinline__ unsigned short f2bf(float f) {
  unsigned u = __builtin_bit_cast(unsigned, f);
  u += 0x7fffu + ((u >> 16) & 1u);
  return (unsigned short)(u >> 16);
}

__device__ __forceinline__ float bf2f(unsigned short h) {
  return __builtin_bit_cast(float, (unsigned)h << 16);
}

__device__ __forceinline__ void gload16(const void* g, void* l) {
  __builtin_amdgcn_global_load_lds((const __attribute__((address_space(1))) void*)g,
                                   (__attribute__((address_space(3))) void*)l,
                                   16, 0, 0);
}

// XCD-aware remap (bijective when gridDim.x*gridDim.y % 8 == 0).
__device__ __forceinline__ void xcd_remap(int& bx, int& by) {
  const int nx = gridDim.x;
  const int nwg = nx * gridDim.y;
  const int L = by * nx + bx;
  const int per = nwg >> 3;
  const int Lp = (L & 7) * per + (L >> 3);
  bx = Lp % nx;
  by = Lp / nx;
}

// ---- shared scratch for the w1/w2 transpose tiles (49.7 KB) ----
struct TransLds { float Afp[64 * 128]; unsigned Bu[128 * 33]; };

// Tile geometry shared by both trans_tile variants.
__device__ __forceinline__ void trans_geom(
    int tile, const float* __restrict__ w1, const float* __restrict__ w2,
    unsigned short* __restrict__ w1t, unsigned short* __restrict__ w2t,
    const float*& in, unsigned short*& out, int& R, int& C, int& r0, int& c0)
{
  const int m = tile >> 8;          // matrix 0..15
  const int t = tile & 255;
  if (m < 8) {
    in = w1 + (size_t)m * HID * FF;  out = w1t + (size_t)m * HID * FF;
    R = HID; C = FF;  r0 = (t >> 4) * 64;  c0 = (t & 15) * 128;
  } else {
    in = w2 + (size_t)(m - 8) * FF * HID;  out = w2t + (size_t)(m - 8) * FF * HID;
    R = FF; C = HID;  r0 = (t >> 3) * 64;  c0 = (t & 7) * 128;
  }
}

// One 64x128 fp32 tile -> bf16 transposed. 256 threads. Async gload16 staging.
__device__ __forceinline__ void trans_tile(
    int tile, const float* __restrict__ w1, const float* __restrict__ w2,
    unsigned short* __restrict__ w1t, unsigned short* __restrict__ w2t,
    int tid, TransLds* T)
{
  const float* in; unsigned short* out; int R, C, r0, c0;
  trans_geom(tile, w1, w2, w1t, w2t, in, out, R, C, r0, c0);
  const int wv = tid >> 6, ln = tid & 63;
#pragma unroll
  for (int p = 0; p < 8; p++) {
    const int ebase = p * 1024 + wv * 256;
    const int eo = ebase + ln * 4;
    const int r = eo >> 7, c = eo & 127;
    gload16(in + (size_t)(r0 + r) * C + c0 + c, (char*)T->Afp + (size_t)ebase * 4);
  }
  asm volatile("s_waitcnt vmcnt(0)" ::: "memory");
  __syncthreads();
#pragma unroll
  for (int it = 0; it < 16; it++) {
    const int idx = it * 256 + tid;
    const int rp = idx >> 7;
    const int c = idx & 127;
    const float v0 = T->Afp[(2 * rp) * 128 + c];
    const float v1 = T->Afp[(2 * rp + 1) * 128 + c];
    T->Bu[c * 33 + rp] = (unsigned)f2bf(v0) | ((unsigned)f2bf(v1) << 16);
  }
  __syncthreads();
#pragma unroll
  for (int it = 0; it < 8; it++) {
    const int idx = it * 256 + tid;
    const int c = idx >> 4;
    const int r4 = (idx & 15) * 4;
    const unsigned u0 = T->Bu[c * 33 + (r4 >> 1)];
    const unsigned u1 = T->Bu[c * 33 + (r4 >> 1) + 1];
    ushort4 u;
    u.x = (unsigned short)(u0 & 0xffff);
    u.y = (unsigned short)(u0 >> 16);
    u.z = (unsigned short)(u1 & 0xffff);
    u.w = (unsigned short)(u1 >> 16);
    *reinterpret_cast<ushort4*>(&out[(size_t)(c0 + c) * R + r0 + r4]) = u;
  }
}

// Same tile, 512 threads (hosted in the attention launch).
__device__ __forceinline__ void trans_tile512(
    int tile, const float* __restrict__ w1, const float* __restrict__ w2,
    unsigned short* __restrict__ w1t, unsigned short* __restrict__ w2t,
    int tid, TransLds* T)
{
  const float* in; unsigned short* out; int R, C, r0, c0;
  trans_geom(tile, w1, w2, w1t, w2t, in, out, R, C, r0, c0);
  const int wv = tid >> 6, ln = tid & 63;   // wv in [0,8)
#pragma unroll
  for (int p = 0; p < 4; p++) {
    const int ebase = p * 2048 + wv * 256;
    const int eo = ebase + ln * 4;
    const int r = eo >> 7, c = eo & 127;
    gload16(in + (size_t)(r0 + r) * C + c0 + c, (char*)T->Afp + (size_t)ebase * 4);
  }
  asm volatile("s_waitcnt vmcnt(0)" ::: "memory");
  __syncthreads();
#pragma unroll
  for (int it = 0; it < 8; it++) {
    const int idx = it * 512 + tid;
    const int rp = idx >> 7;
    const int c = idx & 127;
    const float v0 = T->Afp[(2 * rp) * 128 + c];
    const float v1 = T->Afp[(2 * rp + 1) * 128 + c];
    T->Bu[c * 33 + rp] = (unsigned)f2bf(v0) | ((unsigned)f2bf(v1) << 16);
  }
  __syncthreads();
#pragma unroll
  for (int it = 0; it < 4; it++) {
    const int idx = it * 512 + tid;
    const int c = idx >> 4;
    const int r4 = (idx & 15) * 4;
    const unsigned u0 = T->Bu[c * 33 + (r4 >> 1)];
    const unsigned u1 = T->Bu[c * 33 + (r4 >> 1) + 1];
    ushort4 u;
    u.x = (unsigned short)(u0 & 0xffff);
    u.y = (unsigned short)(u0 >> 16);
    u.z = (unsigned short)(u1 & 0xffff);
    u.w = (unsigned short)(u1 >> 16);
    *reinterpret_cast<ushort4*>(&out[(size_t)(c0 + c) * R + r0 + r4]) = u;
  }
}

// ============ 128x128 / BK=32 GEMM, 3-slot depth-2 counted-vmcnt pipeline ==========
#define PIPE_WAIT(i, NT)                                                     \
  if ((i) == (NT) - 1)                                                       \
    asm volatile("s_waitcnt vmcnt(0) lgkmcnt(0)" ::: "memory");              \
  else                                                                       \
    asm volatile("s_waitcnt vmcnt(4) lgkmcnt(0)" ::: "memory");              \
  __builtin_amdgcn_s_barrier();

#define GEMM_FRAGS_MFMA(CC)                                                  \
  bf16x8 af[4], bfr[4];                                                      \
  _Pragma("unroll")                                                          \
  for (int mt = 0; mt < 4; mt++)                                             \
    af[mt] = *reinterpret_cast<const bf16x8*>(                               \
        &Asm[CC][(wm + mt * 16 + la) * 32 + lk]);                            \
  _Pragma("unroll")                                                          \
  for (int nt = 0; nt < 4; nt++)                                             \
    bfr[nt] = *reinterpret_cast<const bf16x8*>(                              \
        &Bsm[CC][(wn + nt * 16 + la) * 32 + lk]);                            \
  __builtin_amdgcn_s_setprio(1);                                             \
  _Pragma("unroll")                                                          \
  for (int mt = 0; mt < 4; mt++)                                             \
    _Pragma("unroll")                                                        \
    for (int nt = 0; nt < 4; nt++)                                           \
      acc[mt][nt] =                                                          \
          __builtin_amdgcn_mfma_f32_16x16x32_bf16(af[mt], bfr[nt], acc[mt][nt], 0, 0, 0); \
  __builtin_amdgcn_s_setprio(0);

#define PIPE_ROT()                                                           \
  cc = (cc == 2) ? 0 : cc + 1;                                               \
  cs = (cs == 2) ? 0 : cs + 1;

// ------- FUSED: z==0 -> QKV GEMM; z=1..5 -> w1/w2 transpose tiles [1536,3200) ------
__global__ __launch_bounds__(256) void qkv_trans_kernel(
    const unsigned short* __restrict__ A, const unsigned short* __restrict__ Bt,
    const float* __restrict__ bias,
    unsigned short* __restrict__ q_out, unsigned short* __restrict__ k_out,
    unsigned short* __restrict__ vt_out,
    const float* __restrict__ w1, const float* __restrict__ w2,
    unsigned short* __restrict__ w1t, unsigned short* __restrict__ w2t)
{
  __shared__ union {
    struct { unsigned short A[3][4096]; unsigned short B[3][4096]; } g;   // 48 KB
    TransLds t;                                                           // 49.7 KB
  } sm;
  const int tid = threadIdx.x;

  if (blockIdx.z == 0) {
    unsigned short (*Asm)[4096] = sm.g.A;
    unsigned short (*Bsm)[4096] = sm.g.B;
    int bx = blockIdx.x, by = blockIdx.y;
    xcd_remap(bx, by);
    const int wave = tid >> 6;
    const int lane = tid & 63;
    const int m0 = by * 128;
    const int n0 = bx * 128;
    const int wm = (wave >> 1) * 64;
    const int wn = (wave & 1) * 64;
    const int la = lane & 15;
    const int lk = (lane >> 4) * 8;

    f32x4 acc[4][4] = {};

    const int srow = tid >> 2;
    const int skoff = (tid & 3) * 8;
    const unsigned short* Ag = A + (size_t)(m0 + srow) * HID + skoff;
    const unsigned short* Bg = Bt + (size_t)(n0 + srow) * HID + skoff;

    auto stage = [&](int s, int k0) {
      gload16(Ag + k0, &Asm[s][wave * 512]);
      gload16(Ag + (size_t)64 * HID + k0, &Asm[s][2048 + wave * 512]);
      gload16(Bg + k0, &Bsm[s][wave * 512]);
      gload16(Bg + (size_t)64 * HID + k0, &Bsm[s][2048 + wave * 512]);
    };

    stage(0, 0);
    stage(1, 32);
    const int NT = HID >> 5;
    int cc = 0, cs = 2;
    for (int i = 0; i < NT; ++i) {
      PIPE_WAIT(i, NT)
      if (i + 2 < NT) stage(cs, (i + 2) << 5);
      GEMM_FRAGS_MFMA(cc)
      PIPE_ROT()
    }

    const int lg = lane >> 4;
#pragma unroll
    for (int mt = 0; mt < 4; mt++) {
#pragma unroll
      for (int nt = 0; nt < 4; nt++) {
#pragma unroll
        for (int r = 0; r < 4; r++) {
          const int row = m0 + wm + mt * 16 + lg * 4 + r;
          const int col = n0 + wn + nt * 16 + la;
          float v = acc[mt][nt][r] + bias[col];
          const int hh = (col & 1023) >> 6;
          const int dd = col & 63;
          const unsigned short bv = f2bf(v);
          if (col < 1024)
            q_out[(size_t)hh * SL * HD + (size_t)row * HD + dd] = bv;
          else if (col < 2048)
            k_out[(size_t)hh * SL * HD + (size_t)row * HD + dd] = bv;
          else
            vt_out[(size_t)hh * HD * SL + (size_t)dd * SL + row] = bv;
        }
      }
    }
  } else {
    const int id = blockIdx.y * 24 + blockIdx.x;          // 0..383
    const int tile = 1536 + ((int)blockIdx.z - 1) * 384 + id;
    if (tile >= 3200) return;
    trans_tile(tile, w1, w2, w1t, w2t, tid, &sm.t);
  }
}

// ------- out-proj GEMM (z=0,1: split-K fp32 partials) + transpose tiles [3200,4096) -
__global__ __launch_bounds__(256) void gemm_bt2(
    const unsigned short* __restrict__ A, const unsigned short* __restrict__ Bt,
    float* __restrict__ outf,
    const float* __restrict__ w1, const float* __restrict__ w2,
    unsigned short* __restrict__ w1t, unsigned short* __restrict__ w2t)
{
  __shared__ union {
    struct { unsigned short A[3][4096]; unsigned short B[3][4096]; } g;
    TransLds t;
  } sm;
  const int tid = threadIdx.x;

  if (blockIdx.z >= 2) {
    const int id = blockIdx.y * 8 + blockIdx.x;          // 0..127
    const int tile = 3200 + ((int)blockIdx.z - 2) * 128 + id;
    trans_tile(tile, w1, w2, w1t, w2t, tid, &sm.t);
    return;
  }

  unsigned short (*Asm)[4096] = sm.g.A;
  unsigned short (*Bsm)[4096] = sm.g.B;
  int bx = blockIdx.x, by = blockIdx.y;
  xcd_remap(bx, by);
  const int wave = tid >> 6;
  const int lane = tid & 63;
  const int m0 = by * 128;
  const int n0 = bx * 128;
  const int koff = blockIdx.z * (HID / 2);
  const int wm = (wave >> 1) * 64;
  const int wn = (wave & 1) * 64;
  const int la = lane & 15;
  const int lk = (lane >> 4) * 8;

  f32x4 acc[4][4] = {};

  const int srow = tid >> 2;
  const int skoff = (tid & 3) * 8;
  const unsigned short* Ag = A + (size_t)(m0 + srow) * HID + koff + skoff;
  const unsigned short* Bg = Bt + (size_t)(n0 + srow) * HID + koff + skoff;

  auto stage = [&](int s, int k0) {
    gload16(Ag + k0, &Asm[s][wave * 512]);
    gload16(Ag + (size_t)64 * HID + k0, &Asm[s][2048 + wave * 512]);
    gload16(Bg + k0, &Bsm[s][wave * 512]);
    gload16(Bg + (size_t)64 * HID + k0, &Bsm[s][2048 + wave * 512]);
  };

  stage(0, 0);
  stage(1, 32);
  const int NT = (HID / 2) >> 5;
  int cc = 0, cs = 2;
  for (int i = 0; i < NT; ++i) {
    PIPE_WAIT(i, NT)
    if (i + 2 < NT) stage(cs, (i + 2) << 5);
    GEMM_FRAGS_MFMA(cc)
    PIPE_ROT()
  }

  const int lg = lane >> 4;
#pragma unroll
  for (int mt = 0; mt < 4; mt++) {
#pragma unroll
    for (int nt = 0; nt < 4; nt++) {
#pragma unroll
      for (int r = 0; r < 4; r++) {
        const int row = m0 + wm + mt * 16 + lg * 4 + r;
        const int col = n0 + wn + nt * 16 + la;
        outf[(size_t)blockIdx.z * SL * HID + (size_t)row * HID + col] = acc[mt][nt][r];
      }
    }
  }
}

// ---------------- MoE GEMM1: gathered A, gelu*gate epilogue -> hmidg (bf16) --------
__global__ __launch_bounds__(256) void gemm_moe1(
    const unsigned short* __restrict__ A, const unsigned short* __restrict__ w1t,
    const int* __restrict__ perm, const float* __restrict__ gateg,
    const int* __restrict__ texp, const int* __restrict__ trow,
    unsigned short* __restrict__ hmidg)
{
  __shared__ unsigned short Asm[3][128 * 32];
  __shared__ unsigned short Bsm[3][128 * 32];
  int bx = blockIdx.x, by = blockIdx.y;
  xcd_remap(bx, by);
  const int e = texp[by];
  if (e < 0) return;
  const int row0 = trow[by];
  const int tid = threadIdx.x;
  const int wave = tid >> 6;
  const int lane = tid & 63;
  const int n0 = bx * 128;
  const int wm = (wave >> 1) * 64;
  const int wn = (wave & 1) * 64;
  const int la = lane & 15;
  const int lk = (lane >> 4) * 8;
  f32x4 acc[4][4] = {};

  const int srow = tid >> 2;
  const int skoff = (tid & 3) * 8;
  const int p0 = perm[row0 + srow];
  const int p1 = perm[row0 + 64 + srow];
  const unsigned short* Ag0 = A + (size_t)(p0 < 0 ? 0 : (p0 >> 1)) * HID + skoff;
  const unsigned short* Ag1 = A + (size_t)(p1 < 0 ? 0 : (p1 >> 1)) * HID + skoff;
  const unsigned short* Bg = w1t + (size_t)e * HID * FF + (size_t)(n0 + srow) * HID + skoff;

  auto stage = [&](int s, int k0) {
    gload16(Ag0 + k0, &Asm[s][wave * 512]);
    gload16(Ag1 + k0, &Asm[s][2048 + wave * 512]);
    gload16(Bg + k0, &Bsm[s][wave * 512]);
    gload16(Bg + (size_t)64 * HID + k0, &Bsm[s][2048 + wave * 512]);
  };

  stage(0, 0);
  stage(1, 32);
  const int NT = HID >> 5;
  int cc = 0, cs = 2;
  for (int i = 0; i < NT; ++i) {
    PIPE_WAIT(i, NT)
    if (i + 2 < NT) stage(cs, (i + 2) << 5);
    GEMM_FRAGS_MFMA(cc)
    PIPE_ROT()
  }

  const int lg = lane >> 4;
#pragma unroll
  for (int mt = 0; mt < 4; mt++) {
    float gr[4];
#pragma unroll
    for (int r = 0; r < 4; r++) gr[r] = gateg[row0 + wm + mt * 16 + lg * 4 + r];
#pragma unroll
    for (int nt = 0; nt < 4; nt++) {
#pragma unroll
      for (int r = 0; r < 4; r++) {
        const int grow = row0 + wm + mt * 16 + lg * 4 + r;
        const int col = n0 + wn + nt * 16 + la;
        const float v = acc[mt][nt][r];
        const float g = 0.5f * v * (1.0f + erff(v * 0.70710678118f));
        hmidg[(size_t)grow * FF + col] = f2bf(g * gr[r]);
      }
    }
  }
}

// ------- MoE GEMM2: split-K x2, scatter bf16 partial rows -> ybuf[z*2+slot][token] -
__global__ __launch_bounds__(256) void gemm_moe2(
    const unsigned short* __restrict__ A, const unsigned short* __restrict__ w2t,
    const int* __restrict__ perm,
    const int* __restrict__ texp, const int* __restrict__ trow,
    unsigned short* __restrict__ ybuf)
{
  __shared__ unsigned short Asm[3][128 * 32];
  __shared__ unsigned short Bsm[3][128 * 32];
  int bx = blockIdx.x, by = blockIdx.y;
  xcd_remap(bx, by);
  const int e = texp[by];
  if (e < 0) return;
  const int row0 = trow[by];
  const int tid = threadIdx.x;
  const int wave = tid >> 6;
  const int lane = tid & 63;
  const int n0 = bx * 128;
  const int koff = blockIdx.z * (FF / 2);
  const int wm = (wave >> 1) * 64;
  const int wn = (wave & 1) * 64;
  const int la = lane & 15;
  const int lk = (lane >> 4) * 8;
  f32x4 acc[4][4] = {};

  const int srow = tid >> 2;
  const int skoff = (tid & 3) * 8;
  const unsigned short* Ag = A + (size_t)(row0 + srow) * FF + koff + skoff;
  const unsigned short* Bg = w2t + (size_t)e * FF * HID + (size_t)(n0 + srow) * FF + koff + skoff;

  auto stage = [&](int s, int k0) {
    gload16(Ag + k0, &Asm[s][wave * 512]);
    gload16(Ag + (size_t)64 * FF + k0, &Asm[s][2048 + wave * 512]);
    gload16(Bg + k0, &Bsm[s][wave * 512]);
    gload16(Bg + (size_t)64 * FF + k0, &Bsm[s][2048 + wave * 512]);
  };

  stage(0, 0);
  stage(1, 32);
  const int NT = (FF / 2) >> 5;
  int cc = 0, cs = 2;
  for (int i = 0; i < NT; ++i) {
    PIPE_WAIT(i, NT)
    if (i + 2 < NT) stage(cs, (i + 2) << 5);
    GEMM_FRAGS_MFMA(cc)
    PIPE_ROT()
  }

  const int lg = lane >> 4;
#pragma unroll
  for (int mt = 0; mt < 4; mt++) {
    int pr[4];
#pragma unroll
    for (int r = 0; r < 4; r++) pr[r] = perm[row0 + wm + mt * 16 + lg * 4 + r];
#pragma unroll
    for (int nt = 0; nt < 4; nt++) {
#pragma unroll
      for (int r = 0; r < 4; r++) {
        const int p = pr[r];
        if (p >= 0) {
          const int col = n0 + wn + nt * 16 + la;
          ybuf[(size_t)(blockIdx.z * 2 + (p & 1)) * SL * HID + (size_t)(p >> 1) * HID + col] =
              f2bf(acc[mt][nt][r]);
        }
      }
    }
  }
}

// FUSED: x<SL -> LayerNorm(ln1); x in [SL,SL+512) -> weight convert;
//        x in [SL+512, SL+1024) -> transpose tiles [0,512)
__global__ __launch_bounds__(256) void ln_conv_kernel(
    const float* __restrict__ x, const float* __restrict__ w, const float* __restrict__ b,
    unsigned short* __restrict__ ob,
    const float4* __restrict__ cva, const float4* __restrict__ cvb,
    ushort4* __restrict__ coa, ushort4* __restrict__ cob,
    const float* __restrict__ w1, const float* __restrict__ w2,
    unsigned short* __restrict__ w1t, unsigned short* __restrict__ w2t)
{
  __shared__ union { struct { float ps[4], pq[4]; } l; TransLds t; } sm;
  const int tid = threadIdx.x;
  if ((int)blockIdx.x < SL) {
    const int row = blockIdx.x;
    const float4 v = *reinterpret_cast<const float4*>(&x[(size_t)row * HID + tid * 4]);
    float s = v.x + v.y + v.z + v.w;
    float q = v.x * v.x + v.y * v.y + v.z * v.z + v.w * v.w;
    for (int off = 32; off > 0; off >>= 1) {
      s += __shfl_down(s, off);
      q += __shfl_down(q, off);
    }
    const int wave = tid >> 6, lane = tid & 63;
    if (lane == 0) { sm.l.ps[wave] = s; sm.l.pq[wave] = q; }
    __syncthreads();
    s = sm.l.ps[0] + sm.l.ps[1] + sm.l.ps[2] + sm.l.ps[3];
    q = sm.l.pq[0] + sm.l.pq[1] + sm.l.pq[2] + sm.l.pq[3];
    const float mu = s * (1.0f / HID);
    const float inv = rsqrtf(q * (1.0f / HID) - mu * mu + 1e-5f);
    const int i = tid * 4;
    const float4 wv = *reinterpret_cast<const float4*>(&w[i]);
    const float4 bv = *reinterpret_cast<const float4*>(&b[i]);
    ushort4 u;
    u.x = f2bf((v.x - mu) * inv * wv.x + bv.x);
    u.y = f2bf((v.y - mu) * inv * wv.y + bv.y);
    u.z = f2bf((v.z - mu) * inv * wv.z + bv.z);
    u.w = f2bf((v.w - mu) * inv * wv.w + bv.w);
    *reinterpret_cast<ushort4*>(&ob[(size_t)row * HID + i]) = u;
  } else if ((int)blockIdx.x < SL + 512) {
    const int NA = 3 * HID * HID / 4, NB = HID * HID / 4;
    for (int i = ((int)blockIdx.x - SL) * 256 + tid; i < NA + NB; i += 512 * 256) {
      if (i < NA) {
        const float4 v = cva[i];
        ushort4 u; u.x = f2bf(v.x); u.y = f2bf(v.y); u.z = f2bf(v.z); u.w = f2bf(v.w);
        coa[i] = u;
      } else {
        const float4 v = cvb[i - NA];
        ushort4 u; u.x = f2bf(v.x); u.y = f2bf(v.y); u.z = f2bf(v.z); u.w = f2bf(v.w);
        cob[i - NA] = u;
      }
    }
  } else {
    const int tile = (int)blockIdx.x - SL - 512;   // 0..511
    trans_tile(tile, w1, w2, w1t, w2t, tid, &sm.t);
  }
}

// ------- fused: x1 = x + bias + p0 + p1; LN(x1) -> hn2_b; ROUTER (top-2) -----------
__global__ __launch_bounds__(256) void combine_ln(
    const float4* __restrict__ x, const float* __restrict__ bias,
    const float4* __restrict__ p0, const float4* __restrict__ p1,
    float4* __restrict__ x1,
    const float* __restrict__ w, const float* __restrict__ b,
    unsigned short* __restrict__ ob,
    const float* __restrict__ rw,
    int* __restrict__ ti, float* __restrict__ tg, int* __restrict__ cnt)
{
  __shared__ float ps[4], pq[4];
  __shared__ float rsm[4][8];
  const int row = blockIdx.x;
  const int tid = threadIdx.x;
  const int i4 = row * 256 + tid;
  const int i = tid * 4;
  const float4 bv0 = *reinterpret_cast<const float4*>(&bias[i]);
  const float4 a = x[i4], c = p0[i4], d = p1[i4];
  float4 v;
  v.x = a.x + bv0.x + c.x + d.x;
  v.y = a.y + bv0.y + c.y + d.y;
  v.z = a.z + bv0.z + c.z + d.z;
  v.w = a.w + bv0.w + c.w + d.w;
  x1[i4] = v;
  float s = v.x + v.y + v.z + v.w;
  float q = v.x * v.x + v.y * v.y + v.z * v.z + v.w * v.w;
  for (int off = 32; off > 0; off >>= 1) {
    s += __shfl_down(s, off);
    q += __shfl_down(q, off);
  }
  const int wave = tid >> 6, lane = tid & 63;
  if (lane == 0) { ps[wave] = s; pq[wave] = q; }
  __syncthreads();
  s = ps[0] + ps[1] + ps[2] + ps[3];
  q = pq[0] + pq[1] + pq[2] + pq[3];
  const float mu = s * (1.0f / HID);
  const float inv = rsqrtf(q * (1.0f / HID) - mu * mu + 1e-5f);
  const float4 wv = *reinterpret_cast<const float4*>(&w[i]);
  const float4 bv = *reinterpret_cast<const float4*>(&b[i]);
  const float o0 = (v.x - mu) * inv * wv.x + bv.x;
  const float o1 = (v.y - mu) * inv * wv.y + bv.y;
  const float o2 = (v.z - mu) * inv * wv.z + bv.z;
  const float o3 = (v.w - mu) * inv * wv.w + bv.w;
  ushort4 u; u.x = f2bf(o0); u.y = f2bf(o1); u.z = f2bf(o2); u.w = f2bf(o3);
  *reinterpret_cast<ushort4*>(&ob[(size_t)row * HID + i]) = u;

  // ---- fused router: logits[e] = sum_i hn2[i] * rw[e][i] (fp32) ----
  float pl[NEXP];
#pragma unroll
  for (int e = 0; e < NEXP; e++) {
    const float4 rv = *reinterpret_cast<const float4*>(&rw[e * HID + i]);
    pl[e] = o0 * rv.x + o1 * rv.y + o2 * rv.z + o3 * rv.w;
  }
#pragma unroll
  for (int e = 0; e < NEXP; e++) {
    pl[e] += __shfl_xor(pl[e], 32);
    pl[e] += __shfl_xor(pl[e], 16);
    pl[e] += __shfl_xor(pl[e], 8);
    pl[e] += __shfl_xor(pl[e], 4);
    pl[e] += __shfl_xor(pl[e], 2);
    pl[e] += __shfl_xor(pl[e], 1);
  }
  if (lane == 0) {
#pragma unroll
    for (int e = 0; e < NEXP; e++) rsm[wave][e] = pl[e];
  }
  __syncthreads();
  if (tid == 0) {
    float lgt[NEXP];
#pragma unroll
    for (int e = 0; e < NEXP; e++)
      lgt[e] = rsm[0][e] + rsm[1][e] + rsm[2][e] + rsm[3][e];
    float mx = lgt[0];
#pragma unroll
    for (int e = 1; e < NEXP; e++) mx = fmaxf(mx, lgt[e]);
    float Z = 0.f;
    float pexp[NEXP];
#pragma unroll
    for (int e = 0; e < NEXP; e++) { pexp[e] = expf(lgt[e] - mx); Z += pexp[e]; }
    const float invZ = 1.f / Z;
    int i1 = 0;
#pragma unroll
    for (int e = 1; e < NEXP; e++) if (pexp[e] > pexp[i1]) i1 = e;
    int i2 = (i1 == 0) ? 1 : 0;
#pragma unroll
    for (int e = 0; e < NEXP; e++) if (e != i1 && pexp[e] > pexp[i2]) i2 = e;
    ti[2 * row] = i1; ti[2 * row + 1] = i2;
    tg[2 * row] = pexp[i1] * invZ; tg[2 * row + 1] = pexp[i2] * invZ;
    atomicAdd(&cnt[i1 * CPAD], 1);
    atomicAdd(&cnt[i2 * CPAD], 1);
  }
}

// ------- fused scan + build: single block, LDS-atomic fills ----------------
__global__ __launch_bounds__(256) void scan_build_kernel(
    const int* __restrict__ cnt, const int* __restrict__ ti, const float* __restrict__ tg,
    int* __restrict__ texp, int* __restrict__ trow,
    int* __restrict__ perm, float* __restrict__ gateg)
{
  __shared__ int poff[NEXP];
  __shared__ int lfill[NEXP];
  const int tid = threadIdx.x;
  if (tid == 0) {
    int off = 0, nt = 0;
    for (int e = 0; e < NEXP; e++) {
      poff[e] = off;
      const int c = cnt[e * CPAD];
      const int ntl = (c + 127) >> 7;
      for (int i = 0; i < ntl; i++) { texp[nt] = e; trow[nt] = off + i * 128; nt++; }
      off += ntl * 128;
    }
    for (int i = nt; i < MAXTILE; i++) { texp[i] = -1; trow[i] = 0; }
  }
  if (tid < NEXP) lfill[tid] = 0;
  __syncthreads();
  for (int t = tid; t < SL; t += 256) {
#pragma unroll
    for (int s2 = 0; s2 < 2; s2++) {
      const int e = ti[2 * t + s2];
      const int l = atomicAdd(&lfill[e], 1);
      const int pos = poff[e] + l;
      perm[pos] = 2 * t + s2;
      gateg[pos] = tg[2 * t + s2];
    }
  }
}

// ---------------- final: out = x1 + y0 + y1 + y2 + y3 (bf16 slabs) ----------------
__global__ __launch_bounds__(256) void final_add(
    const float4* __restrict__ x1, const ushort4* __restrict__ y0,
    const ushort4* __restrict__ y1, const ushort4* __restrict__ y2,
    const ushort4* __restrict__ y3, float4* __restrict__ out)
{
  const int i = blockIdx.x * 256 + threadIdx.x;
  const float4 a = x1[i];
  const ushort4 b = y0[i], c = y1[i], d = y2[i], e = y3[i];
  float4 o;
  o.x = a.x + bf2f(b.x) + bf2f(c.x) + bf2f(d.x) + bf2f(e.x);
  o.y = a.y + bf2f(b.y) + bf2f(c.y) + bf2f(d.y) + bf2f(e.y);
  o.z = a.z + bf2f(b.z) + bf2f(c.z) + bf2f(d.z) + bf2f(e.z);
  o.w = a.w + bf2f(b.w) + bf2f(c.w) + bf2f(d.w) + bf2f(e.w);
  out[i] = o;
}

// ------- flash attention (z=0), causal, paired q-tiles, 8 waves = 2 KV-split groups;
//         z=1..4 -> w1/w2 transpose tiles [512,1536) (co-resident: 80KB LDS each) ----
#define SC2 0.1803368801111204f  /* 0.125 * log2(e) */
#define PPITCH 16                /* u32 pitch for P rows (16 -> 80KB block, 2/CU) */
__global__ __launch_bounds__(512) void attn_kernel(
    const unsigned short* __restrict__ qb, const unsigned short* __restrict__ kb,
    const unsigned short* __restrict__ vtb, unsigned short* __restrict__ attn,
    const float* __restrict__ w1, const float* __restrict__ w2,
    unsigned short* __restrict__ w1t, unsigned short* __restrict__ w2t)
{
  __shared__ union {
    struct {
      unsigned short Kt[2][2][64 * 64];   // 32 KB
      unsigned short Vt[2][2][64 * 64];   // 32 KB
      unsigned plds[8 * 32 * PPITCH];     // 16 KB
    } a;
    TransLds t;                           // 49.7 KB
  } sm;
  const int tid = threadIdx.x;

  if (blockIdx.z > 0) {
    const int id = blockIdx.y * 16 + blockIdx.x;             // 0..255
    const int tile = 512 + ((int)blockIdx.z - 1) * 256 + id; // [512,1536)
    trans_tile512(tile, w1, w2, w1t, w2t, tid, &sm.t);
    return;
  }

  const int h = blockIdx.y;
  const int wave = tid >> 6, lane = tid & 63;
  const int grp = wave >> 2;
  const int w4 = wave & 3;
  const int la = lane & 15, lg = lane >> 4;
  const int la7 = la & 7;
  const unsigned short* qh = qb + (size_t)h * SL * HD;
  const unsigned short* kh = kb + (size_t)h * SL * HD;
  const unsigned short* vh = vtb + (size_t)h * HD * SL;
  unsigned* pu = &sm.a.plds[wave * 32 * PPITCH];

  const int sr_lo = w4 * 8 + (lane >> 3);
  const int ss = lane & 7;

  auto stageKV = [&](int t, int buf) {
    const int kvb = t * 64;
#pragma unroll
    for (int j = 0; j < 2; j++) {
      const int row = j * 32 + sr_lo;
      const int s = ss ^ (row & 7);
      gload16(kh + (size_t)(kvb + row) * HD + s * 8, &sm.a.Kt[grp][buf][j * 2048 + w4 * 512]);
      gload16(vh + (size_t)row * SL + kvb + s * 8, &sm.a.Vt[grp][buf][j * 2048 + w4 * 512]);
    }
  };

  for (int half = 0; half < 2; half++) {
    const int qt = half ? (31 - blockIdx.x) : blockIdx.x;
    const int m0 = qt * 64 + w4 * 16;
    const int T = qt + 1;
    const int S = (T + 1) >> 1;
    const int q = m0 + la;

    bf16x8 aq0 = *reinterpret_cast<const bf16x8*>(&qh[(size_t)(m0 + la) * HD + lg * 8]);
    bf16x8 aq1 = *reinterpret_cast<const bf16x8*>(&qh[(size_t)(m0 + la) * HD + 32 + lg * 8]);

    f32x4 oacc[4] = {};
    float mrun = -1e30f, lrun = 0.f;

    if (grp < T) stageKV(grp, 0);
    __syncthreads();
    int cur = 0;

    for (int s = 0; s < S; s++) {
      const int tmy = 2 * s + grp;
      if (tmy + 2 < T) stageKV(tmy + 2, cur ^ 1);
      if (tmy < T) {
        const int kv0 = tmy * 64;
        const unsigned short* Kb = sm.a.Kt[grp][cur];
        const unsigned short* Vb = sm.a.Vt[grp][cur];

        f32x4 sac[4] = {};
        __builtin_amdgcn_s_setprio(1);
#pragma unroll
        for (int nt = 0; nt < 4; nt++) {
          const int row = nt * 16 + la;
          bf16x8 b0 = *reinterpret_cast<const bf16x8*>(&Kb[row * 64 + ((lg ^ la7) << 3)]);
          bf16x8 b1 = *reinterpret_cast<const bf16x8*>(&Kb[row * 64 + (((4 + lg) ^ la7) << 3)]);
          sac[nt] = __builtin_amdgcn_mfma_f32_16x16x32_bf16(b0, aq0, sac[nt], 0, 0, 0);
          sac[nt] = __builtin_amdgcn_mfma_f32_16x16x32_bf16(b1, aq1, sac[nt], 0, 0, 0);
        }
        __builtin_amdgcn_s_setprio(0);
        float sv[4][4];
        const bool diag = (tmy == qt);
#pragma unroll
        for (int nt = 0; nt < 4; nt++)
#pragma unroll
          for (int r = 0; r < 4; r++) {
            float xs = sac[nt][r] * SC2;
            if (diag && (kv0 + nt * 16 + lg * 4 + r) > q) xs = -1e30f;
            sv[nt][r] = xs;
          }
        float pm = fmaxf(fmaxf(sv[0][0], sv[0][1]), fmaxf(sv[0][2], sv[0][3]));
#pragma unroll
        for (int nt = 1; nt < 4; nt++)
          pm = fmaxf(pm, fmaxf(fmaxf(sv[nt][0], sv[nt][1]), fmaxf(sv[nt][2], sv[nt][3])));
        pm = fmaxf(pm, __shfl_xor(pm, 16));
        pm = fmaxf(pm, __shfl_xor(pm, 32));
        const float mn = fmaxf(mrun, pm);
        float rs = 0.f;
#pragma unroll
        for (int nt = 0; nt < 4; nt++)
#pragma unroll
          for (int r = 0; r < 4; r++) {
            const float pe = exp2f(sv[nt][r] - mn);
            sv[nt][r] = pe;
            rs += pe;
          }
        rs += __shfl_xor(rs, 16);
        rs += __shfl_xor(rs, 32);
        if (__ballot(pm > mrun) != 0ULL) {
          const float al = exp2f(mrun - mn);
#pragma unroll
          for (int dt = 0; dt < 4; dt++)
#pragma unroll
            for (int r = 0; r < 4; r++) oacc[dt][r] *= al;
          lrun = lrun * al + rs;
          mrun = mn;
        } else {
          lrun += rs;
        }
#pragma unroll
        for (int nt = 0; nt < 4; nt++)
#pragma unroll
          for (int rp = 0; rp < 2; rp++) {
            unsigned pk;
            asm("v_cvt_pk_bf16_f32 %0, %1, %2"
                : "=v"(pk) : "v"(sv[nt][rp * 2]), "v"(sv[nt][rp * 2 + 1]));
            pu[(nt * 8 + lg * 2 + rp) * PPITCH + la] = pk;
          }
        asm volatile("s_waitcnt lgkmcnt(0)" ::: "memory");
        __builtin_amdgcn_sched_barrier(0);
        u32x4 w0, w1v;
#pragma unroll
        for (int jj = 0; jj < 4; jj++) {
          w0[jj] = pu[(lg * 4 + jj) * PPITCH + la];
          w1v[jj] = pu[(16 + lg * 4 + jj) * PPITCH + la];
        }
        const bf16x8 pa0 = __builtin_bit_cast(bf16x8, w0);
        const bf16x8 pa1 = __builtin_bit_cast(bf16x8, w1v);
        __builtin_amdgcn_s_setprio(1);
#pragma unroll
        for (int dt = 0; dt < 4; dt++) {
          const int row = dt * 16 + la;
          bf16x8 v0 = *reinterpret_cast<const bf16x8*>(&Vb[row * 64 + ((lg ^ la7) << 3)]);
          bf16x8 v1 = *reinterpret_cast<const bf16x8*>(&Vb[row * 64 + (((4 + lg) ^ la7) << 3)]);
          oacc[dt] = __builtin_amdgcn_mfma_f32_16x16x32_bf16(v0, pa0, oacc[dt], 0, 0, 0);
          oacc[dt] = __builtin_amdgcn_mfma_f32_16x16x32_bf16(v1, pa1, oacc[dt], 0, 0, 0);
        }
        __builtin_amdgcn_s_setprio(0);
      }
      __syncthreads();
      cur ^= 1;
    }

    float* xb = (float*)&sm.a.Kt[0][0][0];
    float* mlb = (float*)&sm.a.Vt[0][0][0];
    if (grp == 1) {
#pragma unroll
      for (int dt = 0; dt < 4; dt++)
#pragma unroll
        for (int r = 0; r < 4; r++)
          xb[w4 * 1024 + (dt * 16 + lg * 4 + r) * 16 + la] = oacc[dt][r];
      if (lg == 0) {
        mlb[w4 * 32 + la * 2] = mrun;
        mlb[w4 * 32 + la * 2 + 1] = lrun;
      }
    }
    __syncthreads();
    if (grp == 0) {
      const float m1 = mlb[w4 * 32 + la * 2];
      const float l1 = mlb[w4 * 32 + la * 2 + 1];
      const float mm = fmaxf(mrun, m1);
      const float a0 = exp2f(mrun - mm);
      const float a1 = exp2f(m1 - mm);
      const float linv = 1.0f / (lrun * a0 + l1 * a1);
#pragma unroll
      for (int dt = 0; dt < 4; dt++) {
        ushort4 u;
        float o0 = (oacc[dt][0] * a0 + xb[w4 * 1024 + (dt * 16 + lg * 4 + 0) * 16 + la] * a1) * linv;
        float o1 = (oacc[dt][1] * a0 + xb[w4 * 1024 + (dt * 16 + lg * 4 + 1) * 16 + la] * a1) * linv;
        float o2 = (oacc[dt][2] * a0 + xb[w4 * 1024 + (dt * 16 + lg * 4 + 2) * 16 + la] * a1) * linv;
        float o3 = (oacc[dt][3] * a0 + xb[w4 * 1024 + (dt * 16 + lg * 4 + 3) * 16 + la] * a1) * linv;
        u.x = f2bf(o0); u.y = f2bf(o1); u.z = f2bf(o2); u.w = f2bf(o3);
        *reinterpret_cast<ushort4*>(&attn[(size_t)q * HID + h * HD + dt * 16 + lg * 4]) = u;
      }
    }
    __syncthreads();
  }
}

extern "C" void kernel_launch(void* const* d_in, const int* in_sizes, int n_in,
                              void* d_out, int out_size, void* d_ws, size_t ws_size,
                              hipStream_t stream)
{
  const float* x          = (const float*)d_in[0];
  const float* ln1_w      = (const float*)d_in[1];
  const float* ln1_b      = (const float*)d_in[2];
  const float* in_proj_w  = (const float*)d_in[3];
  const float* in_proj_b  = (const float*)d_in[4];
  const float* out_proj_w = (const float*)d_in[5];
  const float* out_proj_b = (const float*)d_in[6];
  const float* ln2_w      = (const float*)d_in[7];
  const float* ln2_b      = (const float*)d_in[8];
  const float* router_w   = (const float*)d_in[9];
  const float* w1         = (const float*)d_in[10];
  const float* w2         = (const float*)d_in[11];
  float* out = (float*)d_out;

  char* ws = (char*)d_ws;
  size_t off = 0;
  auto alloc = [&](size_t bytes) -> void* {
    void* p = ws + off;
    off += (bytes + 255) & ~(size_t)255;
    return p;
  };
  unsigned short* hn_b   = (unsigned short*)alloc((size_t)SL * HID * 2);
  unsigned short* ipw_b  = (unsigned short*)alloc((size_t)3 * HID * HID * 2);
  unsigned short* opw_b  = (unsigned short*)alloc((size_t)HID * HID * 2);
  unsigned short* qb     = (unsigned short*)alloc((size_t)SL * HID * 2);
  unsigned short* kb     = (unsigned short*)alloc((size_t)SL * HID * 2);
  unsigned short* vtb    = (unsigned short*)alloc((size_t)SL * HID * 2);
  unsigned short* attn_b = (unsigned short*)alloc((size_t)SL * HID * 2);
  float*          x1     = (float*)alloc((size_t)SL * HID * 4);
  float*          pbuf   = (float*)alloc((size_t)2 * SL * HID * 4);
  unsigned short* hn2_b  = (unsigned short*)alloc((size_t)SL * HID * 2);
  unsigned short* w1t    = (unsigned short*)alloc((size_t)NEXP * HID * FF * 2);
  unsigned short* w2t    = (unsigned short*)alloc((size_t)NEXP * HID * FF * 2);
  unsigned short* hmidg  = (unsigned short*)alloc((size_t)MAXROWS * FF * 2);
  unsigned short* ybuf   = (unsigned short*)alloc((size_t)4 * SL * HID * 2);
  int*            ti     = (int*)alloc((size_t)SL * 2 * 4);
  float*          tg     = (float*)alloc((size_t)SL * 2 * 4);
  int*            perm   = (int*)alloc((size_t)MAXROWS * 4);
  float*          gateg  = (float*)alloc((size_t)MAXROWS * 4);
  int*            cnt    = (int*)alloc(NEXP * CPAD * 4);
  int*            texp   = (int*)alloc(64 * 4);
  int*            trow   = (int*)alloc(64 * 4);

  const dim3 blk(256);

  hipMemsetAsync(cnt, 0, NEXP * CPAD * 4, stream);
  hipMemsetAsync(perm, 0xFF, (size_t)MAXROWS * 4, stream);
  hipMemsetAsync(gateg, 0, (size_t)MAXROWS * 4, stream);

  // fused LayerNorm(ln1) + weight convert + transpose tiles [0,512)
  ln_conv_kernel<<<SL + 1024, blk, 0, stream>>>(
      x, ln1_w, ln1_b, hn_b,
      (const float4*)in_proj_w, (const float4*)out_proj_w,
      (ushort4*)ipw_b, (ushort4*)opw_b,
      w1, w2, w1t, w2t);

  // fused QKV GEMM (z=0) + transpose tiles [1536,3200) (z=1..5, guarded)
  qkv_trans_kernel<<<dim3(3 * HID / 128, SL / 128, 6), blk, 0, stream>>>(
      hn_b, ipw_b, in_proj_b, qb, kb, vtb, w1, w2, w1t, w2t);

  // attn (z=0) + transpose tiles [512,1536) (z=1..4, co-resident at 80KB LDS)
  attn_kernel<<<dim3(16, NHEAD, 5), dim3(512), 0, stream>>>(
      qb, kb, vtb, attn_b, w1, w2, w1t, w2t);

  // out-proj split-K x2 (z=0,1, fp32 partials) + transpose tiles [3200,4096) (z=2..8)
  gemm_bt2<<<dim3(HID / 128, SL / 128, 9), blk, 0, stream>>>(
      attn_b, opw_b, pbuf, w1, w2, w1t, w2t);

  // fused combine + LN2 + router (fp32 partials -> exact router)
  combine_ln<<<SL, blk, 0, stream>>>(
      (const float4*)x, out_proj_b, (const float4*)pbuf,
      (const float4*)(pbuf + (size_t)SL * HID), (float4*)x1,
      ln2_w, ln2_b, hn2_b,
      router_w, ti, tg, cnt);

  scan_build_kernel<<<1, blk, 0, stream>>>(cnt, ti, tg, texp, trow, perm, gateg);

  gemm_moe1<<<dim3(FF / 128, MAXTILE), blk, 0, stream>>>(
      hn2_b, w1t, perm, gateg, texp, trow, hmidg);
  gemm_moe2<<<dim3(HID / 128, MAXTILE, 2), blk, 0, stream>>>(
      hmidg, w2t, perm, texp, trow, ybuf);

  final_add<<<SL * HID / 1024, blk, 0, stream>>>(
      (const float4*)x1, (const ushort4*)ybuf,
      (const ushort4*)(ybuf + (size_t)SL * HID),
      (const ushort4*)(ybuf + (size_t)2 * SL * HID),
      (const ushort4*)(ybuf + (size_t)3 * SL * HID),
      (float4*)out);
}